// Round 8
// baseline (456.264 us; speedup 1.0000x reference)
//
#include <hip/hip_runtime.h>
#include <hip/hip_bf16.h>

#define DD 128   // hidden dim
#define SCB 256  // scan block size
#define CE  512  // edges per block in edge_pass (4 waves x 128)

typedef __attribute__((ext_vector_type(8))) short bf16x8;
typedef __attribute__((ext_vector_type(4))) float f32x4;

__device__ __forceinline__ unsigned bf16_rne(float f) {
    unsigned u = __float_as_uint(f);
    return (u + 0x7fffu + ((u >> 16) & 1u)) >> 16;
}

// ---------------------------------------------------------------------------
// counting-sort preprocessing (sort edges by idx_i)
// ---------------------------------------------------------------------------
__global__ __launch_bounds__(256)
void hist_kernel(const int* __restrict__ idx_i, int* __restrict__ cnt, int E)
{
    const int e = blockIdx.x * 256 + threadIdx.x;
    if (e < E) atomicAdd(&cnt[idx_i[e]], 1);
}

__global__ __launch_bounds__(SCB)
void scan1_kernel(const int* __restrict__ cnt, int* __restrict__ exc,
                  int* __restrict__ bsum, int n)
{
    __shared__ int s[SCB];
    const int i = blockIdx.x * SCB + (int)threadIdx.x;
    const int v = (i < n) ? cnt[i] : 0;
    s[threadIdx.x] = v;
    __syncthreads();
    #pragma unroll
    for (int off = 1; off < SCB; off <<= 1) {
        int t = (threadIdx.x >= off) ? s[threadIdx.x - off] : 0;
        __syncthreads();
        s[threadIdx.x] += t;
        __syncthreads();
    }
    if (i < n) exc[i] = s[threadIdx.x] - v;
    if (threadIdx.x == SCB - 1) bsum[blockIdx.x] = s[threadIdx.x];
}

__global__ __launch_bounds__(SCB)
void scan2_kernel(int* __restrict__ bsum, int nb)
{
    __shared__ int s[SCB];
    const int v = (threadIdx.x < nb) ? bsum[threadIdx.x] : 0;
    s[threadIdx.x] = v;
    __syncthreads();
    #pragma unroll
    for (int off = 1; off < SCB; off <<= 1) {
        int t = (threadIdx.x >= off) ? s[threadIdx.x - off] : 0;
        __syncthreads();
        s[threadIdx.x] += t;
        __syncthreads();
    }
    if (threadIdx.x < nb) bsum[threadIdx.x] = s[threadIdx.x] - v;
}

__global__ __launch_bounds__(SCB)
void scan3_kernel(int* __restrict__ exc, const int* __restrict__ bsum, int n)
{
    const int i = blockIdx.x * SCB + (int)threadIdx.x;
    if (i < n) exc[i] += bsum[i >> 8];
}

__global__ __launch_bounds__(256)
void scatter_kernel(const int* __restrict__ idx_i, const int* __restrict__ idx_j,
                    int* __restrict__ cursor, int* __restrict__ perm,
                    int* __restrict__ si, int* __restrict__ sj, int E)
{
    const int e = blockIdx.x * 256 + threadIdx.x;
    if (e < E) {
        const int n = idx_i[e];
        const int p = atomicAdd(&cursor[n], 1);
        perm[p] = e;
        si[p] = n;
        sj[p] = idx_j[e];
    }
}

// ---------------------------------------------------------------------------
// generic 128-K split-bf16 MFMA GEMM with optional fused node-update
// (unchanged from R7 — proven at 452 us total)
// ---------------------------------------------------------------------------
__global__ __launch_bounds__(1024)
void gemm128_mfma_kernel(float* __restrict__ A0, const float* __restrict__ A1,
                         int nA, int nTotal,
                         const float* __restrict__ W, const float* __restrict__ bias,
                         int bias_limit, int do_relu, int update,
                         float* __restrict__ sum_agg, int* __restrict__ max_agg,
                         float* __restrict__ out0, float* __restrict__ out1,
                         int ntiles)
{
    __shared__ __align__(16) unsigned char SM[131584];
    char*  const Whi = (char*)SM;
    char*  const Wlo = (char*)SM + 32768;
    char*  const Ahi = (char*)SM + 65536;
    char*  const Alo = (char*)SM + 98304;
    float* const Wf  = (float*)(SM + 65536);
    float* const bs  = (float*)(SM + 131072);

    const int t = (int)threadIdx.x;

    {
        const float4* Wg = (const float4*)W;
        float4* Wd = (float4*)Wf;
        #pragma unroll
        for (int i = 0; i < 4; ++i) Wd[t + i * 1024] = Wg[t + i * 1024];
        if (t < DD) bs[t] = bias ? bias[t] : 0.f;
    }
    __syncthreads();
    {
        const int col = t >> 3;
        const int kb  = (t & 7) * 16;
        unsigned h16[16], l16[16];
        #pragma unroll
        for (int j = 0; j < 16; ++j) {
            const float w = Wf[(size_t)(kb + j) * DD + col];
            const unsigned hb = bf16_rne(w);
            const float hf = __uint_as_float(hb << 16);
            h16[j] = hb;
            l16[j] = bf16_rne(w - hf);
        }
        #pragma unroll
        for (int c = 0; c < 2; ++c) {
            uint4 ph, pl;
            ph.x = h16[c*8+0] | (h16[c*8+1] << 16);
            ph.y = h16[c*8+2] | (h16[c*8+3] << 16);
            ph.z = h16[c*8+4] | (h16[c*8+5] << 16);
            ph.w = h16[c*8+6] | (h16[c*8+7] << 16);
            pl.x = l16[c*8+0] | (l16[c*8+1] << 16);
            pl.y = l16[c*8+2] | (l16[c*8+3] << 16);
            pl.z = l16[c*8+4] | (l16[c*8+5] << 16);
            pl.w = l16[c*8+6] | (l16[c*8+7] << 16);
            const int off = ((col * 256 + (kb + c * 8) * 2)) ^ ((col & 7) << 4);
            *(uint4*)(Whi + off) = ph;
            *(uint4*)(Wlo + off) = pl;
        }
    }

    const int w  = t >> 6;
    const int l  = t & 63;
    const int wm = w >> 2;
    const int wn = w & 3;
    const int g  = l >> 4;
    const int q  = l & 15;

    for (int tile = blockIdx.x; tile < ntiles; tile += gridDim.x) {
        const int e0 = tile * 128;
        __syncthreads();

        #pragma unroll
        for (int i = 0; i < 2; ++i) {
            const int task = t + i * 1024;
            const int row  = task >> 4;
            const int c    = task & 15;
            const int rr = min(e0 + row, nTotal - 1);
            float d[8];
            if (rr < nA) {
                float* ph0 = A0 + (size_t)rr * DD + c * 8;
                const float4 a0 = *(const float4*)ph0;
                const float4 a1 = *(const float4*)(ph0 + 4);
                if (update) {
                    float* sp = sum_agg + (size_t)rr * DD + c * 8;
                    int*   mp = max_agg + (size_t)rr * DD + c * 8;
                    const float4 s0 = *(const float4*)sp;
                    const float4 s1 = *(const float4*)(sp + 4);
                    const int4   m0 = *(const int4*)mp;
                    const int4   m1 = *(const int4*)(mp + 4);
                    d[0] = a0.x * s0.x * __int_as_float(m0.x);
                    d[1] = a0.y * s0.y * __int_as_float(m0.y);
                    d[2] = a0.z * s0.z * __int_as_float(m0.z);
                    d[3] = a0.w * s0.w * __int_as_float(m0.w);
                    d[4] = a1.x * s1.x * __int_as_float(m1.x);
                    d[5] = a1.y * s1.y * __int_as_float(m1.y);
                    d[6] = a1.z * s1.z * __int_as_float(m1.z);
                    d[7] = a1.w * s1.w * __int_as_float(m1.w);
                    *(float4*)ph0       = make_float4(d[0], d[1], d[2], d[3]);
                    *(float4*)(ph0 + 4) = make_float4(d[4], d[5], d[6], d[7]);
                    *(float4*)sp       = make_float4(0.f, 0.f, 0.f, 0.f);
                    *(float4*)(sp + 4) = make_float4(0.f, 0.f, 0.f, 0.f);
                    *(int4*)mp       = make_int4(0, 0, 0, 0);
                    *(int4*)(mp + 4) = make_int4(0, 0, 0, 0);
                } else {
                    d[0] = a0.x; d[1] = a0.y; d[2] = a0.z; d[3] = a0.w;
                    d[4] = a1.x; d[5] = a1.y; d[6] = a1.z; d[7] = a1.w;
                }
            } else {
                const float* pa = A1 + (size_t)(rr - nA) * DD + c * 8;
                const float4 a0 = *(const float4*)pa;
                const float4 a1 = *(const float4*)(pa + 4);
                d[0] = a0.x; d[1] = a0.y; d[2] = a0.z; d[3] = a0.w;
                d[4] = a1.x; d[5] = a1.y; d[6] = a1.z; d[7] = a1.w;
            }
            unsigned h8[8], l8[8];
            #pragma unroll
            for (int j = 0; j < 8; ++j) {
                const unsigned hb = bf16_rne(d[j]);
                const float hf = __uint_as_float(hb << 16);
                h8[j] = hb;
                l8[j] = bf16_rne(d[j] - hf);
            }
            uint4 ph, pl;
            ph.x = h8[0] | (h8[1] << 16);
            ph.y = h8[2] | (h8[3] << 16);
            ph.z = h8[4] | (h8[5] << 16);
            ph.w = h8[6] | (h8[7] << 16);
            pl.x = l8[0] | (l8[1] << 16);
            pl.y = l8[2] | (l8[3] << 16);
            pl.z = l8[4] | (l8[5] << 16);
            pl.w = l8[6] | (l8[7] << 16);
            const int off = ((row * 256 + c * 16)) ^ ((row & 7) << 4);
            *(uint4*)(Ahi + off) = ph;
            *(uint4*)(Alo + off) = pl;
        }
        __syncthreads();

        f32x4 acc[2][2];
        const f32x4 zero = {0.f, 0.f, 0.f, 0.f};
        acc[0][0] = zero; acc[0][1] = zero; acc[1][0] = zero; acc[1][1] = zero;

        #pragma unroll
        for (int ks = 0; ks < 4; ++ks) {
            const int kbyte = ks * 64 + g * 16;
            bf16x8 ah[2], al[2], bh[2], bl[2];
            #pragma unroll
            for (int m = 0; m < 2; ++m) {
                const int row = wm * 32 + m * 16 + q;
                const int off = (row * 256 + kbyte) ^ ((row & 7) << 4);
                ah[m] = *(const bf16x8*)(Ahi + off);
                al[m] = *(const bf16x8*)(Alo + off);
            }
            #pragma unroll
            for (int n = 0; n < 2; ++n) {
                const int colv = wn * 32 + n * 16 + q;
                const int off = (colv * 256 + kbyte) ^ ((colv & 7) << 4);
                bh[n] = *(const bf16x8*)(Whi + off);
                bl[n] = *(const bf16x8*)(Wlo + off);
            }
            #pragma unroll
            for (int m = 0; m < 2; ++m)
                #pragma unroll
                for (int n = 0; n < 2; ++n)
                    acc[m][n] = __builtin_amdgcn_mfma_f32_16x16x32_bf16(ah[m], bh[n], acc[m][n], 0, 0, 0);
            #pragma unroll
            for (int m = 0; m < 2; ++m)
                #pragma unroll
                for (int n = 0; n < 2; ++n)
                    acc[m][n] = __builtin_amdgcn_mfma_f32_16x16x32_bf16(ah[m], bl[n], acc[m][n], 0, 0, 0);
            #pragma unroll
            for (int m = 0; m < 2; ++m)
                #pragma unroll
                for (int n = 0; n < 2; ++n)
                    acc[m][n] = __builtin_amdgcn_mfma_f32_16x16x32_bf16(al[m], bh[n], acc[m][n], 0, 0, 0);
        }

        #pragma unroll
        for (int n = 0; n < 2; ++n) {
            const int colv = wn * 32 + n * 16 + q;
            const float bv = bs[colv];
            #pragma unroll
            for (int m = 0; m < 2; ++m) {
                #pragma unroll
                for (int r = 0; r < 4; ++r) {
                    const int row = e0 + wm * 32 + m * 16 + g * 4 + r;
                    if (row < nTotal) {
                        float v = acc[m][n][r] + ((row < bias_limit) ? bv : 0.f);
                        if (do_relu) v = fmaxf(v, 0.f);
                        out0[(size_t)row * DD + colv] = v;
                        if (out1) out1[(size_t)row * DD + colv] = v;
                    }
                }
            }
        }
    }
}

// ---------------------------------------------------------------------------
// bond v2: packed-split MFMA projection (proven correct in R6) -> hb tile in
// LDS -> R5's serial 16-edge run-length epilogue (proven cheap atomics).
//   hb = relu(edge_attr[perm] @ Wb + bb); 512 thr = 8 waves; 64 edges/tile.
// ---------------------------------------------------------------------------
__global__ __launch_bounds__(512, 2)
void bond_mfma2_kernel(const float* __restrict__ edge_attr,
                       const float* __restrict__ Wb, const float* __restrict__ bb,
                       const int* __restrict__ si, const int* __restrict__ perm,
                       float* __restrict__ h_head0,
                       float* __restrict__ sum_agg, int* __restrict__ max_agg,
                       int E, int N, int ntiles)
{
    // LDS: Ap 5120 | B1 10240 | B2 10240 | hb [64][132]f 33792 | bias 512 | ii 256 | pm 256
    __shared__ __align__(16) unsigned char SM[60416];
    char*  const Ap   = (char*)SM;
    char*  const B1   = (char*)SM + 5120;
    char*  const B2   = (char*)SM + 15360;
    float* const hb   = (float*)(SM + 25600);
    float* const bsh  = (float*)(SM + 59392);
    int*   const ii_s = (int*)(SM + 59904);
    int*   const pm_s = (int*)(SM + 60160);

    const int t = (int)threadIdx.x;

    // stage W packs once: B1 = [whi|wlo], B2 = [wlo|whi] along K (exact split)
    {
        const int col = t & 127;
        const int kq  = t >> 7;   // 0..3
        unsigned hq[4], lq[4];
        #pragma unroll
        for (int j = 0; j < 4; ++j) {
            const float w0 = Wb[(size_t)(kq * 4 + j) * DD + col];
            const unsigned hbv = bf16_rne(w0);
            hq[j] = hbv;
            lq[j] = bf16_rne(w0 - __uint_as_float(hbv << 16));
        }
        uint2 ph, pl;
        ph.x = hq[0] | (hq[1] << 16); ph.y = hq[2] | (hq[3] << 16);
        pl.x = lq[0] | (lq[1] << 16); pl.y = lq[2] | (lq[3] << 16);
        *(uint2*)(B1 + col * 80 + kq * 8)      = ph;
        *(uint2*)(B1 + col * 80 + 32 + kq * 8) = pl;
        *(uint2*)(B2 + col * 80 + kq * 8)      = pl;
        *(uint2*)(B2 + col * 80 + 32 + kq * 8) = ph;
        if (t < DD) bsh[t] = bb[t];
    }

    const int w  = t >> 6;
    const int l  = t & 63;
    const int wm = w >> 2;   // 0..1 : 32-row block
    const int wn = w & 3;    // 0..3 : 32-col block
    const int g  = l >> 4;
    const int q  = l & 15;

    const int per = (ntiles + (int)gridDim.x - 1) / (int)gridDim.x;
    const int t0 = blockIdx.x * per;
    const int t1 = min(t0 + per, ntiles);

    for (int tile = t0; tile < t1; ++tile) {
        const int e0 = tile * 64;
        __syncthreads();   // prev-tile readers done; fences W-packs on iter 0

        if (t < 64) {
            const int p = min(e0 + t, E - 1);
            ii_s[t] = si[p];
            pm_s[t] = perm[p];
        }
        if (t < 256) {
            const int row  = t >> 2;
            const int c4   = t & 3;
            const int p    = min(e0 + row, E - 1);
            const int orig = perm[p];
            const float4 a = *(const float4*)(edge_attr + (size_t)orig * 16 + c4 * 4);
            unsigned h4[4], l4[4];
            h4[0] = bf16_rne(a.x); l4[0] = bf16_rne(a.x - __uint_as_float(h4[0] << 16));
            h4[1] = bf16_rne(a.y); l4[1] = bf16_rne(a.y - __uint_as_float(h4[1] << 16));
            h4[2] = bf16_rne(a.z); l4[2] = bf16_rne(a.z - __uint_as_float(h4[2] << 16));
            h4[3] = bf16_rne(a.w); l4[3] = bf16_rne(a.w - __uint_as_float(h4[3] << 16));
            uint2 ph, pl;
            ph.x = h4[0] | (h4[1] << 16); ph.y = h4[2] | (h4[3] << 16);
            pl.x = l4[0] | (l4[1] << 16); pl.y = l4[2] | (l4[3] << 16);
            *(uint2*)(Ap + row * 80 + c4 * 8)      = ph;
            *(uint2*)(Ap + row * 80 + 32 + c4 * 8) = pl;
        }
        __syncthreads();

        // MFMA: hb tile 64x128
        f32x4 acc[2][2];
        const f32x4 zero = {0.f, 0.f, 0.f, 0.f};
        acc[0][0] = zero; acc[0][1] = zero; acc[1][0] = zero; acc[1][1] = zero;
        bf16x8 av[2];
        #pragma unroll
        for (int m = 0; m < 2; ++m)
            av[m] = *(const bf16x8*)(Ap + (wm * 32 + m * 16 + q) * 80 + g * 16);
        #pragma unroll
        for (int n = 0; n < 2; ++n) {
            const int colv = wn * 32 + n * 16 + q;
            const bf16x8 b1 = *(const bf16x8*)(B1 + colv * 80 + g * 16);
            const bf16x8 b2 = *(const bf16x8*)(B2 + colv * 80 + g * 16);
            #pragma unroll
            for (int m = 0; m < 2; ++m) {
                acc[m][n] = __builtin_amdgcn_mfma_f32_16x16x32_bf16(av[m], b1, acc[m][n], 0, 0, 0);
                acc[m][n] = __builtin_amdgcn_mfma_f32_16x16x32_bf16(av[m], b2, acc[m][n], 0, 0, 0);
            }
        }
        // spill tile to LDS (padded stride 132 -> <=2-way bank alias)
        #pragma unroll
        for (int n = 0; n < 2; ++n) {
            const int colv = wn * 32 + n * 16 + q;
            #pragma unroll
            for (int m = 0; m < 2; ++m)
                #pragma unroll
                for (int r = 0; r < 4; ++r)
                    hb[(wm * 32 + m * 16 + g * 4 + r) * 132 + colv] = acc[m][n][r];
        }
        __syncthreads();

        // R5-style serial run-length epilogue: seg = 16 consecutive edges
        {
            const int o   = t & 127;
            const int seg = t >> 7;   // 0..3
            const float bo = bsh[o];
            int curNode = ii_s[seg * 16];
            float rs = 0.f, rm = 0.f;
            #pragma unroll 4
            for (int j = 0; j < 16; ++j) {
                const int row = seg * 16 + j;
                float v = fmaxf(hb[row * 132 + o] + bo, 0.f);
                const int e = e0 + row;
                if (e < E) {
                    const int orig = pm_s[row];
                    if (orig < N) h_head0[(size_t)orig * DD + o] = v;
                } else {
                    v = 0.f;
                }
                const int gi = ii_s[row];
                if (gi != curNode) {
                    atomicAdd(&sum_agg[(size_t)curNode * DD + o], rs);
                    atomicMax(&max_agg[(size_t)curNode * DD + o], __float_as_int(rm));
                    curNode = gi; rs = v; rm = v;
                } else {
                    rs += v; rm = fmaxf(rm, v);
                }
            }
            atomicAdd(&sum_agg[(size_t)curNode * DD + o], rs);
            atomicMax(&max_agg[(size_t)curNode * DD + o], __float_as_int(rm));
        }
    }
}

// ---------------------------------------------------------------------------
// edge pass v3: v = relu(P[si]-Q[sj]); 4 waves x 128 edges; interior nodes
// (strictly between a wave-chunk's first/last node) are exclusively owned ->
// plain coalesced stores; only boundary nodes use atomics.
// ---------------------------------------------------------------------------
__global__ __launch_bounds__(256)
void edge_pass_kernel(const float* __restrict__ PQ,
                      const int* __restrict__ si, const int* __restrict__ sj,
                      const int* __restrict__ perm,
                      float* __restrict__ head_next, int store_head,
                      float* __restrict__ sum_agg, int* __restrict__ max_agg,
                      int E, int N)
{
    __shared__ int si_s[CE], sj_s[CE], pm_s[CE];
    const int p0b = blockIdx.x * CE;
    if (p0b >= E) return;
    const int t = (int)threadIdx.x;
    for (int i = t; i < CE; i += 256) {
        const int p = min(p0b + i, E - 1);
        si_s[i] = si[p];
        sj_s[i] = sj[p];
        pm_s[i] = perm[p];
    }
    __syncthreads();

    const int w    = t >> 6;
    const int lane = t & 63;
    const int c    = lane * 2;
    const int q0   = w * 128;
    const int pg0  = p0b + q0;
    if (pg0 >= E) return;

    const int firstNode = si_s[q0];
    const int lastNode  = si_s[q0 + 127];

    const float* __restrict__ Qbase = PQ + (size_t)N * DD + c;

    float2 qa = *(const float2*)(Qbase + (size_t)sj_s[q0 + 0] * DD);
    float2 qb = *(const float2*)(Qbase + (size_t)sj_s[q0 + 1] * DD);
    float2 qc = *(const float2*)(Qbase + (size_t)sj_s[q0 + 2] * DD);
    float2 qd = *(const float2*)(Qbase + (size_t)sj_s[q0 + 3] * DD);

    int curNode = firstNode;
    float2 Pi = *(const float2*)(PQ + (size_t)curNode * DD + c);
    float2 rs = make_float2(0.f, 0.f), rm = make_float2(0.f, 0.f);

    #define EP_FLUSH()                                                           \
    {                                                                            \
        if (curNode == firstNode || curNode == lastNode) {                       \
            atomicAdd(&sum_agg[(size_t)curNode * DD + c],     rs.x);             \
            atomicAdd(&sum_agg[(size_t)curNode * DD + c + 1], rs.y);             \
            atomicMax(&max_agg[(size_t)curNode * DD + c],     __float_as_int(rm.x)); \
            atomicMax(&max_agg[(size_t)curNode * DD + c + 1], __float_as_int(rm.y)); \
        } else {                                                                 \
            *(float2*)(sum_agg + (size_t)curNode * DD + c) = rs;                 \
            *(int2*)(max_agg + (size_t)curNode * DD + c) =                       \
                make_int2(__float_as_int(rm.x), __float_as_int(rm.y));           \
        }                                                                        \
    }

    #define EP_STEP(K, QREG)                                                     \
    {                                                                            \
        const int kk = (K);                                                      \
        const int i = si_s[q0 + kk];                                             \
        if (i != curNode) {                                                      \
            EP_FLUSH();                                                          \
            curNode = i;                                                         \
            Pi = *(const float2*)(PQ + (size_t)i * DD + c);                      \
            rs = make_float2(0.f, 0.f);                                          \
            rm = make_float2(0.f, 0.f);                                          \
        }                                                                        \
        float2 v;                                                                \
        v.x = fmaxf(Pi.x - QREG.x, 0.f);                                         \
        v.y = fmaxf(Pi.y - QREG.y, 0.f);                                         \
        if (pg0 + kk >= E) { v.x = 0.f; v.y = 0.f; }                             \
        rs.x += v.x; rs.y += v.y;                                                \
        rm.x = fmaxf(rm.x, v.x); rm.y = fmaxf(rm.y, v.y);                        \
        if (store_head && (pg0 + kk) < E) {                                      \
            const int orig = pm_s[q0 + kk];                                      \
            if (orig < N) *(float2*)(head_next + (size_t)orig * DD + c) = v;     \
        }                                                                        \
        if (kk + 4 < 128)                                                        \
            QREG = *(const float2*)(Qbase + (size_t)sj_s[q0 + kk + 4] * DD);     \
    }

    #pragma unroll 8
    for (int k = 0; k < 128; k += 4) {
        EP_STEP(k + 0, qa);
        EP_STEP(k + 1, qb);
        EP_STEP(k + 2, qc);
        EP_STEP(k + 3, qd);
    }
    EP_FLUSH();   // final run: curNode == lastNode -> atomic path
    #undef EP_STEP
    #undef EP_FLUSH
}

// ---------------------------------------------------------------------------
// final: out = [ha, x_proj] @ W_lin + b_lin via split-bf16 MFMA, K=256
// (unchanged from R7)
// ---------------------------------------------------------------------------
__global__ __launch_bounds__(512, 2)
void final_mfma_kernel(const float* __restrict__ h, const float* __restrict__ sum_agg,
                       const int* __restrict__ max_agg, const float* __restrict__ xp,
                       const float* __restrict__ Wl, const float* __restrict__ bl,
                       float* __restrict__ out, int N)
{
    __shared__ __align__(16) unsigned char SM[65808];
    char*  const Whi = (char*)SM;
    char*  const Wlo = (char*)SM + 32768;
    float* const Wf  = (float*)SM;
    float* const bs  = (float*)(SM + 65536);

    const int t = (int)threadIdx.x;
    {
        const float4* Wg = (const float4*)Wl;
        float4* Wd = (float4*)Wf;
        #pragma unroll
        for (int i = 0; i < 8; ++i) Wd[t + i * 512] = Wg[t + i * 512];
        if (t < 64) bs[t] = bl[t];
    }
    __syncthreads();
    {
        const int col = t & 63;
        const int kb  = (t >> 6) * 32;
        float v[32];
        #pragma unroll
        for (int j = 0; j < 32; ++j) v[j] = Wf[(size_t)(kb + j) * 64 + col];
        __syncthreads();
        #pragma unroll
        for (int c = 0; c < 4; ++c) {
            unsigned h8[8], l8[8];
            #pragma unroll
            for (int j = 0; j < 8; ++j) {
                const float w0 = v[c * 8 + j];
                const unsigned hb = bf16_rne(w0);
                h8[j] = hb;
                l8[j] = bf16_rne(w0 - __uint_as_float(hb << 16));
            }
            uint4 ph, pl;
            ph.x = h8[0] | (h8[1] << 16); ph.y = h8[2] | (h8[3] << 16);
            ph.z = h8[4] | (h8[5] << 16); ph.w = h8[6] | (h8[7] << 16);
            pl.x = l8[0] | (l8[1] << 16); pl.y = l8[2] | (l8[3] << 16);
            pl.z = l8[4] | (l8[5] << 16); pl.w = l8[6] | (l8[7] << 16);
            const int off = (col * 512 + (kb + c * 8) * 2) ^ ((col & 7) << 4);
            *(uint4*)(Whi + off) = ph;
            *(uint4*)(Wlo + off) = pl;
        }
    }
    __syncthreads();

    const int w  = t >> 6;
    const int l  = t & 63;
    const int wm = w >> 1;
    const int wn = w & 1;
    const int g  = l >> 4;
    const int q  = l & 15;
    const int r0 = (int)blockIdx.x * 128;

    f32x4 acc[2][2];
    const f32x4 zero = {0.f, 0.f, 0.f, 0.f};
    acc[0][0] = zero; acc[0][1] = zero; acc[1][0] = zero; acc[1][1] = zero;

    #pragma unroll
    for (int ks = 0; ks < 8; ++ks) {
        const int kf = (ks & 3) * 32 + g * 8;
        bf16x8 ah[2], al[2];
        #pragma unroll
        for (int m = 0; m < 2; ++m) {
            const int rr = min(r0 + wm * 32 + m * 16 + q, N - 1);
            float d[8];
            if (ks < 4) {
                const float* ph = h       + (size_t)rr * DD + kf;
                const float* ps = sum_agg + (size_t)rr * DD + kf;
                const int*   pm = max_agg + (size_t)rr * DD + kf;
                const float4 a0 = *(const float4*)ph;
                const float4 a1 = *(const float4*)(ph + 4);
                const float4 s0 = *(const float4*)ps;
                const float4 s1 = *(const float4*)(ps + 4);
                const int4   i0 = *(const int4*)pm;
                const int4   i1 = *(const int4*)(pm + 4);
                d[0] = a0.x * a0.x * s0.x * __int_as_float(i0.x);
                d[1] = a0.y * a0.y * s0.y * __int_as_float(i0.y);
                d[2] = a0.z * a0.z * s0.z * __int_as_float(i0.z);
                d[3] = a0.w * a0.w * s0.w * __int_as_float(i0.w);
                d[4] = a1.x * a1.x * s1.x * __int_as_float(i1.x);
                d[5] = a1.y * a1.y * s1.y * __int_as_float(i1.y);
                d[6] = a1.z * a1.z * s1.z * __int_as_float(i1.z);
                d[7] = a1.w * a1.w * s1.w * __int_as_float(i1.w);
            } else {
                const float* pa = xp + (size_t)rr * DD + kf;
                const float4 a0 = *(const float4*)pa;
                const float4 a1 = *(const float4*)(pa + 4);
                d[0] = a0.x; d[1] = a0.y; d[2] = a0.z; d[3] = a0.w;
                d[4] = a1.x; d[5] = a1.y; d[6] = a1.z; d[7] = a1.w;
            }
            unsigned h8[8], l8[8];
            #pragma unroll
            for (int j = 0; j < 8; ++j) {
                const unsigned hb = bf16_rne(d[j]);
                h8[j] = hb;
                l8[j] = bf16_rne(d[j] - __uint_as_float(hb << 16));
            }
            uint4 ph2, pl2;
            ph2.x = h8[0] | (h8[1] << 16); ph2.y = h8[2] | (h8[3] << 16);
            ph2.z = h8[4] | (h8[5] << 16); ph2.w = h8[6] | (h8[7] << 16);
            pl2.x = l8[0] | (l8[1] << 16); pl2.y = l8[2] | (l8[3] << 16);
            pl2.z = l8[4] | (l8[5] << 16); pl2.w = l8[6] | (l8[7] << 16);
            ah[m] = *(bf16x8*)&ph2;
            al[m] = *(bf16x8*)&pl2;
        }
        bf16x8 bh[2], blo[2];
        #pragma unroll
        for (int n = 0; n < 2; ++n) {
            const int colv = wn * 32 + n * 16 + q;
            const int off = (colv * 512 + ks * 64 + g * 16) ^ ((colv & 7) << 4);
            bh[n]  = *(const bf16x8*)(Whi + off);
            blo[n] = *(const bf16x8*)(Wlo + off);
        }
        #pragma unroll
        for (int m = 0; m < 2; ++m)
            #pragma unroll
            for (int n = 0; n < 2; ++n) {
                acc[m][n] = __builtin_amdgcn_mfma_f32_16x16x32_bf16(ah[m], bh[n],  acc[m][n], 0, 0, 0);
                acc[m][n] = __builtin_amdgcn_mfma_f32_16x16x32_bf16(ah[m], blo[n], acc[m][n], 0, 0, 0);
                acc[m][n] = __builtin_amdgcn_mfma_f32_16x16x32_bf16(al[m], bh[n],  acc[m][n], 0, 0, 0);
            }
    }

    #pragma unroll
    for (int n = 0; n < 2; ++n) {
        const int colv = wn * 32 + n * 16 + q;
        const float bv = bs[colv];
        #pragma unroll
        for (int m = 0; m < 2; ++m) {
            #pragma unroll
            for (int r = 0; r < 4; ++r) {
                const int row = r0 + wm * 32 + m * 16 + g * 4 + r;
                if (row < N) out[(size_t)row * 64 + colv] = acc[m][n][r] + bv;
            }
        }
    }
}

// ---------------------------------------------------------------------------
extern "C" void kernel_launch(void* const* d_in, const int* in_sizes, int n_in,
                              void* d_out, int out_size, void* d_ws, size_t ws_size,
                              hipStream_t stream)
{
    const float* x         = (const float*)d_in[0];
    const int*   edge_idx  = (const int*)d_in[1];
    const float* edge_attr = (const float*)d_in[2];
    const float* W_atom    = (const float*)d_in[3];
    const float* b_atom    = (const float*)d_in[4];
    const float* W_bond    = (const float*)d_in[5];
    const float* b_bond    = (const float*)d_in[6];
    const float* W_seq     = (const float*)d_in[7];
    const float* b_seq     = (const float*)d_in[8];
    const float* W_lin     = (const float*)d_in[9];
    const float* b_lin     = (const float*)d_in[10];
    float* out = (float*)d_out;

    const int N = in_sizes[0] / DD;   // 30000
    const int E = in_sizes[1] / 2;    // 480000
    const int* idx_i = edge_idx;
    const int* idx_j = edge_idx + E;

    const size_t nd = (size_t)N * DD;
    float* ws      = (float*)d_ws;
    float* x_proj  = ws;
    float* h_atom  = x_proj + nd;
    float* head    = h_atom + nd;
    float* sum_agg = head + nd;
    int*   max_agg = (int*)(sum_agg + nd);
    float* PQ      = (float*)(max_agg + nd);   // 2N x 128
    int*   cnt     = (int*)(PQ + 2 * nd);
    int*   cursor  = cnt + N;
    int*   bsum    = cursor + N;
    int*   perm    = bsum + 256;
    int*   si      = perm + E;
    int*   sj      = si + E;

    // ---- counting sort of edges by idx_i ----
    hipMemsetAsync(cnt, 0, (size_t)N * 4, stream);
    hist_kernel<<<(E + 255) / 256, 256, 0, stream>>>(idx_i, cnt, E);
    const int nb_scan = (N + SCB - 1) / SCB;
    scan1_kernel<<<nb_scan, SCB, 0, stream>>>(cnt, cursor, bsum, N);
    scan2_kernel<<<1, SCB, 0, stream>>>(bsum, nb_scan);
    scan3_kernel<<<nb_scan, SCB, 0, stream>>>(cursor, bsum, N);
    scatter_kernel<<<(E + 255) / 256, 256, 0, stream>>>(idx_i, idx_j, cursor, perm, si, sj, E);

    hipMemsetAsync(sum_agg, 0, nd * 4, stream);
    hipMemsetAsync(max_agg, 0, nd * 4, stream);

    // node projection via MFMA: x_proj = h_atom = relu(x @ W_atom + b_atom)
    const int ntiles_n = (N + 127) / 128;
    gemm128_mfma_kernel<<<min(ntiles_n, 256), 1024, 0, stream>>>(
        (float*)x, x, N, N, W_atom, b_atom, N, 1, 0, nullptr, nullptr,
        x_proj, h_atom, ntiles_n);

    // bond projection + layer-0 aggregation
    const int ntiles_b = (E + 63) / 64;
    bond_mfma2_kernel<<<1024, 512, 0, stream>>>(edge_attr, W_bond, b_bond,
                                                si, perm, head,
                                                sum_agg, max_agg, E, N, ntiles_b);

    const int ntiles_pq = (2 * N + 127) / 128;
    const int ep_blocks = (E + CE - 1) / CE;
    for (int l = 0; l < 3; ++l) {
        gemm128_mfma_kernel<<<256, 1024, 0, stream>>>(
            h_atom, head, N, 2 * N, W_seq + (size_t)l * DD * DD,
            b_seq + (size_t)l * DD, N, 0, 1, sum_agg, max_agg,
            PQ, nullptr, ntiles_pq);
        edge_pass_kernel<<<ep_blocks, 256, 0, stream>>>(
            PQ, si, sj, perm, head, (l < 2) ? 1 : 0, sum_agg, max_agg, E, N);
    }

    final_mfma_kernel<<<(N + 127) / 128, 512, 0, stream>>>(
        h_atom, sum_agg, (const int*)max_agg, x_proj, W_lin, b_lin, out, N);
}

// Round 9
// 440.103 us; speedup vs baseline: 1.0367x; 1.0367x over previous
//
#include <hip/hip_runtime.h>
#include <hip/hip_bf16.h>

#define DD 128   // hidden dim
#define SCB 256  // scan block size
#define CE  512  // edges per block in edge_pass (4 waves x 128)

typedef __attribute__((ext_vector_type(8))) short bf16x8;
typedef __attribute__((ext_vector_type(4))) float f32x4;

__device__ __forceinline__ unsigned bf16_rne(float f) {
    unsigned u = __float_as_uint(f);
    return (u + 0x7fffu + ((u >> 16) & 1u)) >> 16;
}

// ---------------------------------------------------------------------------
// counting-sort preprocessing (sort edges by idx_i)
// ---------------------------------------------------------------------------
__global__ __launch_bounds__(256)
void hist_kernel(const int* __restrict__ idx_i, int* __restrict__ cnt, int E)
{
    const int e = blockIdx.x * 256 + threadIdx.x;
    if (e < E) atomicAdd(&cnt[idx_i[e]], 1);
}

__global__ __launch_bounds__(SCB)
void scan1_kernel(const int* __restrict__ cnt, int* __restrict__ exc,
                  int* __restrict__ bsum, int n)
{
    __shared__ int s[SCB];
    const int i = blockIdx.x * SCB + (int)threadIdx.x;
    const int v = (i < n) ? cnt[i] : 0;
    s[threadIdx.x] = v;
    __syncthreads();
    #pragma unroll
    for (int off = 1; off < SCB; off <<= 1) {
        int t = (threadIdx.x >= off) ? s[threadIdx.x - off] : 0;
        __syncthreads();
        s[threadIdx.x] += t;
        __syncthreads();
    }
    if (i < n) exc[i] = s[threadIdx.x] - v;
    if (threadIdx.x == SCB - 1) bsum[blockIdx.x] = s[threadIdx.x];
}

__global__ __launch_bounds__(SCB)
void scan2_kernel(int* __restrict__ bsum, int nb)
{
    __shared__ int s[SCB];
    const int v = (threadIdx.x < nb) ? bsum[threadIdx.x] : 0;
    s[threadIdx.x] = v;
    __syncthreads();
    #pragma unroll
    for (int off = 1; off < SCB; off <<= 1) {
        int t = (threadIdx.x >= off) ? s[threadIdx.x - off] : 0;
        __syncthreads();
        s[threadIdx.x] += t;
        __syncthreads();
    }
    if (threadIdx.x < nb) bsum[threadIdx.x] = s[threadIdx.x] - v;
}

__global__ __launch_bounds__(SCB)
void scan3_kernel(int* __restrict__ exc, const int* __restrict__ bsum, int n)
{
    const int i = blockIdx.x * SCB + (int)threadIdx.x;
    if (i < n) exc[i] += bsum[i >> 8];
}

__global__ __launch_bounds__(256)
void scatter_kernel(const int* __restrict__ idx_i, const int* __restrict__ idx_j,
                    int* __restrict__ cursor, int* __restrict__ perm,
                    int* __restrict__ si, int* __restrict__ sj, int E)
{
    const int e = blockIdx.x * 256 + threadIdx.x;
    if (e < E) {
        const int n = idx_i[e];
        const int p = atomicAdd(&cursor[n], 1);
        perm[p] = e;
        si[p] = n;
        sj[p] = idx_j[e];
    }
}

// ---------------------------------------------------------------------------
// generic 128-K split-bf16 MFMA GEMM with optional fused node-update
// ---------------------------------------------------------------------------
__global__ __launch_bounds__(1024)
void gemm128_mfma_kernel(float* __restrict__ A0, const float* __restrict__ A1,
                         int nA, int nTotal,
                         const float* __restrict__ W, const float* __restrict__ bias,
                         int bias_limit, int do_relu, int update,
                         float* __restrict__ sum_agg, int* __restrict__ max_agg,
                         float* __restrict__ out0, float* __restrict__ out1,
                         int ntiles)
{
    __shared__ __align__(16) unsigned char SM[131584];
    char*  const Whi = (char*)SM;
    char*  const Wlo = (char*)SM + 32768;
    char*  const Ahi = (char*)SM + 65536;
    char*  const Alo = (char*)SM + 98304;
    float* const Wf  = (float*)(SM + 65536);
    float* const bs  = (float*)(SM + 131072);

    const int t = (int)threadIdx.x;

    {
        const float4* Wg = (const float4*)W;
        float4* Wd = (float4*)Wf;
        #pragma unroll
        for (int i = 0; i < 4; ++i) Wd[t + i * 1024] = Wg[t + i * 1024];
        if (t < DD) bs[t] = bias ? bias[t] : 0.f;
    }
    __syncthreads();
    {
        const int col = t >> 3;
        const int kb  = (t & 7) * 16;
        unsigned h16[16], l16[16];
        #pragma unroll
        for (int j = 0; j < 16; ++j) {
            const float w = Wf[(size_t)(kb + j) * DD + col];
            const unsigned hb = bf16_rne(w);
            const float hf = __uint_as_float(hb << 16);
            h16[j] = hb;
            l16[j] = bf16_rne(w - hf);
        }
        #pragma unroll
        for (int c = 0; c < 2; ++c) {
            uint4 ph, pl;
            ph.x = h16[c*8+0] | (h16[c*8+1] << 16);
            ph.y = h16[c*8+2] | (h16[c*8+3] << 16);
            ph.z = h16[c*8+4] | (h16[c*8+5] << 16);
            ph.w = h16[c*8+6] | (h16[c*8+7] << 16);
            pl.x = l16[c*8+0] | (l16[c*8+1] << 16);
            pl.y = l16[c*8+2] | (l16[c*8+3] << 16);
            pl.z = l16[c*8+4] | (l16[c*8+5] << 16);
            pl.w = l16[c*8+6] | (l16[c*8+7] << 16);
            const int off = ((col * 256 + (kb + c * 8) * 2)) ^ ((col & 7) << 4);
            *(uint4*)(Whi + off) = ph;
            *(uint4*)(Wlo + off) = pl;
        }
    }

    const int w  = t >> 6;
    const int l  = t & 63;
    const int wm = w >> 2;
    const int wn = w & 3;
    const int g  = l >> 4;
    const int q  = l & 15;

    for (int tile = blockIdx.x; tile < ntiles; tile += gridDim.x) {
        const int e0 = tile * 128;
        __syncthreads();

        #pragma unroll
        for (int i = 0; i < 2; ++i) {
            const int task = t + i * 1024;
            const int row  = task >> 4;
            const int c    = task & 15;
            const int rr = min(e0 + row, nTotal - 1);
            float d[8];
            if (rr < nA) {
                float* ph0 = A0 + (size_t)rr * DD + c * 8;
                const float4 a0 = *(const float4*)ph0;
                const float4 a1 = *(const float4*)(ph0 + 4);
                if (update) {
                    float* sp = sum_agg + (size_t)rr * DD + c * 8;
                    int*   mp = max_agg + (size_t)rr * DD + c * 8;
                    const float4 s0 = *(const float4*)sp;
                    const float4 s1 = *(const float4*)(sp + 4);
                    const int4   m0 = *(const int4*)mp;
                    const int4   m1 = *(const int4*)(mp + 4);
                    d[0] = a0.x * s0.x * __int_as_float(m0.x);
                    d[1] = a0.y * s0.y * __int_as_float(m0.y);
                    d[2] = a0.z * s0.z * __int_as_float(m0.z);
                    d[3] = a0.w * s0.w * __int_as_float(m0.w);
                    d[4] = a1.x * s1.x * __int_as_float(m1.x);
                    d[5] = a1.y * s1.y * __int_as_float(m1.y);
                    d[6] = a1.z * s1.z * __int_as_float(m1.z);
                    d[7] = a1.w * s1.w * __int_as_float(m1.w);
                    *(float4*)ph0       = make_float4(d[0], d[1], d[2], d[3]);
                    *(float4*)(ph0 + 4) = make_float4(d[4], d[5], d[6], d[7]);
                    *(float4*)sp       = make_float4(0.f, 0.f, 0.f, 0.f);
                    *(float4*)(sp + 4) = make_float4(0.f, 0.f, 0.f, 0.f);
                    *(int4*)mp       = make_int4(0, 0, 0, 0);
                    *(int4*)(mp + 4) = make_int4(0, 0, 0, 0);
                } else {
                    d[0] = a0.x; d[1] = a0.y; d[2] = a0.z; d[3] = a0.w;
                    d[4] = a1.x; d[5] = a1.y; d[6] = a1.z; d[7] = a1.w;
                }
            } else {
                const float* pa = A1 + (size_t)(rr - nA) * DD + c * 8;
                const float4 a0 = *(const float4*)pa;
                const float4 a1 = *(const float4*)(pa + 4);
                d[0] = a0.x; d[1] = a0.y; d[2] = a0.z; d[3] = a0.w;
                d[4] = a1.x; d[5] = a1.y; d[6] = a1.z; d[7] = a1.w;
            }
            unsigned h8[8], l8[8];
            #pragma unroll
            for (int j = 0; j < 8; ++j) {
                const unsigned hb = bf16_rne(d[j]);
                const float hf = __uint_as_float(hb << 16);
                h8[j] = hb;
                l8[j] = bf16_rne(d[j] - hf);
            }
            uint4 ph, pl;
            ph.x = h8[0] | (h8[1] << 16);
            ph.y = h8[2] | (h8[3] << 16);
            ph.z = h8[4] | (h8[5] << 16);
            ph.w = h8[6] | (h8[7] << 16);
            pl.x = l8[0] | (l8[1] << 16);
            pl.y = l8[2] | (l8[3] << 16);
            pl.z = l8[4] | (l8[5] << 16);
            pl.w = l8[6] | (l8[7] << 16);
            const int off = ((row * 256 + c * 16)) ^ ((row & 7) << 4);
            *(uint4*)(Ahi + off) = ph;
            *(uint4*)(Alo + off) = pl;
        }
        __syncthreads();

        f32x4 acc[2][2];
        const f32x4 zero = {0.f, 0.f, 0.f, 0.f};
        acc[0][0] = zero; acc[0][1] = zero; acc[1][0] = zero; acc[1][1] = zero;

        #pragma unroll
        for (int ks = 0; ks < 4; ++ks) {
            const int kbyte = ks * 64 + g * 16;
            bf16x8 ah[2], al[2], bh[2], bl[2];
            #pragma unroll
            for (int m = 0; m < 2; ++m) {
                const int row = wm * 32 + m * 16 + q;
                const int off = (row * 256 + kbyte) ^ ((row & 7) << 4);
                ah[m] = *(const bf16x8*)(Ahi + off);
                al[m] = *(const bf16x8*)(Alo + off);
            }
            #pragma unroll
            for (int n = 0; n < 2; ++n) {
                const int colv = wn * 32 + n * 16 + q;
                const int off = (colv * 256 + kbyte) ^ ((colv & 7) << 4);
                bh[n] = *(const bf16x8*)(Whi + off);
                bl[n] = *(const bf16x8*)(Wlo + off);
            }
            #pragma unroll
            for (int m = 0; m < 2; ++m)
                #pragma unroll
                for (int n = 0; n < 2; ++n)
                    acc[m][n] = __builtin_amdgcn_mfma_f32_16x16x32_bf16(ah[m], bh[n], acc[m][n], 0, 0, 0);
            #pragma unroll
            for (int m = 0; m < 2; ++m)
                #pragma unroll
                for (int n = 0; n < 2; ++n)
                    acc[m][n] = __builtin_amdgcn_mfma_f32_16x16x32_bf16(ah[m], bl[n], acc[m][n], 0, 0, 0);
            #pragma unroll
            for (int m = 0; m < 2; ++m)
                #pragma unroll
                for (int n = 0; n < 2; ++n)
                    acc[m][n] = __builtin_amdgcn_mfma_f32_16x16x32_bf16(al[m], bh[n], acc[m][n], 0, 0, 0);
        }

        #pragma unroll
        for (int n = 0; n < 2; ++n) {
            const int colv = wn * 32 + n * 16 + q;
            const float bv = bs[colv];
            #pragma unroll
            for (int m = 0; m < 2; ++m) {
                #pragma unroll
                for (int r = 0; r < 4; ++r) {
                    const int row = e0 + wm * 32 + m * 16 + g * 4 + r;
                    if (row < nTotal) {
                        float v = acc[m][n][r] + ((row < bias_limit) ? bv : 0.f);
                        if (do_relu) v = fmaxf(v, 0.f);
                        out0[(size_t)row * DD + colv] = v;
                        if (out1) out1[(size_t)row * DD + colv] = v;
                    }
                }
            }
        }
    }
}

// ---------------------------------------------------------------------------
// bond projection + layer-0 aggregation over SORTED edges
// (R5-proven VALU path, 72 us — beats both MFMA variants, which are
//  barrier/atomic-bound: R6 = 307 us, R8 = 92 us)
// ---------------------------------------------------------------------------
__global__ __launch_bounds__(256)
void bond_proj_agg_kernel(const float* __restrict__ edge_attr,
                          const float* __restrict__ Wb, const float* __restrict__ bb,
                          const int* __restrict__ si, const int* __restrict__ perm,
                          float* __restrict__ h_head0,
                          float* __restrict__ sum_agg, int* __restrict__ max_agg,
                          int E, int N)
{
    __shared__ float Ws[16 * DD];
    __shared__ float bs2[DD];
    __shared__ __align__(16) float ea_s[32][16];
    __shared__ int ii2[32], pm2[32];

    for (int idx = (int)threadIdx.x; idx < 16 * DD; idx += 256) Ws[idx] = Wb[idx];
    if (threadIdx.x < DD) bs2[threadIdx.x] = bb[threadIdx.x];

    const int p0 = blockIdx.x * 32;
    {
        const int t = (int)threadIdx.x;
        const int row = t >> 3;
        const int k2 = (t & 7) * 2;
        const int ppc = min(p0 + row, E - 1);
        const int orig = perm[ppc];
        const float2 v2 = *(const float2*)(edge_attr + (size_t)orig * 16 + k2);
        ea_s[row][k2] = v2.x;
        ea_s[row][k2 + 1] = v2.y;
        if (t < 32) {
            const int q = min(p0 + t, E - 1);
            ii2[t] = si[q];
            pm2[t] = perm[q];
        }
    }
    __syncthreads();

    const int o    = threadIdx.x & 127;
    const int half = threadIdx.x >> 7;

    float wcol[16];
    #pragma unroll
    for (int k = 0; k < 16; ++k) wcol[k] = Ws[k * DD + o];
    const float bo = bs2[o];

    int curNode = ii2[half * 16];
    float rs = 0.f, rm = 0.f;
    #pragma unroll 4
    for (int j = 0; j < 16; ++j) {
        const int row = half * 16 + j;
        const float4* ear = (const float4*)(&ea_s[row][0]);
        const float4 q0 = ear[0], q1 = ear[1], q2 = ear[2], q3 = ear[3];
        float acc = bo;
        acc = fmaf(q0.x, wcol[ 0], acc);
        acc = fmaf(q0.y, wcol[ 1], acc);
        acc = fmaf(q0.z, wcol[ 2], acc);
        acc = fmaf(q0.w, wcol[ 3], acc);
        acc = fmaf(q1.x, wcol[ 4], acc);
        acc = fmaf(q1.y, wcol[ 5], acc);
        acc = fmaf(q1.z, wcol[ 6], acc);
        acc = fmaf(q1.w, wcol[ 7], acc);
        acc = fmaf(q2.x, wcol[ 8], acc);
        acc = fmaf(q2.y, wcol[ 9], acc);
        acc = fmaf(q2.z, wcol[10], acc);
        acc = fmaf(q2.w, wcol[11], acc);
        acc = fmaf(q3.x, wcol[12], acc);
        acc = fmaf(q3.y, wcol[13], acc);
        acc = fmaf(q3.z, wcol[14], acc);
        acc = fmaf(q3.w, wcol[15], acc);
        float v = fmaxf(acc, 0.f);
        const int pe = p0 + row;
        if (pe < E) {
            const int orig = pm2[row];
            if (orig < N) h_head0[(size_t)orig * DD + o] = v;
        } else {
            v = 0.f;
        }
        const int gi = ii2[row];
        if (gi != curNode) {
            atomicAdd(&sum_agg[(size_t)curNode * DD + o], rs);
            atomicMax(&max_agg[(size_t)curNode * DD + o], __float_as_int(rm));
            curNode = gi; rs = v; rm = v;
        } else {
            rs += v; rm = fmaxf(rm, v);
        }
    }
    atomicAdd(&sum_agg[(size_t)curNode * DD + o], rs);
    atomicMax(&max_agg[(size_t)curNode * DD + o], __float_as_int(rm));
}

// ---------------------------------------------------------------------------
// edge pass v3: v = relu(P[si]-Q[sj]); 4 waves x 128 edges; interior nodes
// (strictly between a wave-chunk's first/last node) are exclusively owned ->
// plain coalesced stores; only boundary nodes use atomics.
// ---------------------------------------------------------------------------
__global__ __launch_bounds__(256)
void edge_pass_kernel(const float* __restrict__ PQ,
                      const int* __restrict__ si, const int* __restrict__ sj,
                      const int* __restrict__ perm,
                      float* __restrict__ head_next, int store_head,
                      float* __restrict__ sum_agg, int* __restrict__ max_agg,
                      int E, int N)
{
    __shared__ int si_s[CE], sj_s[CE], pm_s[CE];
    const int p0b = blockIdx.x * CE;
    if (p0b >= E) return;
    const int t = (int)threadIdx.x;
    for (int i = t; i < CE; i += 256) {
        const int p = min(p0b + i, E - 1);
        si_s[i] = si[p];
        sj_s[i] = sj[p];
        pm_s[i] = perm[p];
    }
    __syncthreads();

    const int w    = t >> 6;
    const int lane = t & 63;
    const int c    = lane * 2;
    const int q0   = w * 128;
    const int pg0  = p0b + q0;
    if (pg0 >= E) return;

    const int firstNode = si_s[q0];
    const int lastNode  = si_s[q0 + 127];

    const float* __restrict__ Qbase = PQ + (size_t)N * DD + c;

    float2 qa = *(const float2*)(Qbase + (size_t)sj_s[q0 + 0] * DD);
    float2 qb = *(const float2*)(Qbase + (size_t)sj_s[q0 + 1] * DD);
    float2 qc = *(const float2*)(Qbase + (size_t)sj_s[q0 + 2] * DD);
    float2 qd = *(const float2*)(Qbase + (size_t)sj_s[q0 + 3] * DD);

    int curNode = firstNode;
    float2 Pi = *(const float2*)(PQ + (size_t)curNode * DD + c);
    float2 rs = make_float2(0.f, 0.f), rm = make_float2(0.f, 0.f);

    #define EP_FLUSH()                                                           \
    {                                                                            \
        if (curNode == firstNode || curNode == lastNode) {                       \
            atomicAdd(&sum_agg[(size_t)curNode * DD + c],     rs.x);             \
            atomicAdd(&sum_agg[(size_t)curNode * DD + c + 1], rs.y);             \
            atomicMax(&max_agg[(size_t)curNode * DD + c],     __float_as_int(rm.x)); \
            atomicMax(&max_agg[(size_t)curNode * DD + c + 1], __float_as_int(rm.y)); \
        } else {                                                                 \
            *(float2*)(sum_agg + (size_t)curNode * DD + c) = rs;                 \
            *(int2*)(max_agg + (size_t)curNode * DD + c) =                       \
                make_int2(__float_as_int(rm.x), __float_as_int(rm.y));           \
        }                                                                        \
    }

    #define EP_STEP(K, QREG)                                                     \
    {                                                                            \
        const int kk = (K);                                                      \
        const int i = si_s[q0 + kk];                                             \
        if (i != curNode) {                                                      \
            EP_FLUSH();                                                          \
            curNode = i;                                                         \
            Pi = *(const float2*)(PQ + (size_t)i * DD + c);                      \
            rs = make_float2(0.f, 0.f);                                          \
            rm = make_float2(0.f, 0.f);                                          \
        }                                                                        \
        float2 v;                                                                \
        v.x = fmaxf(Pi.x - QREG.x, 0.f);                                         \
        v.y = fmaxf(Pi.y - QREG.y, 0.f);                                         \
        if (pg0 + kk >= E) { v.x = 0.f; v.y = 0.f; }                             \
        rs.x += v.x; rs.y += v.y;                                                \
        rm.x = fmaxf(rm.x, v.x); rm.y = fmaxf(rm.y, v.y);                        \
        if (store_head && (pg0 + kk) < E) {                                      \
            const int orig = pm_s[q0 + kk];                                      \
            if (orig < N) *(float2*)(head_next + (size_t)orig * DD + c) = v;     \
        }                                                                        \
        if (kk + 4 < 128)                                                        \
            QREG = *(const float2*)(Qbase + (size_t)sj_s[q0 + kk + 4] * DD);     \
    }

    #pragma unroll 8
    for (int k = 0; k < 128; k += 4) {
        EP_STEP(k + 0, qa);
        EP_STEP(k + 1, qb);
        EP_STEP(k + 2, qc);
        EP_STEP(k + 3, qd);
    }
    EP_FLUSH();   // final run: curNode == lastNode -> atomic path
    #undef EP_STEP
    #undef EP_FLUSH
}

// ---------------------------------------------------------------------------
// final: out = [ha, x_proj] @ W_lin + b_lin via split-bf16 MFMA, K=256
// ---------------------------------------------------------------------------
__global__ __launch_bounds__(512, 2)
void final_mfma_kernel(const float* __restrict__ h, const float* __restrict__ sum_agg,
                       const int* __restrict__ max_agg, const float* __restrict__ xp,
                       const float* __restrict__ Wl, const float* __restrict__ bl,
                       float* __restrict__ out, int N)
{
    __shared__ __align__(16) unsigned char SM[65808];
    char*  const Whi = (char*)SM;
    char*  const Wlo = (char*)SM + 32768;
    float* const Wf  = (float*)SM;
    float* const bs  = (float*)(SM + 65536);

    const int t = (int)threadIdx.x;
    {
        const float4* Wg = (const float4*)Wl;
        float4* Wd = (float4*)Wf;
        #pragma unroll
        for (int i = 0; i < 8; ++i) Wd[t + i * 512] = Wg[t + i * 512];
        if (t < 64) bs[t] = bl[t];
    }
    __syncthreads();
    {
        const int col = t & 63;
        const int kb  = (t >> 6) * 32;
        float v[32];
        #pragma unroll
        for (int j = 0; j < 32; ++j) v[j] = Wf[(size_t)(kb + j) * 64 + col];
        __syncthreads();
        #pragma unroll
        for (int c = 0; c < 4; ++c) {
            unsigned h8[8], l8[8];
            #pragma unroll
            for (int j = 0; j < 8; ++j) {
                const float w0 = v[c * 8 + j];
                const unsigned hb = bf16_rne(w0);
                h8[j] = hb;
                l8[j] = bf16_rne(w0 - __uint_as_float(hb << 16));
            }
            uint4 ph, pl;
            ph.x = h8[0] | (h8[1] << 16); ph.y = h8[2] | (h8[3] << 16);
            ph.z = h8[4] | (h8[5] << 16); ph.w = h8[6] | (h8[7] << 16);
            pl.x = l8[0] | (l8[1] << 16); pl.y = l8[2] | (l8[3] << 16);
            pl.z = l8[4] | (l8[5] << 16); pl.w = l8[6] | (l8[7] << 16);
            const int off = (col * 512 + (kb + c * 8) * 2) ^ ((col & 7) << 4);
            *(uint4*)(Whi + off) = ph;
            *(uint4*)(Wlo + off) = pl;
        }
    }
    __syncthreads();

    const int w  = t >> 6;
    const int l  = t & 63;
    const int wm = w >> 1;
    const int wn = w & 1;
    const int g  = l >> 4;
    const int q  = l & 15;
    const int r0 = (int)blockIdx.x * 128;

    f32x4 acc[2][2];
    const f32x4 zero = {0.f, 0.f, 0.f, 0.f};
    acc[0][0] = zero; acc[0][1] = zero; acc[1][0] = zero; acc[1][1] = zero;

    #pragma unroll
    for (int ks = 0; ks < 8; ++ks) {
        const int kf = (ks & 3) * 32 + g * 8;
        bf16x8 ah[2], al[2];
        #pragma unroll
        for (int m = 0; m < 2; ++m) {
            const int rr = min(r0 + wm * 32 + m * 16 + q, N - 1);
            float d[8];
            if (ks < 4) {
                const float* ph = h       + (size_t)rr * DD + kf;
                const float* ps = sum_agg + (size_t)rr * DD + kf;
                const int*   pm = max_agg + (size_t)rr * DD + kf;
                const float4 a0 = *(const float4*)ph;
                const float4 a1 = *(const float4*)(ph + 4);
                const float4 s0 = *(const float4*)ps;
                const float4 s1 = *(const float4*)(ps + 4);
                const int4   i0 = *(const int4*)pm;
                const int4   i1 = *(const int4*)(pm + 4);
                d[0] = a0.x * a0.x * s0.x * __int_as_float(i0.x);
                d[1] = a0.y * a0.y * s0.y * __int_as_float(i0.y);
                d[2] = a0.z * a0.z * s0.z * __int_as_float(i0.z);
                d[3] = a0.w * a0.w * s0.w * __int_as_float(i0.w);
                d[4] = a1.x * a1.x * s1.x * __int_as_float(i1.x);
                d[5] = a1.y * a1.y * s1.y * __int_as_float(i1.y);
                d[6] = a1.z * a1.z * s1.z * __int_as_float(i1.z);
                d[7] = a1.w * a1.w * s1.w * __int_as_float(i1.w);
            } else {
                const float* pa = xp + (size_t)rr * DD + kf;
                const float4 a0 = *(const float4*)pa;
                const float4 a1 = *(const float4*)(pa + 4);
                d[0] = a0.x; d[1] = a0.y; d[2] = a0.z; d[3] = a0.w;
                d[4] = a1.x; d[5] = a1.y; d[6] = a1.z; d[7] = a1.w;
            }
            unsigned h8[8], l8[8];
            #pragma unroll
            for (int j = 0; j < 8; ++j) {
                const unsigned hb = bf16_rne(d[j]);
                h8[j] = hb;
                l8[j] = bf16_rne(d[j] - __uint_as_float(hb << 16));
            }
            uint4 ph2, pl2;
            ph2.x = h8[0] | (h8[1] << 16); ph2.y = h8[2] | (h8[3] << 16);
            ph2.z = h8[4] | (h8[5] << 16); ph2.w = h8[6] | (h8[7] << 16);
            pl2.x = l8[0] | (l8[1] << 16); pl2.y = l8[2] | (l8[3] << 16);
            pl2.z = l8[4] | (l8[5] << 16); pl2.w = l8[6] | (l8[7] << 16);
            ah[m] = *(bf16x8*)&ph2;
            al[m] = *(bf16x8*)&pl2;
        }
        bf16x8 bh[2], blo[2];
        #pragma unroll
        for (int n = 0; n < 2; ++n) {
            const int colv = wn * 32 + n * 16 + q;
            const int off = (colv * 512 + ks * 64 + g * 16) ^ ((colv & 7) << 4);
            bh[n]  = *(const bf16x8*)(Whi + off);
            blo[n] = *(const bf16x8*)(Wlo + off);
        }
        #pragma unroll
        for (int m = 0; m < 2; ++m)
            #pragma unroll
            for (int n = 0; n < 2; ++n) {
                acc[m][n] = __builtin_amdgcn_mfma_f32_16x16x32_bf16(ah[m], bh[n],  acc[m][n], 0, 0, 0);
                acc[m][n] = __builtin_amdgcn_mfma_f32_16x16x32_bf16(ah[m], blo[n], acc[m][n], 0, 0, 0);
                acc[m][n] = __builtin_amdgcn_mfma_f32_16x16x32_bf16(al[m], bh[n],  acc[m][n], 0, 0, 0);
            }
    }

    #pragma unroll
    for (int n = 0; n < 2; ++n) {
        const int colv = wn * 32 + n * 16 + q;
        const float bv = bs[colv];
        #pragma unroll
        for (int m = 0; m < 2; ++m) {
            #pragma unroll
            for (int r = 0; r < 4; ++r) {
                const int row = r0 + wm * 32 + m * 16 + g * 4 + r;
                if (row < N) out[(size_t)row * 64 + colv] = acc[m][n][r] + bv;
            }
        }
    }
}

// ---------------------------------------------------------------------------
extern "C" void kernel_launch(void* const* d_in, const int* in_sizes, int n_in,
                              void* d_out, int out_size, void* d_ws, size_t ws_size,
                              hipStream_t stream)
{
    const float* x         = (const float*)d_in[0];
    const int*   edge_idx  = (const int*)d_in[1];
    const float* edge_attr = (const float*)d_in[2];
    const float* W_atom    = (const float*)d_in[3];
    const float* b_atom    = (const float*)d_in[4];
    const float* W_bond    = (const float*)d_in[5];
    const float* b_bond    = (const float*)d_in[6];
    const float* W_seq     = (const float*)d_in[7];
    const float* b_seq     = (const float*)d_in[8];
    const float* W_lin     = (const float*)d_in[9];
    const float* b_lin     = (const float*)d_in[10];
    float* out = (float*)d_out;

    const int N = in_sizes[0] / DD;   // 30000
    const int E = in_sizes[1] / 2;    // 480000
    const int* idx_i = edge_idx;
    const int* idx_j = edge_idx + E;

    const size_t nd = (size_t)N * DD;
    float* ws      = (float*)d_ws;
    float* x_proj  = ws;
    float* h_atom  = x_proj + nd;
    float* head    = h_atom + nd;
    float* sum_agg = head + nd;
    int*   max_agg = (int*)(sum_agg + nd);
    float* PQ      = (float*)(max_agg + nd);   // 2N x 128
    int*   cnt     = (int*)(PQ + 2 * nd);
    int*   cursor  = cnt + N;
    int*   bsum    = cursor + N;
    int*   perm    = bsum + 256;
    int*   si      = perm + E;
    int*   sj      = si + E;

    // ---- counting sort of edges by idx_i ----
    hipMemsetAsync(cnt, 0, (size_t)N * 4, stream);
    hist_kernel<<<(E + 255) / 256, 256, 0, stream>>>(idx_i, cnt, E);
    const int nb_scan = (N + SCB - 1) / SCB;
    scan1_kernel<<<nb_scan, SCB, 0, stream>>>(cnt, cursor, bsum, N);
    scan2_kernel<<<1, SCB, 0, stream>>>(bsum, nb_scan);
    scan3_kernel<<<nb_scan, SCB, 0, stream>>>(cursor, bsum, N);
    scatter_kernel<<<(E + 255) / 256, 256, 0, stream>>>(idx_i, idx_j, cursor, perm, si, sj, E);

    hipMemsetAsync(sum_agg, 0, nd * 4, stream);
    hipMemsetAsync(max_agg, 0, nd * 4, stream);

    // node projection via MFMA: x_proj = h_atom = relu(x @ W_atom + b_atom)
    const int ntiles_n = (N + 127) / 128;
    gemm128_mfma_kernel<<<min(ntiles_n, 256), 1024, 0, stream>>>(
        (float*)x, x, N, N, W_atom, b_atom, N, 1, 0, nullptr, nullptr,
        x_proj, h_atom, ntiles_n);

    // bond projection + layer-0 aggregation (R5 VALU path)
    bond_proj_agg_kernel<<<(E + 31) / 32, 256, 0, stream>>>(edge_attr, W_bond, b_bond,
                                                            si, perm, head,
                                                            sum_agg, max_agg, E, N);

    const int ntiles_pq = (2 * N + 127) / 128;
    const int ep_blocks = (E + CE - 1) / CE;
    for (int l = 0; l < 3; ++l) {
        gemm128_mfma_kernel<<<256, 1024, 0, stream>>>(
            h_atom, head, N, 2 * N, W_seq + (size_t)l * DD * DD,
            b_seq + (size_t)l * DD, N, 0, 1, sum_agg, max_agg,
            PQ, nullptr, ntiles_pq);
        edge_pass_kernel<<<ep_blocks, 256, 0, stream>>>(
            PQ, si, sj, perm, head, (l < 2) ? 1 : 0, sum_agg, max_agg, E, N);
    }

    final_mfma_kernel<<<(N + 127) / 128, 512, 0, stream>>>(
        h_atom, sum_agg, (const int*)max_agg, x_proj, W_lin, b_lin, out, N);
}

// Round 10
// 429.803 us; speedup vs baseline: 1.0616x; 1.0240x over previous
//
#include <hip/hip_runtime.h>
#include <hip/hip_bf16.h>

#define DD 128   // hidden dim
#define SCB 256  // scan block size
#define CE  512  // edges per block in edge_pass (4 waves x 128)
#define CB  512  // edges per block in bond pass (4 waves x 128)

typedef __attribute__((ext_vector_type(8))) short bf16x8;
typedef __attribute__((ext_vector_type(4))) float f32x4;

__device__ __forceinline__ unsigned bf16_rne(float f) {
    unsigned u = __float_as_uint(f);
    return (u + 0x7fffu + ((u >> 16) & 1u)) >> 16;
}

// ---------------------------------------------------------------------------
// counting-sort preprocessing (sort edges by idx_i)
// ---------------------------------------------------------------------------
__global__ __launch_bounds__(256)
void hist_kernel(const int* __restrict__ idx_i, int* __restrict__ cnt, int E)
{
    const int e = blockIdx.x * 256 + threadIdx.x;
    if (e < E) atomicAdd(&cnt[idx_i[e]], 1);
}

__global__ __launch_bounds__(SCB)
void scan1_kernel(const int* __restrict__ cnt, int* __restrict__ exc,
                  int* __restrict__ bsum, int n)
{
    __shared__ int s[SCB];
    const int i = blockIdx.x * SCB + (int)threadIdx.x;
    const int v = (i < n) ? cnt[i] : 0;
    s[threadIdx.x] = v;
    __syncthreads();
    #pragma unroll
    for (int off = 1; off < SCB; off <<= 1) {
        int t = (threadIdx.x >= off) ? s[threadIdx.x - off] : 0;
        __syncthreads();
        s[threadIdx.x] += t;
        __syncthreads();
    }
    if (i < n) exc[i] = s[threadIdx.x] - v;
    if (threadIdx.x == SCB - 1) bsum[blockIdx.x] = s[threadIdx.x];
}

__global__ __launch_bounds__(SCB)
void scan2_kernel(int* __restrict__ bsum, int nb)
{
    __shared__ int s[SCB];
    const int v = (threadIdx.x < nb) ? bsum[threadIdx.x] : 0;
    s[threadIdx.x] = v;
    __syncthreads();
    #pragma unroll
    for (int off = 1; off < SCB; off <<= 1) {
        int t = (threadIdx.x >= off) ? s[threadIdx.x - off] : 0;
        __syncthreads();
        s[threadIdx.x] += t;
        __syncthreads();
    }
    if (threadIdx.x < nb) bsum[threadIdx.x] = s[threadIdx.x] - v;
}

__global__ __launch_bounds__(SCB)
void scan3_kernel(int* __restrict__ exc, const int* __restrict__ bsum, int n)
{
    const int i = blockIdx.x * SCB + (int)threadIdx.x;
    if (i < n) exc[i] += bsum[i >> 8];
}

__global__ __launch_bounds__(256)
void scatter_kernel(const int* __restrict__ idx_i, const int* __restrict__ idx_j,
                    int* __restrict__ cursor, int* __restrict__ perm,
                    int* __restrict__ si, int* __restrict__ sj, int E)
{
    const int e = blockIdx.x * 256 + threadIdx.x;
    if (e < E) {
        const int n = idx_i[e];
        const int p = atomicAdd(&cursor[n], 1);
        perm[p] = e;
        si[p] = n;
        sj[p] = idx_j[e];
    }
}

// ---------------------------------------------------------------------------
// generic 128-K split-bf16 MFMA GEMM with optional fused node-update
// (unchanged)
// ---------------------------------------------------------------------------
__global__ __launch_bounds__(1024)
void gemm128_mfma_kernel(float* __restrict__ A0, const float* __restrict__ A1,
                         int nA, int nTotal,
                         const float* __restrict__ W, const float* __restrict__ bias,
                         int bias_limit, int do_relu, int update,
                         float* __restrict__ sum_agg, int* __restrict__ max_agg,
                         float* __restrict__ out0, float* __restrict__ out1,
                         int ntiles)
{
    __shared__ __align__(16) unsigned char SM[131584];
    char*  const Whi = (char*)SM;
    char*  const Wlo = (char*)SM + 32768;
    char*  const Ahi = (char*)SM + 65536;
    char*  const Alo = (char*)SM + 98304;
    float* const Wf  = (float*)(SM + 65536);
    float* const bs  = (float*)(SM + 131072);

    const int t = (int)threadIdx.x;

    {
        const float4* Wg = (const float4*)W;
        float4* Wd = (float4*)Wf;
        #pragma unroll
        for (int i = 0; i < 4; ++i) Wd[t + i * 1024] = Wg[t + i * 1024];
        if (t < DD) bs[t] = bias ? bias[t] : 0.f;
    }
    __syncthreads();
    {
        const int col = t >> 3;
        const int kb  = (t & 7) * 16;
        unsigned h16[16], l16[16];
        #pragma unroll
        for (int j = 0; j < 16; ++j) {
            const float w = Wf[(size_t)(kb + j) * DD + col];
            const unsigned hb = bf16_rne(w);
            const float hf = __uint_as_float(hb << 16);
            h16[j] = hb;
            l16[j] = bf16_rne(w - hf);
        }
        #pragma unroll
        for (int c = 0; c < 2; ++c) {
            uint4 ph, pl;
            ph.x = h16[c*8+0] | (h16[c*8+1] << 16);
            ph.y = h16[c*8+2] | (h16[c*8+3] << 16);
            ph.z = h16[c*8+4] | (h16[c*8+5] << 16);
            ph.w = h16[c*8+6] | (h16[c*8+7] << 16);
            pl.x = l16[c*8+0] | (l16[c*8+1] << 16);
            pl.y = l16[c*8+2] | (l16[c*8+3] << 16);
            pl.z = l16[c*8+4] | (l16[c*8+5] << 16);
            pl.w = l16[c*8+6] | (l16[c*8+7] << 16);
            const int off = ((col * 256 + (kb + c * 8) * 2)) ^ ((col & 7) << 4);
            *(uint4*)(Whi + off) = ph;
            *(uint4*)(Wlo + off) = pl;
        }
    }

    const int w  = t >> 6;
    const int l  = t & 63;
    const int wm = w >> 2;
    const int wn = w & 3;
    const int g  = l >> 4;
    const int q  = l & 15;

    for (int tile = blockIdx.x; tile < ntiles; tile += gridDim.x) {
        const int e0 = tile * 128;
        __syncthreads();

        #pragma unroll
        for (int i = 0; i < 2; ++i) {
            const int task = t + i * 1024;
            const int row  = task >> 4;
            const int c    = task & 15;
            const int rr = min(e0 + row, nTotal - 1);
            float d[8];
            if (rr < nA) {
                float* ph0 = A0 + (size_t)rr * DD + c * 8;
                const float4 a0 = *(const float4*)ph0;
                const float4 a1 = *(const float4*)(ph0 + 4);
                if (update) {
                    float* sp = sum_agg + (size_t)rr * DD + c * 8;
                    int*   mp = max_agg + (size_t)rr * DD + c * 8;
                    const float4 s0 = *(const float4*)sp;
                    const float4 s1 = *(const float4*)(sp + 4);
                    const int4   m0 = *(const int4*)mp;
                    const int4   m1 = *(const int4*)(mp + 4);
                    d[0] = a0.x * s0.x * __int_as_float(m0.x);
                    d[1] = a0.y * s0.y * __int_as_float(m0.y);
                    d[2] = a0.z * s0.z * __int_as_float(m0.z);
                    d[3] = a0.w * s0.w * __int_as_float(m0.w);
                    d[4] = a1.x * s1.x * __int_as_float(m1.x);
                    d[5] = a1.y * s1.y * __int_as_float(m1.y);
                    d[6] = a1.z * s1.z * __int_as_float(m1.z);
                    d[7] = a1.w * s1.w * __int_as_float(m1.w);
                    *(float4*)ph0       = make_float4(d[0], d[1], d[2], d[3]);
                    *(float4*)(ph0 + 4) = make_float4(d[4], d[5], d[6], d[7]);
                    *(float4*)sp       = make_float4(0.f, 0.f, 0.f, 0.f);
                    *(float4*)(sp + 4) = make_float4(0.f, 0.f, 0.f, 0.f);
                    *(int4*)mp       = make_int4(0, 0, 0, 0);
                    *(int4*)(mp + 4) = make_int4(0, 0, 0, 0);
                } else {
                    d[0] = a0.x; d[1] = a0.y; d[2] = a0.z; d[3] = a0.w;
                    d[4] = a1.x; d[5] = a1.y; d[6] = a1.z; d[7] = a1.w;
                }
            } else {
                const float* pa = A1 + (size_t)(rr - nA) * DD + c * 8;
                const float4 a0 = *(const float4*)pa;
                const float4 a1 = *(const float4*)(pa + 4);
                d[0] = a0.x; d[1] = a0.y; d[2] = a0.z; d[3] = a0.w;
                d[4] = a1.x; d[5] = a1.y; d[6] = a1.z; d[7] = a1.w;
            }
            unsigned h8[8], l8[8];
            #pragma unroll
            for (int j = 0; j < 8; ++j) {
                const unsigned hb = bf16_rne(d[j]);
                const float hf = __uint_as_float(hb << 16);
                h8[j] = hb;
                l8[j] = bf16_rne(d[j] - hf);
            }
            uint4 ph, pl;
            ph.x = h8[0] | (h8[1] << 16);
            ph.y = h8[2] | (h8[3] << 16);
            ph.z = h8[4] | (h8[5] << 16);
            ph.w = h8[6] | (h8[7] << 16);
            pl.x = l8[0] | (l8[1] << 16);
            pl.y = l8[2] | (l8[3] << 16);
            pl.z = l8[4] | (l8[5] << 16);
            pl.w = l8[6] | (l8[7] << 16);
            const int off = ((row * 256 + c * 16)) ^ ((row & 7) << 4);
            *(uint4*)(Ahi + off) = ph;
            *(uint4*)(Alo + off) = pl;
        }
        __syncthreads();

        f32x4 acc[2][2];
        const f32x4 zero = {0.f, 0.f, 0.f, 0.f};
        acc[0][0] = zero; acc[0][1] = zero; acc[1][0] = zero; acc[1][1] = zero;

        #pragma unroll
        for (int ks = 0; ks < 4; ++ks) {
            const int kbyte = ks * 64 + g * 16;
            bf16x8 ah[2], al[2], bh[2], bl[2];
            #pragma unroll
            for (int m = 0; m < 2; ++m) {
                const int row = wm * 32 + m * 16 + q;
                const int off = (row * 256 + kbyte) ^ ((row & 7) << 4);
                ah[m] = *(const bf16x8*)(Ahi + off);
                al[m] = *(const bf16x8*)(Alo + off);
            }
            #pragma unroll
            for (int n = 0; n < 2; ++n) {
                const int colv = wn * 32 + n * 16 + q;
                const int off = (colv * 256 + kbyte) ^ ((colv & 7) << 4);
                bh[n] = *(const bf16x8*)(Whi + off);
                bl[n] = *(const bf16x8*)(Wlo + off);
            }
            #pragma unroll
            for (int m = 0; m < 2; ++m)
                #pragma unroll
                for (int n = 0; n < 2; ++n)
                    acc[m][n] = __builtin_amdgcn_mfma_f32_16x16x32_bf16(ah[m], bh[n], acc[m][n], 0, 0, 0);
            #pragma unroll
            for (int m = 0; m < 2; ++m)
                #pragma unroll
                for (int n = 0; n < 2; ++n)
                    acc[m][n] = __builtin_amdgcn_mfma_f32_16x16x32_bf16(ah[m], bl[n], acc[m][n], 0, 0, 0);
            #pragma unroll
            for (int m = 0; m < 2; ++m)
                #pragma unroll
                for (int n = 0; n < 2; ++n)
                    acc[m][n] = __builtin_amdgcn_mfma_f32_16x16x32_bf16(al[m], bh[n], acc[m][n], 0, 0, 0);
        }

        #pragma unroll
        for (int n = 0; n < 2; ++n) {
            const int colv = wn * 32 + n * 16 + q;
            const float bv = bs[colv];
            #pragma unroll
            for (int m = 0; m < 2; ++m) {
                #pragma unroll
                for (int r = 0; r < 4; ++r) {
                    const int row = e0 + wm * 32 + m * 16 + g * 4 + r;
                    if (row < nTotal) {
                        float v = acc[m][n][r] + ((row < bias_limit) ? bv : 0.f);
                        if (do_relu) v = fmaxf(v, 0.f);
                        out0[(size_t)row * DD + colv] = v;
                        if (out1) out1[(size_t)row * DD + colv] = v;
                    }
                }
            }
        }
    }
}

// ---------------------------------------------------------------------------
// bond pass v4: edge_pass-v3 structure for the bond projection.
//   one block = 512 sorted edges; stage edge_attr rows (gathered via perm)
//   into LDS; 4 waves x 128 edges; lane owns 2 cols with W cols in regs;
//   ea row read is lane-uniform -> LDS broadcast; segmented-ownership
//   aggregation (interior nodes = plain stores, boundary = atomics).
// ---------------------------------------------------------------------------
__global__ __launch_bounds__(256)
void bond_pass_kernel(const float* __restrict__ edge_attr,
                      const float* __restrict__ Wb, const float* __restrict__ bb,
                      const int* __restrict__ si, const int* __restrict__ perm,
                      float* __restrict__ h_head0,
                      float* __restrict__ sum_agg, int* __restrict__ max_agg,
                      int E, int N)
{
    __shared__ __align__(16) float ea_s[CB][16];   // 32 KB
    __shared__ int si_s[CB], pm_s[CB];             // 4 KB

    const int p0b = blockIdx.x * CB;
    if (p0b >= E) return;
    const int t = (int)threadIdx.x;

    for (int i = t; i < CB; i += 256) {
        const int p = min(p0b + i, E - 1);
        si_s[i] = si[p];
        pm_s[i] = perm[p];
    }
    for (int task = t; task < CB * 4; task += 256) {
        const int row = task >> 2;
        const int c4  = task & 3;
        const int p = min(p0b + row, E - 1);
        const int orig = perm[p];
        *(float4*)(&ea_s[row][c4 * 4]) =
            *(const float4*)(edge_attr + (size_t)orig * 16 + c4 * 4);
    }
    __syncthreads();

    const int w    = t >> 6;
    const int lane = t & 63;
    const int c    = lane * 2;
    const int q0   = w * 128;
    const int pg0  = p0b + q0;
    if (pg0 >= E) return;

    // W columns c and c+1 in registers (L2-hot broadcast across blocks)
    float wc0[16], wc1[16];
    #pragma unroll
    for (int k = 0; k < 16; ++k) {
        const float2 wv = *(const float2*)(Wb + k * DD + c);
        wc0[k] = wv.x; wc1[k] = wv.y;
    }
    const float2 bc = *(const float2*)(bb + c);

    const int firstNode = si_s[q0];
    const int lastNode  = si_s[q0 + 127];

    int curNode = firstNode;
    float2 rs = make_float2(0.f, 0.f), rm = make_float2(0.f, 0.f);

    #define BP_FLUSH()                                                           \
    {                                                                            \
        if (curNode == firstNode || curNode == lastNode) {                       \
            atomicAdd(&sum_agg[(size_t)curNode * DD + c],     rs.x);             \
            atomicAdd(&sum_agg[(size_t)curNode * DD + c + 1], rs.y);             \
            atomicMax(&max_agg[(size_t)curNode * DD + c],     __float_as_int(rm.x)); \
            atomicMax(&max_agg[(size_t)curNode * DD + c + 1], __float_as_int(rm.y)); \
        } else {                                                                 \
            *(float2*)(sum_agg + (size_t)curNode * DD + c) = rs;                 \
            *(int2*)(max_agg + (size_t)curNode * DD + c) =                       \
                make_int2(__float_as_int(rm.x), __float_as_int(rm.y));           \
        }                                                                        \
    }

    #pragma unroll 4
    for (int kk = 0; kk < 128; ++kk) {
        const int i = si_s[q0 + kk];
        if (i != curNode) {
            BP_FLUSH();
            curNode = i;
            rs = make_float2(0.f, 0.f);
            rm = make_float2(0.f, 0.f);
        }
        const float4* ear = (const float4*)(&ea_s[q0 + kk][0]);
        const float4 e0 = ear[0], e1 = ear[1], e2 = ear[2], e3 = ear[3];
        float ax = bc.x, ay = bc.y;
        ax = fmaf(e0.x, wc0[ 0], ax);  ay = fmaf(e0.x, wc1[ 0], ay);
        ax = fmaf(e0.y, wc0[ 1], ax);  ay = fmaf(e0.y, wc1[ 1], ay);
        ax = fmaf(e0.z, wc0[ 2], ax);  ay = fmaf(e0.z, wc1[ 2], ay);
        ax = fmaf(e0.w, wc0[ 3], ax);  ay = fmaf(e0.w, wc1[ 3], ay);
        ax = fmaf(e1.x, wc0[ 4], ax);  ay = fmaf(e1.x, wc1[ 4], ay);
        ax = fmaf(e1.y, wc0[ 5], ax);  ay = fmaf(e1.y, wc1[ 5], ay);
        ax = fmaf(e1.z, wc0[ 6], ax);  ay = fmaf(e1.z, wc1[ 6], ay);
        ax = fmaf(e1.w, wc0[ 7], ax);  ay = fmaf(e1.w, wc1[ 7], ay);
        ax = fmaf(e2.x, wc0[ 8], ax);  ay = fmaf(e2.x, wc1[ 8], ay);
        ax = fmaf(e2.y, wc0[ 9], ax);  ay = fmaf(e2.y, wc1[ 9], ay);
        ax = fmaf(e2.z, wc0[10], ax);  ay = fmaf(e2.z, wc1[10], ay);
        ax = fmaf(e2.w, wc0[11], ax);  ay = fmaf(e2.w, wc1[11], ay);
        ax = fmaf(e3.x, wc0[12], ax);  ay = fmaf(e3.x, wc1[12], ay);
        ax = fmaf(e3.y, wc0[13], ax);  ay = fmaf(e3.y, wc1[13], ay);
        ax = fmaf(e3.z, wc0[14], ax);  ay = fmaf(e3.z, wc1[14], ay);
        ax = fmaf(e3.w, wc0[15], ax);  ay = fmaf(e3.w, wc1[15], ay);
        float2 v;
        v.x = fmaxf(ax, 0.f);
        v.y = fmaxf(ay, 0.f);
        if (pg0 + kk >= E) { v.x = 0.f; v.y = 0.f; }
        rs.x += v.x; rs.y += v.y;
        rm.x = fmaxf(rm.x, v.x); rm.y = fmaxf(rm.y, v.y);
        if (pg0 + kk < E) {
            const int orig = pm_s[q0 + kk];
            if (orig < N) *(float2*)(h_head0 + (size_t)orig * DD + c) = v;
        }
    }
    BP_FLUSH();   // final run: curNode == lastNode -> atomic path
    #undef BP_FLUSH
}

// ---------------------------------------------------------------------------
// edge pass v3 (unchanged): v = relu(P[si]-Q[sj]); segmented ownership.
// ---------------------------------------------------------------------------
__global__ __launch_bounds__(256)
void edge_pass_kernel(const float* __restrict__ PQ,
                      const int* __restrict__ si, const int* __restrict__ sj,
                      const int* __restrict__ perm,
                      float* __restrict__ head_next, int store_head,
                      float* __restrict__ sum_agg, int* __restrict__ max_agg,
                      int E, int N)
{
    __shared__ int si_s[CE], sj_s[CE], pm_s[CE];
    const int p0b = blockIdx.x * CE;
    if (p0b >= E) return;
    const int t = (int)threadIdx.x;
    for (int i = t; i < CE; i += 256) {
        const int p = min(p0b + i, E - 1);
        si_s[i] = si[p];
        sj_s[i] = sj[p];
        pm_s[i] = perm[p];
    }
    __syncthreads();

    const int w    = t >> 6;
    const int lane = t & 63;
    const int c    = lane * 2;
    const int q0   = w * 128;
    const int pg0  = p0b + q0;
    if (pg0 >= E) return;

    const int firstNode = si_s[q0];
    const int lastNode  = si_s[q0 + 127];

    const float* __restrict__ Qbase = PQ + (size_t)N * DD + c;

    float2 qa = *(const float2*)(Qbase + (size_t)sj_s[q0 + 0] * DD);
    float2 qb = *(const float2*)(Qbase + (size_t)sj_s[q0 + 1] * DD);
    float2 qc = *(const float2*)(Qbase + (size_t)sj_s[q0 + 2] * DD);
    float2 qd = *(const float2*)(Qbase + (size_t)sj_s[q0 + 3] * DD);

    int curNode = firstNode;
    float2 Pi = *(const float2*)(PQ + (size_t)curNode * DD + c);
    float2 rs = make_float2(0.f, 0.f), rm = make_float2(0.f, 0.f);

    #define EP_FLUSH()                                                           \
    {                                                                            \
        if (curNode == firstNode || curNode == lastNode) {                       \
            atomicAdd(&sum_agg[(size_t)curNode * DD + c],     rs.x);             \
            atomicAdd(&sum_agg[(size_t)curNode * DD + c + 1], rs.y);             \
            atomicMax(&max_agg[(size_t)curNode * DD + c],     __float_as_int(rm.x)); \
            atomicMax(&max_agg[(size_t)curNode * DD + c + 1], __float_as_int(rm.y)); \
        } else {                                                                 \
            *(float2*)(sum_agg + (size_t)curNode * DD + c) = rs;                 \
            *(int2*)(max_agg + (size_t)curNode * DD + c) =                       \
                make_int2(__float_as_int(rm.x), __float_as_int(rm.y));           \
        }                                                                        \
    }

    #define EP_STEP(K, QREG)                                                     \
    {                                                                            \
        const int kk = (K);                                                      \
        const int i = si_s[q0 + kk];                                             \
        if (i != curNode) {                                                      \
            EP_FLUSH();                                                          \
            curNode = i;                                                         \
            Pi = *(const float2*)(PQ + (size_t)i * DD + c);                      \
            rs = make_float2(0.f, 0.f);                                          \
            rm = make_float2(0.f, 0.f);                                          \
        }                                                                        \
        float2 v;                                                                \
        v.x = fmaxf(Pi.x - QREG.x, 0.f);                                         \
        v.y = fmaxf(Pi.y - QREG.y, 0.f);                                         \
        if (pg0 + kk >= E) { v.x = 0.f; v.y = 0.f; }                             \
        rs.x += v.x; rs.y += v.y;                                                \
        rm.x = fmaxf(rm.x, v.x); rm.y = fmaxf(rm.y, v.y);                        \
        if (store_head && (pg0 + kk) < E) {                                      \
            const int orig = pm_s[q0 + kk];                                      \
            if (orig < N) *(float2*)(head_next + (size_t)orig * DD + c) = v;     \
        }                                                                        \
        if (kk + 4 < 128)                                                        \
            QREG = *(const float2*)(Qbase + (size_t)sj_s[q0 + kk + 4] * DD);     \
    }

    #pragma unroll 8
    for (int k = 0; k < 128; k += 4) {
        EP_STEP(k + 0, qa);
        EP_STEP(k + 1, qb);
        EP_STEP(k + 2, qc);
        EP_STEP(k + 3, qd);
    }
    EP_FLUSH();
    #undef EP_STEP
    #undef EP_FLUSH
}

// ---------------------------------------------------------------------------
// final: out = [ha, x_proj] @ W_lin + b_lin via split-bf16 MFMA, K=256
// (unchanged)
// ---------------------------------------------------------------------------
__global__ __launch_bounds__(512, 2)
void final_mfma_kernel(const float* __restrict__ h, const float* __restrict__ sum_agg,
                       const int* __restrict__ max_agg, const float* __restrict__ xp,
                       const float* __restrict__ Wl, const float* __restrict__ bl,
                       float* __restrict__ out, int N)
{
    __shared__ __align__(16) unsigned char SM[65808];
    char*  const Whi = (char*)SM;
    char*  const Wlo = (char*)SM + 32768;
    float* const Wf  = (float*)SM;
    float* const bs  = (float*)(SM + 65536);

    const int t = (int)threadIdx.x;
    {
        const float4* Wg = (const float4*)Wl;
        float4* Wd = (float4*)Wf;
        #pragma unroll
        for (int i = 0; i < 8; ++i) Wd[t + i * 512] = Wg[t + i * 512];
        if (t < 64) bs[t] = bl[t];
    }
    __syncthreads();
    {
        const int col = t & 63;
        const int kb  = (t >> 6) * 32;
        float v[32];
        #pragma unroll
        for (int j = 0; j < 32; ++j) v[j] = Wf[(size_t)(kb + j) * 64 + col];
        __syncthreads();
        #pragma unroll
        for (int c = 0; c < 4; ++c) {
            unsigned h8[8], l8[8];
            #pragma unroll
            for (int j = 0; j < 8; ++j) {
                const float w0 = v[c * 8 + j];
                const unsigned hb = bf16_rne(w0);
                h8[j] = hb;
                l8[j] = bf16_rne(w0 - __uint_as_float(hb << 16));
            }
            uint4 ph, pl;
            ph.x = h8[0] | (h8[1] << 16); ph.y = h8[2] | (h8[3] << 16);
            ph.z = h8[4] | (h8[5] << 16); ph.w = h8[6] | (h8[7] << 16);
            pl.x = l8[0] | (l8[1] << 16); pl.y = l8[2] | (l8[3] << 16);
            pl.z = l8[4] | (l8[5] << 16); pl.w = l8[6] | (l8[7] << 16);
            const int off = (col * 512 + (kb + c * 8) * 2) ^ ((col & 7) << 4);
            *(uint4*)(Whi + off) = ph;
            *(uint4*)(Wlo + off) = pl;
        }
    }
    __syncthreads();

    const int w  = t >> 6;
    const int l  = t & 63;
    const int wm = w >> 1;
    const int wn = w & 1;
    const int g  = l >> 4;
    const int q  = l & 15;
    const int r0 = (int)blockIdx.x * 128;

    f32x4 acc[2][2];
    const f32x4 zero = {0.f, 0.f, 0.f, 0.f};
    acc[0][0] = zero; acc[0][1] = zero; acc[1][0] = zero; acc[1][1] = zero;

    #pragma unroll
    for (int ks = 0; ks < 8; ++ks) {
        const int kf = (ks & 3) * 32 + g * 8;
        bf16x8 ah[2], al[2];
        #pragma unroll
        for (int m = 0; m < 2; ++m) {
            const int rr = min(r0 + wm * 32 + m * 16 + q, N - 1);
            float d[8];
            if (ks < 4) {
                const float* ph = h       + (size_t)rr * DD + kf;
                const float* ps = sum_agg + (size_t)rr * DD + kf;
                const int*   pm = max_agg + (size_t)rr * DD + kf;
                const float4 a0 = *(const float4*)ph;
                const float4 a1 = *(const float4*)(ph + 4);
                const float4 s0 = *(const float4*)ps;
                const float4 s1 = *(const float4*)(ps + 4);
                const int4   i0 = *(const int4*)pm;
                const int4   i1 = *(const int4*)(pm + 4);
                d[0] = a0.x * a0.x * s0.x * __int_as_float(i0.x);
                d[1] = a0.y * a0.y * s0.y * __int_as_float(i0.y);
                d[2] = a0.z * a0.z * s0.z * __int_as_float(i0.z);
                d[3] = a0.w * a0.w * s0.w * __int_as_float(i0.w);
                d[4] = a1.x * a1.x * s1.x * __int_as_float(i1.x);
                d[5] = a1.y * a1.y * s1.y * __int_as_float(i1.y);
                d[6] = a1.z * a1.z * s1.z * __int_as_float(i1.z);
                d[7] = a1.w * a1.w * s1.w * __int_as_float(i1.w);
            } else {
                const float* pa = xp + (size_t)rr * DD + kf;
                const float4 a0 = *(const float4*)pa;
                const float4 a1 = *(const float4*)(pa + 4);
                d[0] = a0.x; d[1] = a0.y; d[2] = a0.z; d[3] = a0.w;
                d[4] = a1.x; d[5] = a1.y; d[6] = a1.z; d[7] = a1.w;
            }
            unsigned h8[8], l8[8];
            #pragma unroll
            for (int j = 0; j < 8; ++j) {
                const unsigned hb = bf16_rne(d[j]);
                h8[j] = hb;
                l8[j] = bf16_rne(d[j] - __uint_as_float(hb << 16));
            }
            uint4 ph2, pl2;
            ph2.x = h8[0] | (h8[1] << 16); ph2.y = h8[2] | (h8[3] << 16);
            ph2.z = h8[4] | (h8[5] << 16); ph2.w = h8[6] | (h8[7] << 16);
            pl2.x = l8[0] | (l8[1] << 16); pl2.y = l8[2] | (l8[3] << 16);
            pl2.z = l8[4] | (l8[5] << 16); pl2.w = l8[6] | (l8[7] << 16);
            ah[m] = *(bf16x8*)&ph2;
            al[m] = *(bf16x8*)&pl2;
        }
        bf16x8 bh[2], blo[2];
        #pragma unroll
        for (int n = 0; n < 2; ++n) {
            const int colv = wn * 32 + n * 16 + q;
            const int off = (colv * 512 + ks * 64 + g * 16) ^ ((colv & 7) << 4);
            bh[n]  = *(const bf16x8*)(Whi + off);
            blo[n] = *(const bf16x8*)(Wlo + off);
        }
        #pragma unroll
        for (int m = 0; m < 2; ++m)
            #pragma unroll
            for (int n = 0; n < 2; ++n) {
                acc[m][n] = __builtin_amdgcn_mfma_f32_16x16x32_bf16(ah[m], bh[n],  acc[m][n], 0, 0, 0);
                acc[m][n] = __builtin_amdgcn_mfma_f32_16x16x32_bf16(ah[m], blo[n], acc[m][n], 0, 0, 0);
                acc[m][n] = __builtin_amdgcn_mfma_f32_16x16x32_bf16(al[m], bh[n],  acc[m][n], 0, 0, 0);
            }
    }

    #pragma unroll
    for (int n = 0; n < 2; ++n) {
        const int colv = wn * 32 + n * 16 + q;
        const float bv = bs[colv];
        #pragma unroll
        for (int m = 0; m < 2; ++m) {
            #pragma unroll
            for (int r = 0; r < 4; ++r) {
                const int row = r0 + wm * 32 + m * 16 + g * 4 + r;
                if (row < N) out[(size_t)row * 64 + colv] = acc[m][n][r] + bv;
            }
        }
    }
}

// ---------------------------------------------------------------------------
extern "C" void kernel_launch(void* const* d_in, const int* in_sizes, int n_in,
                              void* d_out, int out_size, void* d_ws, size_t ws_size,
                              hipStream_t stream)
{
    const float* x         = (const float*)d_in[0];
    const int*   edge_idx  = (const int*)d_in[1];
    const float* edge_attr = (const float*)d_in[2];
    const float* W_atom    = (const float*)d_in[3];
    const float* b_atom    = (const float*)d_in[4];
    const float* W_bond    = (const float*)d_in[5];
    const float* b_bond    = (const float*)d_in[6];
    const float* W_seq     = (const float*)d_in[7];
    const float* b_seq     = (const float*)d_in[8];
    const float* W_lin     = (const float*)d_in[9];
    const float* b_lin     = (const float*)d_in[10];
    float* out = (float*)d_out;

    const int N = in_sizes[0] / DD;   // 30000
    const int E = in_sizes[1] / 2;    // 480000
    const int* idx_i = edge_idx;
    const int* idx_j = edge_idx + E;

    const size_t nd = (size_t)N * DD;
    float* ws      = (float*)d_ws;
    float* x_proj  = ws;
    float* h_atom  = x_proj + nd;
    float* head    = h_atom + nd;
    float* sum_agg = head + nd;
    int*   max_agg = (int*)(sum_agg + nd);
    float* PQ      = (float*)(max_agg + nd);   // 2N x 128
    int*   cnt     = (int*)(PQ + 2 * nd);
    int*   cursor  = cnt + N;
    int*   bsum    = cursor + N;
    int*   perm    = bsum + 256;
    int*   si      = perm + E;
    int*   sj      = si + E;

    // ---- counting sort of edges by idx_i ----
    hipMemsetAsync(cnt, 0, (size_t)N * 4, stream);
    hist_kernel<<<(E + 255) / 256, 256, 0, stream>>>(idx_i, cnt, E);
    const int nb_scan = (N + SCB - 1) / SCB;
    scan1_kernel<<<nb_scan, SCB, 0, stream>>>(cnt, cursor, bsum, N);
    scan2_kernel<<<1, SCB, 0, stream>>>(bsum, nb_scan);
    scan3_kernel<<<nb_scan, SCB, 0, stream>>>(cursor, bsum, N);
    scatter_kernel<<<(E + 255) / 256, 256, 0, stream>>>(idx_i, idx_j, cursor, perm, si, sj, E);

    hipMemsetAsync(sum_agg, 0, nd * 4, stream);
    hipMemsetAsync(max_agg, 0, nd * 4, stream);

    // node projection via MFMA: x_proj = h_atom = relu(x @ W_atom + b_atom)
    const int ntiles_n = (N + 127) / 128;
    gemm128_mfma_kernel<<<min(ntiles_n, 256), 1024, 0, stream>>>(
        (float*)x, x, N, N, W_atom, b_atom, N, 1, 0, nullptr, nullptr,
        x_proj, h_atom, ntiles_n);

    // bond projection + layer-0 aggregation (v4: edge_pass-style)
    bond_pass_kernel<<<(E + CB - 1) / CB, 256, 0, stream>>>(
        edge_attr, W_bond, b_bond, si, perm, head, sum_agg, max_agg, E, N);

    const int ntiles_pq = (2 * N + 127) / 128;
    const int ep_blocks = (E + CE - 1) / CE;
    for (int l = 0; l < 3; ++l) {
        gemm128_mfma_kernel<<<256, 1024, 0, stream>>>(
            h_atom, head, N, 2 * N, W_seq + (size_t)l * DD * DD,
            b_seq + (size_t)l * DD, N, 0, 1, sum_agg, max_agg,
            PQ, nullptr, ntiles_pq);
        edge_pass_kernel<<<ep_blocks, 256, 0, stream>>>(
            PQ, si, sj, perm, head, (l < 2) ? 1 : 0, sum_agg, max_agg, E, N);
    }

    final_mfma_kernel<<<(N + 127) / 128, 512, 0, stream>>>(
        h_atom, sum_agg, (const int*)max_agg, x_proj, W_lin, b_lin, out, N);
}

// Round 11
// 396.269 us; speedup vs baseline: 1.1514x; 1.0846x over previous
//
#include <hip/hip_runtime.h>
#include <hip/hip_bf16.h>

#define DD 128   // hidden dim
#define SCB 256  // scan block size
#define CE  512  // edges per block in edge_pass (8 waves x 64)
#define CB  512  // edges per block in bond pass (4 waves x 128)

typedef __attribute__((ext_vector_type(8))) short bf16x8;
typedef __attribute__((ext_vector_type(4))) float f32x4;

__device__ __forceinline__ unsigned bf16_rne(float f) {
    unsigned u = __float_as_uint(f);
    return (u + 0x7fffu + ((u >> 16) & 1u)) >> 16;
}

// ---------------------------------------------------------------------------
// counting-sort preprocessing (sort edges by idx_i)
// ---------------------------------------------------------------------------
__global__ __launch_bounds__(256)
void hist_kernel(const int* __restrict__ idx_i, int* __restrict__ cnt, int E)
{
    const int e = blockIdx.x * 256 + threadIdx.x;
    if (e < E) atomicAdd(&cnt[idx_i[e]], 1);
}

__global__ __launch_bounds__(SCB)
void scan1_kernel(const int* __restrict__ cnt, int* __restrict__ exc,
                  int* __restrict__ bsum, int n)
{
    __shared__ int s[SCB];
    const int i = blockIdx.x * SCB + (int)threadIdx.x;
    const int v = (i < n) ? cnt[i] : 0;
    s[threadIdx.x] = v;
    __syncthreads();
    #pragma unroll
    for (int off = 1; off < SCB; off <<= 1) {
        int t = (threadIdx.x >= off) ? s[threadIdx.x - off] : 0;
        __syncthreads();
        s[threadIdx.x] += t;
        __syncthreads();
    }
    if (i < n) exc[i] = s[threadIdx.x] - v;
    if (threadIdx.x == SCB - 1) bsum[blockIdx.x] = s[threadIdx.x];
}

__global__ __launch_bounds__(SCB)
void scan2_kernel(int* __restrict__ bsum, int nb)
{
    __shared__ int s[SCB];
    const int v = (threadIdx.x < nb) ? bsum[threadIdx.x] : 0;
    s[threadIdx.x] = v;
    __syncthreads();
    #pragma unroll
    for (int off = 1; off < SCB; off <<= 1) {
        int t = (threadIdx.x >= off) ? s[threadIdx.x - off] : 0;
        __syncthreads();
        s[threadIdx.x] += t;
        __syncthreads();
    }
    if (threadIdx.x < nb) bsum[threadIdx.x] = s[threadIdx.x] - v;
}

__global__ __launch_bounds__(SCB)
void scan3_kernel(int* __restrict__ exc, const int* __restrict__ bsum, int n)
{
    const int i = blockIdx.x * SCB + (int)threadIdx.x;
    if (i < n) exc[i] += bsum[i >> 8];
}

__global__ __launch_bounds__(256)
void scatter_kernel(const int* __restrict__ idx_i, const int* __restrict__ idx_j,
                    int* __restrict__ cursor, int* __restrict__ perm,
                    int* __restrict__ si, int* __restrict__ sj, int E)
{
    const int e = blockIdx.x * 256 + threadIdx.x;
    if (e < E) {
        const int n = idx_i[e];
        const int p = atomicAdd(&cursor[n], 1);
        perm[p] = e;
        si[p] = n;
        sj[p] = idx_j[e];
    }
}

// ---------------------------------------------------------------------------
// generic 128-K split-bf16 MFMA GEMM with optional fused node-update
// (unchanged)
// ---------------------------------------------------------------------------
__global__ __launch_bounds__(1024)
void gemm128_mfma_kernel(float* __restrict__ A0, const float* __restrict__ A1,
                         int nA, int nTotal,
                         const float* __restrict__ W, const float* __restrict__ bias,
                         int bias_limit, int do_relu, int update,
                         float* __restrict__ sum_agg, int* __restrict__ max_agg,
                         float* __restrict__ out0, float* __restrict__ out1,
                         int ntiles)
{
    __shared__ __align__(16) unsigned char SM[131584];
    char*  const Whi = (char*)SM;
    char*  const Wlo = (char*)SM + 32768;
    char*  const Ahi = (char*)SM + 65536;
    char*  const Alo = (char*)SM + 98304;
    float* const Wf  = (float*)(SM + 65536);
    float* const bs  = (float*)(SM + 131072);

    const int t = (int)threadIdx.x;

    {
        const float4* Wg = (const float4*)W;
        float4* Wd = (float4*)Wf;
        #pragma unroll
        for (int i = 0; i < 4; ++i) Wd[t + i * 1024] = Wg[t + i * 1024];
        if (t < DD) bs[t] = bias ? bias[t] : 0.f;
    }
    __syncthreads();
    {
        const int col = t >> 3;
        const int kb  = (t & 7) * 16;
        unsigned h16[16], l16[16];
        #pragma unroll
        for (int j = 0; j < 16; ++j) {
            const float w = Wf[(size_t)(kb + j) * DD + col];
            const unsigned hb = bf16_rne(w);
            const float hf = __uint_as_float(hb << 16);
            h16[j] = hb;
            l16[j] = bf16_rne(w - hf);
        }
        #pragma unroll
        for (int c = 0; c < 2; ++c) {
            uint4 ph, pl;
            ph.x = h16[c*8+0] | (h16[c*8+1] << 16);
            ph.y = h16[c*8+2] | (h16[c*8+3] << 16);
            ph.z = h16[c*8+4] | (h16[c*8+5] << 16);
            ph.w = h16[c*8+6] | (h16[c*8+7] << 16);
            pl.x = l16[c*8+0] | (l16[c*8+1] << 16);
            pl.y = l16[c*8+2] | (l16[c*8+3] << 16);
            pl.z = l16[c*8+4] | (l16[c*8+5] << 16);
            pl.w = l16[c*8+6] | (l16[c*8+7] << 16);
            const int off = ((col * 256 + (kb + c * 8) * 2)) ^ ((col & 7) << 4);
            *(uint4*)(Whi + off) = ph;
            *(uint4*)(Wlo + off) = pl;
        }
    }

    const int w  = t >> 6;
    const int l  = t & 63;
    const int wm = w >> 2;
    const int wn = w & 3;
    const int g  = l >> 4;
    const int q  = l & 15;

    for (int tile = blockIdx.x; tile < ntiles; tile += gridDim.x) {
        const int e0 = tile * 128;
        __syncthreads();

        #pragma unroll
        for (int i = 0; i < 2; ++i) {
            const int task = t + i * 1024;
            const int row  = task >> 4;
            const int c    = task & 15;
            const int rr = min(e0 + row, nTotal - 1);
            float d[8];
            if (rr < nA) {
                float* ph0 = A0 + (size_t)rr * DD + c * 8;
                const float4 a0 = *(const float4*)ph0;
                const float4 a1 = *(const float4*)(ph0 + 4);
                if (update) {
                    float* sp = sum_agg + (size_t)rr * DD + c * 8;
                    int*   mp = max_agg + (size_t)rr * DD + c * 8;
                    const float4 s0 = *(const float4*)sp;
                    const float4 s1 = *(const float4*)(sp + 4);
                    const int4   m0 = *(const int4*)mp;
                    const int4   m1 = *(const int4*)(mp + 4);
                    d[0] = a0.x * s0.x * __int_as_float(m0.x);
                    d[1] = a0.y * s0.y * __int_as_float(m0.y);
                    d[2] = a0.z * s0.z * __int_as_float(m0.z);
                    d[3] = a0.w * s0.w * __int_as_float(m0.w);
                    d[4] = a1.x * s1.x * __int_as_float(m1.x);
                    d[5] = a1.y * s1.y * __int_as_float(m1.y);
                    d[6] = a1.z * s1.z * __int_as_float(m1.z);
                    d[7] = a1.w * s1.w * __int_as_float(m1.w);
                    *(float4*)ph0       = make_float4(d[0], d[1], d[2], d[3]);
                    *(float4*)(ph0 + 4) = make_float4(d[4], d[5], d[6], d[7]);
                    *(float4*)sp       = make_float4(0.f, 0.f, 0.f, 0.f);
                    *(float4*)(sp + 4) = make_float4(0.f, 0.f, 0.f, 0.f);
                    *(int4*)mp       = make_int4(0, 0, 0, 0);
                    *(int4*)(mp + 4) = make_int4(0, 0, 0, 0);
                } else {
                    d[0] = a0.x; d[1] = a0.y; d[2] = a0.z; d[3] = a0.w;
                    d[4] = a1.x; d[5] = a1.y; d[6] = a1.z; d[7] = a1.w;
                }
            } else {
                const float* pa = A1 + (size_t)(rr - nA) * DD + c * 8;
                const float4 a0 = *(const float4*)pa;
                const float4 a1 = *(const float4*)(pa + 4);
                d[0] = a0.x; d[1] = a0.y; d[2] = a0.z; d[3] = a0.w;
                d[4] = a1.x; d[5] = a1.y; d[6] = a1.z; d[7] = a1.w;
            }
            unsigned h8[8], l8[8];
            #pragma unroll
            for (int j = 0; j < 8; ++j) {
                const unsigned hb = bf16_rne(d[j]);
                const float hf = __uint_as_float(hb << 16);
                h8[j] = hb;
                l8[j] = bf16_rne(d[j] - hf);
            }
            uint4 ph, pl;
            ph.x = h8[0] | (h8[1] << 16);
            ph.y = h8[2] | (h8[3] << 16);
            ph.z = h8[4] | (h8[5] << 16);
            ph.w = h8[6] | (h8[7] << 16);
            pl.x = l8[0] | (l8[1] << 16);
            pl.y = l8[2] | (l8[3] << 16);
            pl.z = l8[4] | (l8[5] << 16);
            pl.w = l8[6] | (l8[7] << 16);
            const int off = ((row * 256 + c * 16)) ^ ((row & 7) << 4);
            *(uint4*)(Ahi + off) = ph;
            *(uint4*)(Alo + off) = pl;
        }
        __syncthreads();

        f32x4 acc[2][2];
        const f32x4 zero = {0.f, 0.f, 0.f, 0.f};
        acc[0][0] = zero; acc[0][1] = zero; acc[1][0] = zero; acc[1][1] = zero;

        #pragma unroll
        for (int ks = 0; ks < 4; ++ks) {
            const int kbyte = ks * 64 + g * 16;
            bf16x8 ah[2], al[2], bh[2], bl[2];
            #pragma unroll
            for (int m = 0; m < 2; ++m) {
                const int row = wm * 32 + m * 16 + q;
                const int off = (row * 256 + kbyte) ^ ((row & 7) << 4);
                ah[m] = *(const bf16x8*)(Ahi + off);
                al[m] = *(const bf16x8*)(Alo + off);
            }
            #pragma unroll
            for (int n = 0; n < 2; ++n) {
                const int colv = wn * 32 + n * 16 + q;
                const int off = (colv * 256 + kbyte) ^ ((colv & 7) << 4);
                bh[n] = *(const bf16x8*)(Whi + off);
                bl[n] = *(const bf16x8*)(Wlo + off);
            }
            #pragma unroll
            for (int m = 0; m < 2; ++m)
                #pragma unroll
                for (int n = 0; n < 2; ++n)
                    acc[m][n] = __builtin_amdgcn_mfma_f32_16x16x32_bf16(ah[m], bh[n], acc[m][n], 0, 0, 0);
            #pragma unroll
            for (int m = 0; m < 2; ++m)
                #pragma unroll
                for (int n = 0; n < 2; ++n)
                    acc[m][n] = __builtin_amdgcn_mfma_f32_16x16x32_bf16(ah[m], bl[n], acc[m][n], 0, 0, 0);
            #pragma unroll
            for (int m = 0; m < 2; ++m)
                #pragma unroll
                for (int n = 0; n < 2; ++n)
                    acc[m][n] = __builtin_amdgcn_mfma_f32_16x16x32_bf16(al[m], bh[n], acc[m][n], 0, 0, 0);
        }

        #pragma unroll
        for (int n = 0; n < 2; ++n) {
            const int colv = wn * 32 + n * 16 + q;
            const float bv = bs[colv];
            #pragma unroll
            for (int m = 0; m < 2; ++m) {
                #pragma unroll
                for (int r = 0; r < 4; ++r) {
                    const int row = e0 + wm * 32 + m * 16 + g * 4 + r;
                    if (row < nTotal) {
                        float v = acc[m][n][r] + ((row < bias_limit) ? bv : 0.f);
                        if (do_relu) v = fmaxf(v, 0.f);
                        out0[(size_t)row * DD + colv] = v;
                        if (out1) out1[(size_t)row * DD + colv] = v;
                    }
                }
            }
        }
    }
}

// ---------------------------------------------------------------------------
// bond pass v4 (unchanged from R10 — proven win)
// ---------------------------------------------------------------------------
__global__ __launch_bounds__(256)
void bond_pass_kernel(const float* __restrict__ edge_attr,
                      const float* __restrict__ Wb, const float* __restrict__ bb,
                      const int* __restrict__ si, const int* __restrict__ perm,
                      float* __restrict__ h_head0,
                      float* __restrict__ sum_agg, int* __restrict__ max_agg,
                      int E, int N)
{
    __shared__ __align__(16) float ea_s[CB][16];   // 32 KB
    __shared__ int si_s[CB], pm_s[CB];             // 4 KB

    const int p0b = blockIdx.x * CB;
    if (p0b >= E) return;
    const int t = (int)threadIdx.x;

    for (int i = t; i < CB; i += 256) {
        const int p = min(p0b + i, E - 1);
        si_s[i] = si[p];
        pm_s[i] = perm[p];
    }
    for (int task = t; task < CB * 4; task += 256) {
        const int row = task >> 2;
        const int c4  = task & 3;
        const int p = min(p0b + row, E - 1);
        const int orig = perm[p];
        *(float4*)(&ea_s[row][c4 * 4]) =
            *(const float4*)(edge_attr + (size_t)orig * 16 + c4 * 4);
    }
    __syncthreads();

    const int w    = t >> 6;
    const int lane = t & 63;
    const int c    = lane * 2;
    const int q0   = w * 128;
    const int pg0  = p0b + q0;
    if (pg0 >= E) return;

    float wc0[16], wc1[16];
    #pragma unroll
    for (int k = 0; k < 16; ++k) {
        const float2 wv = *(const float2*)(Wb + k * DD + c);
        wc0[k] = wv.x; wc1[k] = wv.y;
    }
    const float2 bc = *(const float2*)(bb + c);

    const int firstNode = si_s[q0];
    const int lastNode  = si_s[q0 + 127];

    int curNode = firstNode;
    float2 rs = make_float2(0.f, 0.f), rm = make_float2(0.f, 0.f);

    #define BP_FLUSH()                                                           \
    {                                                                            \
        if (curNode == firstNode || curNode == lastNode) {                       \
            atomicAdd(&sum_agg[(size_t)curNode * DD + c],     rs.x);             \
            atomicAdd(&sum_agg[(size_t)curNode * DD + c + 1], rs.y);             \
            atomicMax(&max_agg[(size_t)curNode * DD + c],     __float_as_int(rm.x)); \
            atomicMax(&max_agg[(size_t)curNode * DD + c + 1], __float_as_int(rm.y)); \
        } else {                                                                 \
            *(float2*)(sum_agg + (size_t)curNode * DD + c) = rs;                 \
            *(int2*)(max_agg + (size_t)curNode * DD + c) =                       \
                make_int2(__float_as_int(rm.x), __float_as_int(rm.y));           \
        }                                                                        \
    }

    #pragma unroll 4
    for (int kk = 0; kk < 128; ++kk) {
        const int i = si_s[q0 + kk];
        if (i != curNode) {
            BP_FLUSH();
            curNode = i;
            rs = make_float2(0.f, 0.f);
            rm = make_float2(0.f, 0.f);
        }
        const float4* ear = (const float4*)(&ea_s[q0 + kk][0]);
        const float4 e0 = ear[0], e1 = ear[1], e2 = ear[2], e3 = ear[3];
        float ax = bc.x, ay = bc.y;
        ax = fmaf(e0.x, wc0[ 0], ax);  ay = fmaf(e0.x, wc1[ 0], ay);
        ax = fmaf(e0.y, wc0[ 1], ax);  ay = fmaf(e0.y, wc1[ 1], ay);
        ax = fmaf(e0.z, wc0[ 2], ax);  ay = fmaf(e0.z, wc1[ 2], ay);
        ax = fmaf(e0.w, wc0[ 3], ax);  ay = fmaf(e0.w, wc1[ 3], ay);
        ax = fmaf(e1.x, wc0[ 4], ax);  ay = fmaf(e1.x, wc1[ 4], ay);
        ax = fmaf(e1.y, wc0[ 5], ax);  ay = fmaf(e1.y, wc1[ 5], ay);
        ax = fmaf(e1.z, wc0[ 6], ax);  ay = fmaf(e1.z, wc1[ 6], ay);
        ax = fmaf(e1.w, wc0[ 7], ax);  ay = fmaf(e1.w, wc1[ 7], ay);
        ax = fmaf(e2.x, wc0[ 8], ax);  ay = fmaf(e2.x, wc1[ 8], ay);
        ax = fmaf(e2.y, wc0[ 9], ax);  ay = fmaf(e2.y, wc1[ 9], ay);
        ax = fmaf(e2.z, wc0[10], ax);  ay = fmaf(e2.z, wc1[10], ay);
        ax = fmaf(e2.w, wc0[11], ax);  ay = fmaf(e2.w, wc1[11], ay);
        ax = fmaf(e3.x, wc0[12], ax);  ay = fmaf(e3.x, wc1[12], ay);
        ax = fmaf(e3.y, wc0[13], ax);  ay = fmaf(e3.y, wc1[13], ay);
        ax = fmaf(e3.z, wc0[14], ax);  ay = fmaf(e3.z, wc1[14], ay);
        ax = fmaf(e3.w, wc0[15], ax);  ay = fmaf(e3.w, wc1[15], ay);
        float2 v;
        v.x = fmaxf(ax, 0.f);
        v.y = fmaxf(ay, 0.f);
        if (pg0 + kk >= E) { v.x = 0.f; v.y = 0.f; }
        rs.x += v.x; rs.y += v.y;
        rm.x = fmaxf(rm.x, v.x); rm.y = fmaxf(rm.y, v.y);
        if (pg0 + kk < E) {
            const int orig = pm_s[q0 + kk];
            if (orig < N) *(float2*)(h_head0 + (size_t)orig * DD + c) = v;
        }
    }
    BP_FLUSH();
    #undef BP_FLUSH
}

// ---------------------------------------------------------------------------
// edge pass v4: 8 waves x 64 edges (2x wave count vs v3) + 8-deep prefetch
// (2x outstanding loads). Segmented ownership unchanged: interior nodes =
// plain stores, boundary (first/last of wave-chunk) = atomics.
// ---------------------------------------------------------------------------
__global__ __launch_bounds__(512)
void edge_pass_kernel(const float* __restrict__ PQ,
                      const int* __restrict__ si, const int* __restrict__ sj,
                      const int* __restrict__ perm,
                      float* __restrict__ head_next, int store_head,
                      float* __restrict__ sum_agg, int* __restrict__ max_agg,
                      int E, int N)
{
    __shared__ int si_s[CE], sj_s[CE], pm_s[CE];
    const int p0b = blockIdx.x * CE;
    if (p0b >= E) return;
    const int t = (int)threadIdx.x;
    for (int i = t; i < CE; i += 512) {
        const int p = min(p0b + i, E - 1);
        si_s[i] = si[p];
        sj_s[i] = sj[p];
        pm_s[i] = perm[p];
    }
    __syncthreads();

    const int w    = t >> 6;         // wave 0..7
    const int lane = t & 63;
    const int c    = lane * 2;
    const int q0   = w * 64;         // wave's first local edge
    const int pg0  = p0b + q0;
    if (pg0 >= E) return;

    const int firstNode = si_s[q0];
    const int lastNode  = si_s[q0 + 63];

    const float* __restrict__ Qbase = PQ + (size_t)N * DD + c;

    // 8-deep prefetch pipeline, statically indexed (manual rotation)
    float2 qa = *(const float2*)(Qbase + (size_t)sj_s[q0 + 0] * DD);
    float2 qb = *(const float2*)(Qbase + (size_t)sj_s[q0 + 1] * DD);
    float2 qc = *(const float2*)(Qbase + (size_t)sj_s[q0 + 2] * DD);
    float2 qd = *(const float2*)(Qbase + (size_t)sj_s[q0 + 3] * DD);
    float2 qe = *(const float2*)(Qbase + (size_t)sj_s[q0 + 4] * DD);
    float2 qf = *(const float2*)(Qbase + (size_t)sj_s[q0 + 5] * DD);
    float2 qg = *(const float2*)(Qbase + (size_t)sj_s[q0 + 6] * DD);
    float2 qh = *(const float2*)(Qbase + (size_t)sj_s[q0 + 7] * DD);

    int curNode = firstNode;
    float2 Pi = *(const float2*)(PQ + (size_t)curNode * DD + c);
    float2 rs = make_float2(0.f, 0.f), rm = make_float2(0.f, 0.f);

    #define EP_FLUSH()                                                           \
    {                                                                            \
        if (curNode == firstNode || curNode == lastNode) {                       \
            atomicAdd(&sum_agg[(size_t)curNode * DD + c],     rs.x);             \
            atomicAdd(&sum_agg[(size_t)curNode * DD + c + 1], rs.y);             \
            atomicMax(&max_agg[(size_t)curNode * DD + c],     __float_as_int(rm.x)); \
            atomicMax(&max_agg[(size_t)curNode * DD + c + 1], __float_as_int(rm.y)); \
        } else {                                                                 \
            *(float2*)(sum_agg + (size_t)curNode * DD + c) = rs;                 \
            *(int2*)(max_agg + (size_t)curNode * DD + c) =                       \
                make_int2(__float_as_int(rm.x), __float_as_int(rm.y));           \
        }                                                                        \
    }

    #define EP_STEP(K, QREG)                                                     \
    {                                                                            \
        const int kk = (K);                                                      \
        const int i = si_s[q0 + kk];                                             \
        if (i != curNode) {                                                      \
            EP_FLUSH();                                                          \
            curNode = i;                                                         \
            Pi = *(const float2*)(PQ + (size_t)i * DD + c);                      \
            rs = make_float2(0.f, 0.f);                                          \
            rm = make_float2(0.f, 0.f);                                          \
        }                                                                        \
        float2 v;                                                                \
        v.x = fmaxf(Pi.x - QREG.x, 0.f);                                         \
        v.y = fmaxf(Pi.y - QREG.y, 0.f);                                         \
        if (pg0 + kk >= E) { v.x = 0.f; v.y = 0.f; }                             \
        rs.x += v.x; rs.y += v.y;                                                \
        rm.x = fmaxf(rm.x, v.x); rm.y = fmaxf(rm.y, v.y);                        \
        if (store_head && (pg0 + kk) < E) {                                      \
            const int orig = pm_s[q0 + kk];                                      \
            if (orig < N) *(float2*)(head_next + (size_t)orig * DD + c) = v;     \
        }                                                                        \
        if (kk + 8 < 64)                                                         \
            QREG = *(const float2*)(Qbase + (size_t)sj_s[q0 + kk + 8] * DD);     \
    }

    #pragma unroll
    for (int k = 0; k < 64; k += 8) {
        EP_STEP(k + 0, qa);
        EP_STEP(k + 1, qb);
        EP_STEP(k + 2, qc);
        EP_STEP(k + 3, qd);
        EP_STEP(k + 4, qe);
        EP_STEP(k + 5, qf);
        EP_STEP(k + 6, qg);
        EP_STEP(k + 7, qh);
    }
    EP_FLUSH();   // final run: curNode == lastNode -> atomic path
    #undef EP_STEP
    #undef EP_FLUSH
}

// ---------------------------------------------------------------------------
// final: out = [ha, x_proj] @ W_lin + b_lin via split-bf16 MFMA, K=256
// (unchanged)
// ---------------------------------------------------------------------------
__global__ __launch_bounds__(512, 2)
void final_mfma_kernel(const float* __restrict__ h, const float* __restrict__ sum_agg,
                       const int* __restrict__ max_agg, const float* __restrict__ xp,
                       const float* __restrict__ Wl, const float* __restrict__ bl,
                       float* __restrict__ out, int N)
{
    __shared__ __align__(16) unsigned char SM[65808];
    char*  const Whi = (char*)SM;
    char*  const Wlo = (char*)SM + 32768;
    float* const Wf  = (float*)SM;
    float* const bs  = (float*)(SM + 65536);

    const int t = (int)threadIdx.x;
    {
        const float4* Wg = (const float4*)Wl;
        float4* Wd = (float4*)Wf;
        #pragma unroll
        for (int i = 0; i < 8; ++i) Wd[t + i * 512] = Wg[t + i * 512];
        if (t < 64) bs[t] = bl[t];
    }
    __syncthreads();
    {
        const int col = t & 63;
        const int kb  = (t >> 6) * 32;
        float v[32];
        #pragma unroll
        for (int j = 0; j < 32; ++j) v[j] = Wf[(size_t)(kb + j) * 64 + col];
        __syncthreads();
        #pragma unroll
        for (int c = 0; c < 4; ++c) {
            unsigned h8[8], l8[8];
            #pragma unroll
            for (int j = 0; j < 8; ++j) {
                const float w0 = v[c * 8 + j];
                const unsigned hb = bf16_rne(w0);
                h8[j] = hb;
                l8[j] = bf16_rne(w0 - __uint_as_float(hb << 16));
            }
            uint4 ph, pl;
            ph.x = h8[0] | (h8[1] << 16); ph.y = h8[2] | (h8[3] << 16);
            ph.z = h8[4] | (h8[5] << 16); ph.w = h8[6] | (h8[7] << 16);
            pl.x = l8[0] | (l8[1] << 16); pl.y = l8[2] | (l8[3] << 16);
            pl.z = l8[4] | (l8[5] << 16); pl.w = l8[6] | (l8[7] << 16);
            const int off = (col * 512 + (kb + c * 8) * 2) ^ ((col & 7) << 4);
            *(uint4*)(Whi + off) = ph;
            *(uint4*)(Wlo + off) = pl;
        }
    }
    __syncthreads();

    const int w  = t >> 6;
    const int l  = t & 63;
    const int wm = w >> 1;
    const int wn = w & 1;
    const int g  = l >> 4;
    const int q  = l & 15;
    const int r0 = (int)blockIdx.x * 128;

    f32x4 acc[2][2];
    const f32x4 zero = {0.f, 0.f, 0.f, 0.f};
    acc[0][0] = zero; acc[0][1] = zero; acc[1][0] = zero; acc[1][1] = zero;

    #pragma unroll
    for (int ks = 0; ks < 8; ++ks) {
        const int kf = (ks & 3) * 32 + g * 8;
        bf16x8 ah[2], al[2];
        #pragma unroll
        for (int m = 0; m < 2; ++m) {
            const int rr = min(r0 + wm * 32 + m * 16 + q, N - 1);
            float d[8];
            if (ks < 4) {
                const float* ph = h       + (size_t)rr * DD + kf;
                const float* ps = sum_agg + (size_t)rr * DD + kf;
                const int*   pm = max_agg + (size_t)rr * DD + kf;
                const float4 a0 = *(const float4*)ph;
                const float4 a1 = *(const float4*)(ph + 4);
                const float4 s0 = *(const float4*)ps;
                const float4 s1 = *(const float4*)(ps + 4);
                const int4   i0 = *(const int4*)pm;
                const int4   i1 = *(const int4*)(pm + 4);
                d[0] = a0.x * a0.x * s0.x * __int_as_float(i0.x);
                d[1] = a0.y * a0.y * s0.y * __int_as_float(i0.y);
                d[2] = a0.z * a0.z * s0.z * __int_as_float(i0.z);
                d[3] = a0.w * a0.w * s0.w * __int_as_float(i0.w);
                d[4] = a1.x * a1.x * s1.x * __int_as_float(i1.x);
                d[5] = a1.y * a1.y * s1.y * __int_as_float(i1.y);
                d[6] = a1.z * a1.z * s1.z * __int_as_float(i1.z);
                d[7] = a1.w * a1.w * s1.w * __int_as_float(i1.w);
            } else {
                const float* pa = xp + (size_t)rr * DD + kf;
                const float4 a0 = *(const float4*)pa;
                const float4 a1 = *(const float4*)(pa + 4);
                d[0] = a0.x; d[1] = a0.y; d[2] = a0.z; d[3] = a0.w;
                d[4] = a1.x; d[5] = a1.y; d[6] = a1.z; d[7] = a1.w;
            }
            unsigned h8[8], l8[8];
            #pragma unroll
            for (int j = 0; j < 8; ++j) {
                const unsigned hb = bf16_rne(d[j]);
                h8[j] = hb;
                l8[j] = bf16_rne(d[j] - __uint_as_float(hb << 16));
            }
            uint4 ph2, pl2;
            ph2.x = h8[0] | (h8[1] << 16); ph2.y = h8[2] | (h8[3] << 16);
            ph2.z = h8[4] | (h8[5] << 16); ph2.w = h8[6] | (h8[7] << 16);
            pl2.x = l8[0] | (l8[1] << 16); pl2.y = l8[2] | (l8[3] << 16);
            pl2.z = l8[4] | (l8[5] << 16); pl2.w = l8[6] | (l8[7] << 16);
            ah[m] = *(bf16x8*)&ph2;
            al[m] = *(bf16x8*)&pl2;
        }
        bf16x8 bh[2], blo[2];
        #pragma unroll
        for (int n = 0; n < 2; ++n) {
            const int colv = wn * 32 + n * 16 + q;
            const int off = (colv * 512 + ks * 64 + g * 16) ^ ((colv & 7) << 4);
            bh[n]  = *(const bf16x8*)(Whi + off);
            blo[n] = *(const bf16x8*)(Wlo + off);
        }
        #pragma unroll
        for (int m = 0; m < 2; ++m)
            #pragma unroll
            for (int n = 0; n < 2; ++n) {
                acc[m][n] = __builtin_amdgcn_mfma_f32_16x16x32_bf16(ah[m], bh[n],  acc[m][n], 0, 0, 0);
                acc[m][n] = __builtin_amdgcn_mfma_f32_16x16x32_bf16(ah[m], blo[n], acc[m][n], 0, 0, 0);
                acc[m][n] = __builtin_amdgcn_mfma_f32_16x16x32_bf16(al[m], bh[n],  acc[m][n], 0, 0, 0);
            }
    }

    #pragma unroll
    for (int n = 0; n < 2; ++n) {
        const int colv = wn * 32 + n * 16 + q;
        const float bv = bs[colv];
        #pragma unroll
        for (int m = 0; m < 2; ++m) {
            #pragma unroll
            for (int r = 0; r < 4; ++r) {
                const int row = r0 + wm * 32 + m * 16 + g * 4 + r;
                if (row < N) out[(size_t)row * 64 + colv] = acc[m][n][r] + bv;
            }
        }
    }
}

// ---------------------------------------------------------------------------
extern "C" void kernel_launch(void* const* d_in, const int* in_sizes, int n_in,
                              void* d_out, int out_size, void* d_ws, size_t ws_size,
                              hipStream_t stream)
{
    const float* x         = (const float*)d_in[0];
    const int*   edge_idx  = (const int*)d_in[1];
    const float* edge_attr = (const float*)d_in[2];
    const float* W_atom    = (const float*)d_in[3];
    const float* b_atom    = (const float*)d_in[4];
    const float* W_bond    = (const float*)d_in[5];
    const float* b_bond    = (const float*)d_in[6];
    const float* W_seq     = (const float*)d_in[7];
    const float* b_seq     = (const float*)d_in[8];
    const float* W_lin     = (const float*)d_in[9];
    const float* b_lin     = (const float*)d_in[10];
    float* out = (float*)d_out;

    const int N = in_sizes[0] / DD;   // 30000
    const int E = in_sizes[1] / 2;    // 480000
    const int* idx_i = edge_idx;
    const int* idx_j = edge_idx + E;

    const size_t nd = (size_t)N * DD;
    float* ws      = (float*)d_ws;
    float* x_proj  = ws;
    float* h_atom  = x_proj + nd;
    float* head    = h_atom + nd;
    float* sum_agg = head + nd;
    int*   max_agg = (int*)(sum_agg + nd);
    float* PQ      = (float*)(max_agg + nd);   // 2N x 128
    int*   cnt     = (int*)(PQ + 2 * nd);
    int*   cursor  = cnt + N;
    int*   bsum    = cursor + N;
    int*   perm    = bsum + 256;
    int*   si      = perm + E;
    int*   sj      = si + E;

    // ---- counting sort of edges by idx_i ----
    hipMemsetAsync(cnt, 0, (size_t)N * 4, stream);
    hist_kernel<<<(E + 255) / 256, 256, 0, stream>>>(idx_i, cnt, E);
    const int nb_scan = (N + SCB - 1) / SCB;
    scan1_kernel<<<nb_scan, SCB, 0, stream>>>(cnt, cursor, bsum, N);
    scan2_kernel<<<1, SCB, 0, stream>>>(bsum, nb_scan);
    scan3_kernel<<<nb_scan, SCB, 0, stream>>>(cursor, bsum, N);
    scatter_kernel<<<(E + 255) / 256, 256, 0, stream>>>(idx_i, idx_j, cursor, perm, si, sj, E);

    hipMemsetAsync(sum_agg, 0, nd * 4, stream);
    hipMemsetAsync(max_agg, 0, nd * 4, stream);

    // node projection via MFMA: x_proj = h_atom = relu(x @ W_atom + b_atom)
    const int ntiles_n = (N + 127) / 128;
    gemm128_mfma_kernel<<<min(ntiles_n, 256), 1024, 0, stream>>>(
        (float*)x, x, N, N, W_atom, b_atom, N, 1, 0, nullptr, nullptr,
        x_proj, h_atom, ntiles_n);

    // bond projection + layer-0 aggregation
    bond_pass_kernel<<<(E + CB - 1) / CB, 256, 0, stream>>>(
        edge_attr, W_bond, b_bond, si, perm, head, sum_agg, max_agg, E, N);

    const int ntiles_pq = (2 * N + 127) / 128;
    const int ep_blocks = (E + CE - 1) / CE;
    for (int l = 0; l < 3; ++l) {
        gemm128_mfma_kernel<<<256, 1024, 0, stream>>>(
            h_atom, head, N, 2 * N, W_seq + (size_t)l * DD * DD,
            b_seq + (size_t)l * DD, N, 0, 1, sum_agg, max_agg,
            PQ, nullptr, ntiles_pq);
        edge_pass_kernel<<<ep_blocks, 512, 0, stream>>>(
            PQ, si, sj, perm, head, (l < 2) ? 1 : 0, sum_agg, max_agg, E, N);
    }

    final_mfma_kernel<<<(N + 127) / 128, 512, 0, stream>>>(
        h_atom, sum_agg, (const int*)max_agg, x_proj, W_lin, b_lin, out, N);
}

// Round 12
// 395.335 us; speedup vs baseline: 1.1541x; 1.0024x over previous
//
#include <hip/hip_runtime.h>
#include <hip/hip_bf16.h>

#define DD 128   // hidden dim
#define SCB 256  // scan block size
#define CE  512  // edges per block in edge_pass (8 waves x 64)
#define CB  512  // edges per block in bond pass (8 waves x 64)

typedef __attribute__((ext_vector_type(8))) short bf16x8;
typedef __attribute__((ext_vector_type(4))) float f32x4;

__device__ __forceinline__ unsigned bf16_rne(float f) {
    unsigned u = __float_as_uint(f);
    return (u + 0x7fffu + ((u >> 16) & 1u)) >> 16;
}

// ---------------------------------------------------------------------------
// counting-sort preprocessing (sort edges by idx_i)
// ---------------------------------------------------------------------------
__global__ __launch_bounds__(256)
void hist_kernel(const int* __restrict__ idx_i, int* __restrict__ cnt, int E)
{
    const int e = blockIdx.x * 256 + threadIdx.x;
    if (e < E) atomicAdd(&cnt[idx_i[e]], 1);
}

__global__ __launch_bounds__(SCB)
void scan1_kernel(const int* __restrict__ cnt, int* __restrict__ exc,
                  int* __restrict__ bsum, int n)
{
    __shared__ int s[SCB];
    const int i = blockIdx.x * SCB + (int)threadIdx.x;
    const int v = (i < n) ? cnt[i] : 0;
    s[threadIdx.x] = v;
    __syncthreads();
    #pragma unroll
    for (int off = 1; off < SCB; off <<= 1) {
        int t = (threadIdx.x >= off) ? s[threadIdx.x - off] : 0;
        __syncthreads();
        s[threadIdx.x] += t;
        __syncthreads();
    }
    if (i < n) exc[i] = s[threadIdx.x] - v;
    if (threadIdx.x == SCB - 1) bsum[blockIdx.x] = s[threadIdx.x];
}

__global__ __launch_bounds__(SCB)
void scan2_kernel(int* __restrict__ bsum, int nb)
{
    __shared__ int s[SCB];
    const int v = (threadIdx.x < nb) ? bsum[threadIdx.x] : 0;
    s[threadIdx.x] = v;
    __syncthreads();
    #pragma unroll
    for (int off = 1; off < SCB; off <<= 1) {
        int t = (threadIdx.x >= off) ? s[threadIdx.x - off] : 0;
        __syncthreads();
        s[threadIdx.x] += t;
        __syncthreads();
    }
    if (threadIdx.x < nb) bsum[threadIdx.x] = s[threadIdx.x] - v;
}

__global__ __launch_bounds__(SCB)
void scan3_kernel(int* __restrict__ exc, const int* __restrict__ bsum, int n)
{
    const int i = blockIdx.x * SCB + (int)threadIdx.x;
    if (i < n) exc[i] += bsum[i >> 8];
}

__global__ __launch_bounds__(256)
void scatter_kernel(const int* __restrict__ idx_i, const int* __restrict__ idx_j,
                    int* __restrict__ cursor, int* __restrict__ perm,
                    int* __restrict__ si, int* __restrict__ sj, int E)
{
    const int e = blockIdx.x * 256 + threadIdx.x;
    if (e < E) {
        const int n = idx_i[e];
        const int p = atomicAdd(&cursor[n], 1);
        perm[p] = e;
        si[p] = n;
        sj[p] = idx_j[e];
    }
}

// ---------------------------------------------------------------------------
// generic 128-K split-bf16 MFMA GEMM with optional fused node-update
// (unchanged)
// ---------------------------------------------------------------------------
__global__ __launch_bounds__(1024)
void gemm128_mfma_kernel(float* __restrict__ A0, const float* __restrict__ A1,
                         int nA, int nTotal,
                         const float* __restrict__ W, const float* __restrict__ bias,
                         int bias_limit, int do_relu, int update,
                         float* __restrict__ sum_agg, int* __restrict__ max_agg,
                         float* __restrict__ out0, float* __restrict__ out1,
                         int ntiles)
{
    __shared__ __align__(16) unsigned char SM[131584];
    char*  const Whi = (char*)SM;
    char*  const Wlo = (char*)SM + 32768;
    char*  const Ahi = (char*)SM + 65536;
    char*  const Alo = (char*)SM + 98304;
    float* const Wf  = (float*)(SM + 65536);
    float* const bs  = (float*)(SM + 131072);

    const int t = (int)threadIdx.x;

    {
        const float4* Wg = (const float4*)W;
        float4* Wd = (float4*)Wf;
        #pragma unroll
        for (int i = 0; i < 4; ++i) Wd[t + i * 1024] = Wg[t + i * 1024];
        if (t < DD) bs[t] = bias ? bias[t] : 0.f;
    }
    __syncthreads();
    {
        const int col = t >> 3;
        const int kb  = (t & 7) * 16;
        unsigned h16[16], l16[16];
        #pragma unroll
        for (int j = 0; j < 16; ++j) {
            const float w = Wf[(size_t)(kb + j) * DD + col];
            const unsigned hb = bf16_rne(w);
            const float hf = __uint_as_float(hb << 16);
            h16[j] = hb;
            l16[j] = bf16_rne(w - hf);
        }
        #pragma unroll
        for (int c = 0; c < 2; ++c) {
            uint4 ph, pl;
            ph.x = h16[c*8+0] | (h16[c*8+1] << 16);
            ph.y = h16[c*8+2] | (h16[c*8+3] << 16);
            ph.z = h16[c*8+4] | (h16[c*8+5] << 16);
            ph.w = h16[c*8+6] | (h16[c*8+7] << 16);
            pl.x = l16[c*8+0] | (l16[c*8+1] << 16);
            pl.y = l16[c*8+2] | (l16[c*8+3] << 16);
            pl.z = l16[c*8+4] | (l16[c*8+5] << 16);
            pl.w = l16[c*8+6] | (l16[c*8+7] << 16);
            const int off = ((col * 256 + (kb + c * 8) * 2)) ^ ((col & 7) << 4);
            *(uint4*)(Whi + off) = ph;
            *(uint4*)(Wlo + off) = pl;
        }
    }

    const int w  = t >> 6;
    const int l  = t & 63;
    const int wm = w >> 2;
    const int wn = w & 3;
    const int g  = l >> 4;
    const int q  = l & 15;

    for (int tile = blockIdx.x; tile < ntiles; tile += gridDim.x) {
        const int e0 = tile * 128;
        __syncthreads();

        #pragma unroll
        for (int i = 0; i < 2; ++i) {
            const int task = t + i * 1024;
            const int row  = task >> 4;
            const int c    = task & 15;
            const int rr = min(e0 + row, nTotal - 1);
            float d[8];
            if (rr < nA) {
                float* ph0 = A0 + (size_t)rr * DD + c * 8;
                const float4 a0 = *(const float4*)ph0;
                const float4 a1 = *(const float4*)(ph0 + 4);
                if (update) {
                    float* sp = sum_agg + (size_t)rr * DD + c * 8;
                    int*   mp = max_agg + (size_t)rr * DD + c * 8;
                    const float4 s0 = *(const float4*)sp;
                    const float4 s1 = *(const float4*)(sp + 4);
                    const int4   m0 = *(const int4*)mp;
                    const int4   m1 = *(const int4*)(mp + 4);
                    d[0] = a0.x * s0.x * __int_as_float(m0.x);
                    d[1] = a0.y * s0.y * __int_as_float(m0.y);
                    d[2] = a0.z * s0.z * __int_as_float(m0.z);
                    d[3] = a0.w * s0.w * __int_as_float(m0.w);
                    d[4] = a1.x * s1.x * __int_as_float(m1.x);
                    d[5] = a1.y * s1.y * __int_as_float(m1.y);
                    d[6] = a1.z * s1.z * __int_as_float(m1.z);
                    d[7] = a1.w * s1.w * __int_as_float(m1.w);
                    *(float4*)ph0       = make_float4(d[0], d[1], d[2], d[3]);
                    *(float4*)(ph0 + 4) = make_float4(d[4], d[5], d[6], d[7]);
                    *(float4*)sp       = make_float4(0.f, 0.f, 0.f, 0.f);
                    *(float4*)(sp + 4) = make_float4(0.f, 0.f, 0.f, 0.f);
                    *(int4*)mp       = make_int4(0, 0, 0, 0);
                    *(int4*)(mp + 4) = make_int4(0, 0, 0, 0);
                } else {
                    d[0] = a0.x; d[1] = a0.y; d[2] = a0.z; d[3] = a0.w;
                    d[4] = a1.x; d[5] = a1.y; d[6] = a1.z; d[7] = a1.w;
                }
            } else {
                const float* pa = A1 + (size_t)(rr - nA) * DD + c * 8;
                const float4 a0 = *(const float4*)pa;
                const float4 a1 = *(const float4*)(pa + 4);
                d[0] = a0.x; d[1] = a0.y; d[2] = a0.z; d[3] = a0.w;
                d[4] = a1.x; d[5] = a1.y; d[6] = a1.z; d[7] = a1.w;
            }
            unsigned h8[8], l8[8];
            #pragma unroll
            for (int j = 0; j < 8; ++j) {
                const unsigned hb = bf16_rne(d[j]);
                const float hf = __uint_as_float(hb << 16);
                h8[j] = hb;
                l8[j] = bf16_rne(d[j] - hf);
            }
            uint4 ph, pl;
            ph.x = h8[0] | (h8[1] << 16);
            ph.y = h8[2] | (h8[3] << 16);
            ph.z = h8[4] | (h8[5] << 16);
            ph.w = h8[6] | (h8[7] << 16);
            pl.x = l8[0] | (l8[1] << 16);
            pl.y = l8[2] | (l8[3] << 16);
            pl.z = l8[4] | (l8[5] << 16);
            pl.w = l8[6] | (l8[7] << 16);
            const int off = ((row * 256 + c * 16)) ^ ((row & 7) << 4);
            *(uint4*)(Ahi + off) = ph;
            *(uint4*)(Alo + off) = pl;
        }
        __syncthreads();

        f32x4 acc[2][2];
        const f32x4 zero = {0.f, 0.f, 0.f, 0.f};
        acc[0][0] = zero; acc[0][1] = zero; acc[1][0] = zero; acc[1][1] = zero;

        #pragma unroll
        for (int ks = 0; ks < 4; ++ks) {
            const int kbyte = ks * 64 + g * 16;
            bf16x8 ah[2], al[2], bh[2], bl[2];
            #pragma unroll
            for (int m = 0; m < 2; ++m) {
                const int row = wm * 32 + m * 16 + q;
                const int off = (row * 256 + kbyte) ^ ((row & 7) << 4);
                ah[m] = *(const bf16x8*)(Ahi + off);
                al[m] = *(const bf16x8*)(Alo + off);
            }
            #pragma unroll
            for (int n = 0; n < 2; ++n) {
                const int colv = wn * 32 + n * 16 + q;
                const int off = (colv * 256 + kbyte) ^ ((colv & 7) << 4);
                bh[n] = *(const bf16x8*)(Whi + off);
                bl[n] = *(const bf16x8*)(Wlo + off);
            }
            #pragma unroll
            for (int m = 0; m < 2; ++m)
                #pragma unroll
                for (int n = 0; n < 2; ++n)
                    acc[m][n] = __builtin_amdgcn_mfma_f32_16x16x32_bf16(ah[m], bh[n], acc[m][n], 0, 0, 0);
            #pragma unroll
            for (int m = 0; m < 2; ++m)
                #pragma unroll
                for (int n = 0; n < 2; ++n)
                    acc[m][n] = __builtin_amdgcn_mfma_f32_16x16x32_bf16(ah[m], bl[n], acc[m][n], 0, 0, 0);
            #pragma unroll
            for (int m = 0; m < 2; ++m)
                #pragma unroll
                for (int n = 0; n < 2; ++n)
                    acc[m][n] = __builtin_amdgcn_mfma_f32_16x16x32_bf16(al[m], bh[n], acc[m][n], 0, 0, 0);
        }

        #pragma unroll
        for (int n = 0; n < 2; ++n) {
            const int colv = wn * 32 + n * 16 + q;
            const float bv = bs[colv];
            #pragma unroll
            for (int m = 0; m < 2; ++m) {
                #pragma unroll
                for (int r = 0; r < 4; ++r) {
                    const int row = e0 + wm * 32 + m * 16 + g * 4 + r;
                    if (row < nTotal) {
                        float v = acc[m][n][r] + ((row < bias_limit) ? bv : 0.f);
                        if (do_relu) v = fmaxf(v, 0.f);
                        out0[(size_t)row * DD + colv] = v;
                        if (out1) out1[(size_t)row * DD + colv] = v;
                    }
                }
            }
        }
    }
}

// ---------------------------------------------------------------------------
// bond pass v5: 8 waves x 64 edges (R11's proven occupancy medicine applied
// to the bond projection). Lane owns 2 cols, W cols in regs, ea row is a
// lane-uniform LDS broadcast; segmented-ownership aggregation.
// ---------------------------------------------------------------------------
__global__ __launch_bounds__(512)
void bond_pass_kernel(const float* __restrict__ edge_attr,
                      const float* __restrict__ Wb, const float* __restrict__ bb,
                      const int* __restrict__ si, const int* __restrict__ perm,
                      float* __restrict__ h_head0,
                      float* __restrict__ sum_agg, int* __restrict__ max_agg,
                      int E, int N)
{
    __shared__ __align__(16) float ea_s[CB][16];   // 32 KB
    __shared__ int si_s[CB], pm_s[CB];             // 4 KB

    const int p0b = blockIdx.x * CB;
    if (p0b >= E) return;
    const int t = (int)threadIdx.x;

    for (int i = t; i < CB; i += 512) {
        const int p = min(p0b + i, E - 1);
        si_s[i] = si[p];
        pm_s[i] = perm[p];
    }
    for (int task = t; task < CB * 4; task += 512) {
        const int row = task >> 2;
        const int c4  = task & 3;
        const int p = min(p0b + row, E - 1);
        const int orig = perm[p];
        *(float4*)(&ea_s[row][c4 * 4]) =
            *(const float4*)(edge_attr + (size_t)orig * 16 + c4 * 4);
    }
    __syncthreads();

    const int w    = t >> 6;         // wave 0..7
    const int lane = t & 63;
    const int c    = lane * 2;
    const int q0   = w * 64;         // wave's first local edge
    const int pg0  = p0b + q0;
    if (pg0 >= E) return;

    float wc0[16], wc1[16];
    #pragma unroll
    for (int k = 0; k < 16; ++k) {
        const float2 wv = *(const float2*)(Wb + k * DD + c);
        wc0[k] = wv.x; wc1[k] = wv.y;
    }
    const float2 bc = *(const float2*)(bb + c);

    const int firstNode = si_s[q0];
    const int lastNode  = si_s[q0 + 63];

    int curNode = firstNode;
    float2 rs = make_float2(0.f, 0.f), rm = make_float2(0.f, 0.f);

    #define BP_FLUSH()                                                           \
    {                                                                            \
        if (curNode == firstNode || curNode == lastNode) {                       \
            atomicAdd(&sum_agg[(size_t)curNode * DD + c],     rs.x);             \
            atomicAdd(&sum_agg[(size_t)curNode * DD + c + 1], rs.y);             \
            atomicMax(&max_agg[(size_t)curNode * DD + c],     __float_as_int(rm.x)); \
            atomicMax(&max_agg[(size_t)curNode * DD + c + 1], __float_as_int(rm.y)); \
        } else {                                                                 \
            *(float2*)(sum_agg + (size_t)curNode * DD + c) = rs;                 \
            *(int2*)(max_agg + (size_t)curNode * DD + c) =                       \
                make_int2(__float_as_int(rm.x), __float_as_int(rm.y));           \
        }                                                                        \
    }

    #pragma unroll 4
    for (int kk = 0; kk < 64; ++kk) {
        const int i = si_s[q0 + kk];
        if (i != curNode) {
            BP_FLUSH();
            curNode = i;
            rs = make_float2(0.f, 0.f);
            rm = make_float2(0.f, 0.f);
        }
        const float4* ear = (const float4*)(&ea_s[q0 + kk][0]);
        const float4 e0 = ear[0], e1 = ear[1], e2 = ear[2], e3 = ear[3];
        float ax = bc.x, ay = bc.y;
        ax = fmaf(e0.x, wc0[ 0], ax);  ay = fmaf(e0.x, wc1[ 0], ay);
        ax = fmaf(e0.y, wc0[ 1], ax);  ay = fmaf(e0.y, wc1[ 1], ay);
        ax = fmaf(e0.z, wc0[ 2], ax);  ay = fmaf(e0.z, wc1[ 2], ay);
        ax = fmaf(e0.w, wc0[ 3], ax);  ay = fmaf(e0.w, wc1[ 3], ay);
        ax = fmaf(e1.x, wc0[ 4], ax);  ay = fmaf(e1.x, wc1[ 4], ay);
        ax = fmaf(e1.y, wc0[ 5], ax);  ay = fmaf(e1.y, wc1[ 5], ay);
        ax = fmaf(e1.z, wc0[ 6], ax);  ay = fmaf(e1.z, wc1[ 6], ay);
        ax = fmaf(e1.w, wc0[ 7], ax);  ay = fmaf(e1.w, wc1[ 7], ay);
        ax = fmaf(e2.x, wc0[ 8], ax);  ay = fmaf(e2.x, wc1[ 8], ay);
        ax = fmaf(e2.y, wc0[ 9], ax);  ay = fmaf(e2.y, wc1[ 9], ay);
        ax = fmaf(e2.z, wc0[10], ax);  ay = fmaf(e2.z, wc1[10], ay);
        ax = fmaf(e2.w, wc0[11], ax);  ay = fmaf(e2.w, wc1[11], ay);
        ax = fmaf(e3.x, wc0[12], ax);  ay = fmaf(e3.x, wc1[12], ay);
        ax = fmaf(e3.y, wc0[13], ax);  ay = fmaf(e3.y, wc1[13], ay);
        ax = fmaf(e3.z, wc0[14], ax);  ay = fmaf(e3.z, wc1[14], ay);
        ax = fmaf(e3.w, wc0[15], ax);  ay = fmaf(e3.w, wc1[15], ay);
        float2 v;
        v.x = fmaxf(ax, 0.f);
        v.y = fmaxf(ay, 0.f);
        if (pg0 + kk >= E) { v.x = 0.f; v.y = 0.f; }
        rs.x += v.x; rs.y += v.y;
        rm.x = fmaxf(rm.x, v.x); rm.y = fmaxf(rm.y, v.y);
        if (pg0 + kk < E) {
            const int orig = pm_s[q0 + kk];
            if (orig < N) *(float2*)(h_head0 + (size_t)orig * DD + c) = v;
        }
    }
    BP_FLUSH();
    #undef BP_FLUSH
}

// ---------------------------------------------------------------------------
// edge pass v4 (unchanged): 8 waves x 64 edges + 8-deep prefetch;
// segmented ownership.
// ---------------------------------------------------------------------------
__global__ __launch_bounds__(512)
void edge_pass_kernel(const float* __restrict__ PQ,
                      const int* __restrict__ si, const int* __restrict__ sj,
                      const int* __restrict__ perm,
                      float* __restrict__ head_next, int store_head,
                      float* __restrict__ sum_agg, int* __restrict__ max_agg,
                      int E, int N)
{
    __shared__ int si_s[CE], sj_s[CE], pm_s[CE];
    const int p0b = blockIdx.x * CE;
    if (p0b >= E) return;
    const int t = (int)threadIdx.x;
    for (int i = t; i < CE; i += 512) {
        const int p = min(p0b + i, E - 1);
        si_s[i] = si[p];
        sj_s[i] = sj[p];
        pm_s[i] = perm[p];
    }
    __syncthreads();

    const int w    = t >> 6;         // wave 0..7
    const int lane = t & 63;
    const int c    = lane * 2;
    const int q0   = w * 64;
    const int pg0  = p0b + q0;
    if (pg0 >= E) return;

    const int firstNode = si_s[q0];
    const int lastNode  = si_s[q0 + 63];

    const float* __restrict__ Qbase = PQ + (size_t)N * DD + c;

    float2 qa = *(const float2*)(Qbase + (size_t)sj_s[q0 + 0] * DD);
    float2 qb = *(const float2*)(Qbase + (size_t)sj_s[q0 + 1] * DD);
    float2 qc = *(const float2*)(Qbase + (size_t)sj_s[q0 + 2] * DD);
    float2 qd = *(const float2*)(Qbase + (size_t)sj_s[q0 + 3] * DD);
    float2 qe = *(const float2*)(Qbase + (size_t)sj_s[q0 + 4] * DD);
    float2 qf = *(const float2*)(Qbase + (size_t)sj_s[q0 + 5] * DD);
    float2 qg = *(const float2*)(Qbase + (size_t)sj_s[q0 + 6] * DD);
    float2 qh = *(const float2*)(Qbase + (size_t)sj_s[q0 + 7] * DD);

    int curNode = firstNode;
    float2 Pi = *(const float2*)(PQ + (size_t)curNode * DD + c);
    float2 rs = make_float2(0.f, 0.f), rm = make_float2(0.f, 0.f);

    #define EP_FLUSH()                                                           \
    {                                                                            \
        if (curNode == firstNode || curNode == lastNode) {                       \
            atomicAdd(&sum_agg[(size_t)curNode * DD + c],     rs.x);             \
            atomicAdd(&sum_agg[(size_t)curNode * DD + c + 1], rs.y);             \
            atomicMax(&max_agg[(size_t)curNode * DD + c],     __float_as_int(rm.x)); \
            atomicMax(&max_agg[(size_t)curNode * DD + c + 1], __float_as_int(rm.y)); \
        } else {                                                                 \
            *(float2*)(sum_agg + (size_t)curNode * DD + c) = rs;                 \
            *(int2*)(max_agg + (size_t)curNode * DD + c) =                       \
                make_int2(__float_as_int(rm.x), __float_as_int(rm.y));           \
        }                                                                        \
    }

    #define EP_STEP(K, QREG)                                                     \
    {                                                                            \
        const int kk = (K);                                                      \
        const int i = si_s[q0 + kk];                                             \
        if (i != curNode) {                                                      \
            EP_FLUSH();                                                          \
            curNode = i;                                                         \
            Pi = *(const float2*)(PQ + (size_t)i * DD + c);                      \
            rs = make_float2(0.f, 0.f);                                          \
            rm = make_float2(0.f, 0.f);                                          \
        }                                                                        \
        float2 v;                                                                \
        v.x = fmaxf(Pi.x - QREG.x, 0.f);                                         \
        v.y = fmaxf(Pi.y - QREG.y, 0.f);                                         \
        if (pg0 + kk >= E) { v.x = 0.f; v.y = 0.f; }                             \
        rs.x += v.x; rs.y += v.y;                                                \
        rm.x = fmaxf(rm.x, v.x); rm.y = fmaxf(rm.y, v.y);                        \
        if (store_head && (pg0 + kk) < E) {                                      \
            const int orig = pm_s[q0 + kk];                                      \
            if (orig < N) *(float2*)(head_next + (size_t)orig * DD + c) = v;     \
        }                                                                        \
        if (kk + 8 < 64)                                                         \
            QREG = *(const float2*)(Qbase + (size_t)sj_s[q0 + kk + 8] * DD);     \
    }

    #pragma unroll
    for (int k = 0; k < 64; k += 8) {
        EP_STEP(k + 0, qa);
        EP_STEP(k + 1, qb);
        EP_STEP(k + 2, qc);
        EP_STEP(k + 3, qd);
        EP_STEP(k + 4, qe);
        EP_STEP(k + 5, qf);
        EP_STEP(k + 6, qg);
        EP_STEP(k + 7, qh);
    }
    EP_FLUSH();
    #undef EP_STEP
    #undef EP_FLUSH
}

// ---------------------------------------------------------------------------
// final: out = [ha, x_proj] @ W_lin + b_lin via split-bf16 MFMA, K=256
// (unchanged)
// ---------------------------------------------------------------------------
__global__ __launch_bounds__(512, 2)
void final_mfma_kernel(const float* __restrict__ h, const float* __restrict__ sum_agg,
                       const int* __restrict__ max_agg, const float* __restrict__ xp,
                       const float* __restrict__ Wl, const float* __restrict__ bl,
                       float* __restrict__ out, int N)
{
    __shared__ __align__(16) unsigned char SM[65808];
    char*  const Whi = (char*)SM;
    char*  const Wlo = (char*)SM + 32768;
    float* const Wf  = (float*)SM;
    float* const bs  = (float*)(SM + 65536);

    const int t = (int)threadIdx.x;
    {
        const float4* Wg = (const float4*)Wl;
        float4* Wd = (float4*)Wf;
        #pragma unroll
        for (int i = 0; i < 8; ++i) Wd[t + i * 512] = Wg[t + i * 512];
        if (t < 64) bs[t] = bl[t];
    }
    __syncthreads();
    {
        const int col = t & 63;
        const int kb  = (t >> 6) * 32;
        float v[32];
        #pragma unroll
        for (int j = 0; j < 32; ++j) v[j] = Wf[(size_t)(kb + j) * 64 + col];
        __syncthreads();
        #pragma unroll
        for (int c = 0; c < 4; ++c) {
            unsigned h8[8], l8[8];
            #pragma unroll
            for (int j = 0; j < 8; ++j) {
                const float w0 = v[c * 8 + j];
                const unsigned hb = bf16_rne(w0);
                h8[j] = hb;
                l8[j] = bf16_rne(w0 - __uint_as_float(hb << 16));
            }
            uint4 ph, pl;
            ph.x = h8[0] | (h8[1] << 16); ph.y = h8[2] | (h8[3] << 16);
            ph.z = h8[4] | (h8[5] << 16); ph.w = h8[6] | (h8[7] << 16);
            pl.x = l8[0] | (l8[1] << 16); pl.y = l8[2] | (l8[3] << 16);
            pl.z = l8[4] | (l8[5] << 16); pl.w = l8[6] | (l8[7] << 16);
            const int off = (col * 512 + (kb + c * 8) * 2) ^ ((col & 7) << 4);
            *(uint4*)(Whi + off) = ph;
            *(uint4*)(Wlo + off) = pl;
        }
    }
    __syncthreads();

    const int w  = t >> 6;
    const int l  = t & 63;
    const int wm = w >> 1;
    const int wn = w & 1;
    const int g  = l >> 4;
    const int q  = l & 15;
    const int r0 = (int)blockIdx.x * 128;

    f32x4 acc[2][2];
    const f32x4 zero = {0.f, 0.f, 0.f, 0.f};
    acc[0][0] = zero; acc[0][1] = zero; acc[1][0] = zero; acc[1][1] = zero;

    #pragma unroll
    for (int ks = 0; ks < 8; ++ks) {
        const int kf = (ks & 3) * 32 + g * 8;
        bf16x8 ah[2], al[2];
        #pragma unroll
        for (int m = 0; m < 2; ++m) {
            const int rr = min(r0 + wm * 32 + m * 16 + q, N - 1);
            float d[8];
            if (ks < 4) {
                const float* ph = h       + (size_t)rr * DD + kf;
                const float* ps = sum_agg + (size_t)rr * DD + kf;
                const int*   pm = max_agg + (size_t)rr * DD + kf;
                const float4 a0 = *(const float4*)ph;
                const float4 a1 = *(const float4*)(ph + 4);
                const float4 s0 = *(const float4*)ps;
                const float4 s1 = *(const float4*)(ps + 4);
                const int4   i0 = *(const int4*)pm;
                const int4   i1 = *(const int4*)(pm + 4);
                d[0] = a0.x * a0.x * s0.x * __int_as_float(i0.x);
                d[1] = a0.y * a0.y * s0.y * __int_as_float(i0.y);
                d[2] = a0.z * a0.z * s0.z * __int_as_float(i0.z);
                d[3] = a0.w * a0.w * s0.w * __int_as_float(i0.w);
                d[4] = a1.x * a1.x * s1.x * __int_as_float(i1.x);
                d[5] = a1.y * a1.y * s1.y * __int_as_float(i1.y);
                d[6] = a1.z * a1.z * s1.z * __int_as_float(i1.z);
                d[7] = a1.w * a1.w * s1.w * __int_as_float(i1.w);
            } else {
                const float* pa = xp + (size_t)rr * DD + kf;
                const float4 a0 = *(const float4*)pa;
                const float4 a1 = *(const float4*)(pa + 4);
                d[0] = a0.x; d[1] = a0.y; d[2] = a0.z; d[3] = a0.w;
                d[4] = a1.x; d[5] = a1.y; d[6] = a1.z; d[7] = a1.w;
            }
            unsigned h8[8], l8[8];
            #pragma unroll
            for (int j = 0; j < 8; ++j) {
                const unsigned hb = bf16_rne(d[j]);
                h8[j] = hb;
                l8[j] = bf16_rne(d[j] - __uint_as_float(hb << 16));
            }
            uint4 ph2, pl2;
            ph2.x = h8[0] | (h8[1] << 16); ph2.y = h8[2] | (h8[3] << 16);
            ph2.z = h8[4] | (h8[5] << 16); ph2.w = h8[6] | (h8[7] << 16);
            pl2.x = l8[0] | (l8[1] << 16); pl2.y = l8[2] | (l8[3] << 16);
            pl2.z = l8[4] | (l8[5] << 16); pl2.w = l8[6] | (l8[7] << 16);
            ah[m] = *(bf16x8*)&ph2;
            al[m] = *(bf16x8*)&pl2;
        }
        bf16x8 bh[2], blo[2];
        #pragma unroll
        for (int n = 0; n < 2; ++n) {
            const int colv = wn * 32 + n * 16 + q;
            const int off = (colv * 512 + ks * 64 + g * 16) ^ ((colv & 7) << 4);
            bh[n]  = *(const bf16x8*)(Whi + off);
            blo[n] = *(const bf16x8*)(Wlo + off);
        }
        #pragma unroll
        for (int m = 0; m < 2; ++m)
            #pragma unroll
            for (int n = 0; n < 2; ++n) {
                acc[m][n] = __builtin_amdgcn_mfma_f32_16x16x32_bf16(ah[m], bh[n],  acc[m][n], 0, 0, 0);
                acc[m][n] = __builtin_amdgcn_mfma_f32_16x16x32_bf16(ah[m], blo[n], acc[m][n], 0, 0, 0);
                acc[m][n] = __builtin_amdgcn_mfma_f32_16x16x32_bf16(al[m], bh[n],  acc[m][n], 0, 0, 0);
            }
    }

    #pragma unroll
    for (int n = 0; n < 2; ++n) {
        const int colv = wn * 32 + n * 16 + q;
        const float bv = bs[colv];
        #pragma unroll
        for (int m = 0; m < 2; ++m) {
            #pragma unroll
            for (int r = 0; r < 4; ++r) {
                const int row = r0 + wm * 32 + m * 16 + g * 4 + r;
                if (row < N) out[(size_t)row * 64 + colv] = acc[m][n][r] + bv;
            }
        }
    }
}

// ---------------------------------------------------------------------------
extern "C" void kernel_launch(void* const* d_in, const int* in_sizes, int n_in,
                              void* d_out, int out_size, void* d_ws, size_t ws_size,
                              hipStream_t stream)
{
    const float* x         = (const float*)d_in[0];
    const int*   edge_idx  = (const int*)d_in[1];
    const float* edge_attr = (const float*)d_in[2];
    const float* W_atom    = (const float*)d_in[3];
    const float* b_atom    = (const float*)d_in[4];
    const float* W_bond    = (const float*)d_in[5];
    const float* b_bond    = (const float*)d_in[6];
    const float* W_seq     = (const float*)d_in[7];
    const float* b_seq     = (const float*)d_in[8];
    const float* W_lin     = (const float*)d_in[9];
    const float* b_lin     = (const float*)d_in[10];
    float* out = (float*)d_out;

    const int N = in_sizes[0] / DD;   // 30000
    const int E = in_sizes[1] / 2;    // 480000
    const int* idx_i = edge_idx;
    const int* idx_j = edge_idx + E;

    const size_t nd = (size_t)N * DD;
    float* ws      = (float*)d_ws;
    float* x_proj  = ws;
    float* h_atom  = x_proj + nd;
    float* head    = h_atom + nd;
    float* sum_agg = head + nd;
    int*   max_agg = (int*)(sum_agg + nd);
    float* PQ      = (float*)(max_agg + nd);   // 2N x 128
    int*   cnt     = (int*)(PQ + 2 * nd);
    int*   cursor  = cnt + N;
    int*   bsum    = cursor + N;
    int*   perm    = bsum + 256;
    int*   si      = perm + E;
    int*   sj      = si + E;

    // ---- counting sort of edges by idx_i ----
    hipMemsetAsync(cnt, 0, (size_t)N * 4, stream);
    hist_kernel<<<(E + 255) / 256, 256, 0, stream>>>(idx_i, cnt, E);
    const int nb_scan = (N + SCB - 1) / SCB;
    scan1_kernel<<<nb_scan, SCB, 0, stream>>>(cnt, cursor, bsum, N);
    scan2_kernel<<<1, SCB, 0, stream>>>(bsum, nb_scan);
    scan3_kernel<<<nb_scan, SCB, 0, stream>>>(cursor, bsum, N);
    scatter_kernel<<<(E + 255) / 256, 256, 0, stream>>>(idx_i, idx_j, cursor, perm, si, sj, E);

    hipMemsetAsync(sum_agg, 0, nd * 4, stream);
    hipMemsetAsync(max_agg, 0, nd * 4, stream);

    // node projection via MFMA: x_proj = h_atom = relu(x @ W_atom + b_atom)
    const int ntiles_n = (N + 127) / 128;
    gemm128_mfma_kernel<<<min(ntiles_n, 256), 1024, 0, stream>>>(
        (float*)x, x, N, N, W_atom, b_atom, N, 1, 0, nullptr, nullptr,
        x_proj, h_atom, ntiles_n);

    // bond projection + layer-0 aggregation (v5: 8 waves x 64 edges)
    bond_pass_kernel<<<(E + CB - 1) / CB, 512, 0, stream>>>(
        edge_attr, W_bond, b_bond, si, perm, head, sum_agg, max_agg, E, N);

    const int ntiles_pq = (2 * N + 127) / 128;
    const int ep_blocks = (E + CE - 1) / CE;
    for (int l = 0; l < 3; ++l) {
        gemm128_mfma_kernel<<<256, 1024, 0, stream>>>(
            h_atom, head, N, 2 * N, W_seq + (size_t)l * DD * DD,
            b_seq + (size_t)l * DD, N, 0, 1, sum_agg, max_agg,
            PQ, nullptr, ntiles_pq);
        edge_pass_kernel<<<ep_blocks, 512, 0, stream>>>(
            PQ, si, sj, perm, head, (l < 2) ? 1 : 0, sum_agg, max_agg, E, N);
    }

    final_mfma_kernel<<<(N + 127) / 128, 512, 0, stream>>>(
        h_atom, sum_agg, (const int*)max_agg, x_proj, W_lin, b_lin, out, N);
}

// Round 13
// 389.411 us; speedup vs baseline: 1.1717x; 1.0152x over previous
//
#include <hip/hip_runtime.h>
#include <hip/hip_bf16.h>

#define DD 128   // hidden dim
#define SCB 256  // scan block size
#define CE  512  // edges per block in edge_pass (8 waves x 64)
#define CB  512  // edges per block in bond pass (8 waves x 64)

typedef __attribute__((ext_vector_type(8))) short bf16x8;
typedef __attribute__((ext_vector_type(4))) float f32x4;

__device__ __forceinline__ unsigned bf16_rne(float f) {
    unsigned u = __float_as_uint(f);
    return (u + 0x7fffu + ((u >> 16) & 1u)) >> 16;
}

// ---------------------------------------------------------------------------
// counting-sort preprocessing (sort edges by idx_i)
// ---------------------------------------------------------------------------
__global__ __launch_bounds__(256)
void hist_kernel(const int* __restrict__ idx_i, int* __restrict__ cnt, int E)
{
    const int e = blockIdx.x * 256 + threadIdx.x;
    if (e < E) atomicAdd(&cnt[idx_i[e]], 1);
}

__global__ __launch_bounds__(SCB)
void scan1_kernel(const int* __restrict__ cnt, int* __restrict__ exc,
                  int* __restrict__ bsum, int n)
{
    __shared__ int s[SCB];
    const int i = blockIdx.x * SCB + (int)threadIdx.x;
    const int v = (i < n) ? cnt[i] : 0;
    s[threadIdx.x] = v;
    __syncthreads();
    #pragma unroll
    for (int off = 1; off < SCB; off <<= 1) {
        int t = (threadIdx.x >= off) ? s[threadIdx.x - off] : 0;
        __syncthreads();
        s[threadIdx.x] += t;
        __syncthreads();
    }
    if (i < n) exc[i] = s[threadIdx.x] - v;
    if (threadIdx.x == SCB - 1) bsum[blockIdx.x] = s[threadIdx.x];
}

__global__ __launch_bounds__(SCB)
void scan2_kernel(int* __restrict__ bsum, int nb)
{
    __shared__ int s[SCB];
    const int v = (threadIdx.x < nb) ? bsum[threadIdx.x] : 0;
    s[threadIdx.x] = v;
    __syncthreads();
    #pragma unroll
    for (int off = 1; off < SCB; off <<= 1) {
        int t = (threadIdx.x >= off) ? s[threadIdx.x - off] : 0;
        __syncthreads();
        s[threadIdx.x] += t;
        __syncthreads();
    }
    if (threadIdx.x < nb) bsum[threadIdx.x] = s[threadIdx.x] - v;
}

__global__ __launch_bounds__(SCB)
void scan3_kernel(int* __restrict__ exc, const int* __restrict__ bsum, int n)
{
    const int i = blockIdx.x * SCB + (int)threadIdx.x;
    if (i < n) exc[i] += bsum[i >> 8];
}

__global__ __launch_bounds__(256)
void scatter_kernel(const int* __restrict__ idx_i, const int* __restrict__ idx_j,
                    int* __restrict__ cursor, int* __restrict__ perm,
                    int* __restrict__ si, int* __restrict__ sj, int E)
{
    const int e = blockIdx.x * 256 + threadIdx.x;
    if (e < E) {
        const int n = idx_i[e];
        const int p = atomicAdd(&cursor[n], 1);
        perm[p] = e;
        si[p] = n;
        sj[p] = idx_j[e];
    }
}

// ---------------------------------------------------------------------------
// gemm128 v2: 512 threads = 8 waves, wave = 16 cols x 128 rows.
// W fragments (16-col slice, hi/lo, 4 k-steps) live in REGISTERS, loaded
// once per block from global with on-the-fly split -> LDS is A hi/lo only
// (64 KB) -> 2 blocks/CU; barriers overlap across independent blocks.
// C = Ahi*Whi + Ahi*Wlo + Alo*Whi (identical numerics to v1).
// ---------------------------------------------------------------------------
__global__ __launch_bounds__(512, 4)
void gemm128_mfma_kernel(float* __restrict__ A0, const float* __restrict__ A1,
                         int nA, int nTotal,
                         const float* __restrict__ W, const float* __restrict__ bias,
                         int bias_limit, int do_relu, int update,
                         float* __restrict__ sum_agg, int* __restrict__ max_agg,
                         float* __restrict__ out0, float* __restrict__ out1,
                         int ntiles)
{
    __shared__ __align__(16) unsigned char SM[65536];
    char* const Ahi = (char*)SM;
    char* const Alo = (char*)SM + 32768;

    const int t = (int)threadIdx.x;
    const int w = t >> 6;      // 0..7 : col block (16 cols)
    const int l = t & 63;
    const int g = l >> 4;      // 0..3
    const int q = l & 15;
    const int colv = w * 16 + q;

    // ---- per-lane W fragments in registers (tile-invariant) ----
    bf16x8 wh[4], wl[4];
    #pragma unroll
    for (int ks = 0; ks < 4; ++ks) {
        unsigned h8[8], l8[8];
        #pragma unroll
        for (int j = 0; j < 8; ++j) {
            const float w0 = W[(size_t)(ks * 32 + g * 8 + j) * DD + colv];
            const unsigned hb = bf16_rne(w0);
            h8[j] = hb;
            l8[j] = bf16_rne(w0 - __uint_as_float(hb << 16));
        }
        uint4 ph, pl;
        ph.x = h8[0] | (h8[1] << 16); ph.y = h8[2] | (h8[3] << 16);
        ph.z = h8[4] | (h8[5] << 16); ph.w = h8[6] | (h8[7] << 16);
        pl.x = l8[0] | (l8[1] << 16); pl.y = l8[2] | (l8[3] << 16);
        pl.z = l8[4] | (l8[5] << 16); pl.w = l8[6] | (l8[7] << 16);
        wh[ks] = *(bf16x8*)&ph;
        wl[ks] = *(bf16x8*)&pl;
    }
    const float bv = bias ? bias[colv] : 0.f;

    for (int tile = blockIdx.x; tile < ntiles; tile += gridDim.x) {
        const int e0 = tile * 128;
        __syncthreads();   // previous tile's MFMA reads done

        // ---- stage A tile (+ optional fused node-update), swizzled ----
        #pragma unroll
        for (int i = 0; i < 4; ++i) {
            const int task = t + i * 512;
            const int row  = task >> 4;
            const int c    = task & 15;
            const int rr = min(e0 + row, nTotal - 1);
            float d[8];
            if (rr < nA) {
                float* ph0 = A0 + (size_t)rr * DD + c * 8;
                const float4 a0 = *(const float4*)ph0;
                const float4 a1 = *(const float4*)(ph0 + 4);
                if (update) {
                    float* sp = sum_agg + (size_t)rr * DD + c * 8;
                    int*   mp = max_agg + (size_t)rr * DD + c * 8;
                    const float4 s0 = *(const float4*)sp;
                    const float4 s1 = *(const float4*)(sp + 4);
                    const int4   m0 = *(const int4*)mp;
                    const int4   m1 = *(const int4*)(mp + 4);
                    d[0] = a0.x * s0.x * __int_as_float(m0.x);
                    d[1] = a0.y * s0.y * __int_as_float(m0.y);
                    d[2] = a0.z * s0.z * __int_as_float(m0.z);
                    d[3] = a0.w * s0.w * __int_as_float(m0.w);
                    d[4] = a1.x * s1.x * __int_as_float(m1.x);
                    d[5] = a1.y * s1.y * __int_as_float(m1.y);
                    d[6] = a1.z * s1.z * __int_as_float(m1.z);
                    d[7] = a1.w * s1.w * __int_as_float(m1.w);
                    *(float4*)ph0       = make_float4(d[0], d[1], d[2], d[3]);
                    *(float4*)(ph0 + 4) = make_float4(d[4], d[5], d[6], d[7]);
                    *(float4*)sp       = make_float4(0.f, 0.f, 0.f, 0.f);
                    *(float4*)(sp + 4) = make_float4(0.f, 0.f, 0.f, 0.f);
                    *(int4*)mp       = make_int4(0, 0, 0, 0);
                    *(int4*)(mp + 4) = make_int4(0, 0, 0, 0);
                } else {
                    d[0] = a0.x; d[1] = a0.y; d[2] = a0.z; d[3] = a0.w;
                    d[4] = a1.x; d[5] = a1.y; d[6] = a1.z; d[7] = a1.w;
                }
            } else {
                const float* pa = A1 + (size_t)(rr - nA) * DD + c * 8;
                const float4 a0 = *(const float4*)pa;
                const float4 a1 = *(const float4*)(pa + 4);
                d[0] = a0.x; d[1] = a0.y; d[2] = a0.z; d[3] = a0.w;
                d[4] = a1.x; d[5] = a1.y; d[6] = a1.z; d[7] = a1.w;
            }
            unsigned h8[8], l8[8];
            #pragma unroll
            for (int j = 0; j < 8; ++j) {
                const unsigned hb = bf16_rne(d[j]);
                h8[j] = hb;
                l8[j] = bf16_rne(d[j] - __uint_as_float(hb << 16));
            }
            uint4 ph, pl;
            ph.x = h8[0] | (h8[1] << 16); ph.y = h8[2] | (h8[3] << 16);
            ph.z = h8[4] | (h8[5] << 16); ph.w = h8[6] | (h8[7] << 16);
            pl.x = l8[0] | (l8[1] << 16); pl.y = l8[2] | (l8[3] << 16);
            pl.z = l8[4] | (l8[5] << 16); pl.w = l8[6] | (l8[7] << 16);
            const int off = ((row * 256 + c * 16)) ^ ((row & 7) << 4);
            *(uint4*)(Ahi + off) = ph;
            *(uint4*)(Alo + off) = pl;
        }
        __syncthreads();

        // ---- MFMA: wave covers rows 0..127 (8 m-frags) x its 16 cols ----
        f32x4 acc[8];
        const f32x4 zero = {0.f, 0.f, 0.f, 0.f};
        #pragma unroll
        for (int m = 0; m < 8; ++m) acc[m] = zero;

        #pragma unroll
        for (int ks = 0; ks < 4; ++ks) {
            const int kbyte = ks * 64 + g * 16;
            #pragma unroll
            for (int m = 0; m < 8; ++m) {
                const int row = m * 16 + q;
                const int off = (row * 256 + kbyte) ^ ((row & 7) << 4);
                const bf16x8 ah = *(const bf16x8*)(Ahi + off);
                const bf16x8 al = *(const bf16x8*)(Alo + off);
                acc[m] = __builtin_amdgcn_mfma_f32_16x16x32_bf16(ah, wh[ks], acc[m], 0, 0, 0);
                acc[m] = __builtin_amdgcn_mfma_f32_16x16x32_bf16(ah, wl[ks], acc[m], 0, 0, 0);
                acc[m] = __builtin_amdgcn_mfma_f32_16x16x32_bf16(al, wh[ks], acc[m], 0, 0, 0);
            }
        }

        // ---- epilogue ----
        #pragma unroll
        for (int m = 0; m < 8; ++m) {
            #pragma unroll
            for (int r = 0; r < 4; ++r) {
                const int row = e0 + m * 16 + g * 4 + r;
                if (row < nTotal) {
                    float v = acc[m][r] + ((row < bias_limit) ? bv : 0.f);
                    if (do_relu) v = fmaxf(v, 0.f);
                    out0[(size_t)row * DD + colv] = v;
                    if (out1) out1[(size_t)row * DD + colv] = v;
                }
            }
        }
    }
}

// ---------------------------------------------------------------------------
// bond pass v5 (unchanged): 8 waves x 64 edges; W cols in regs; segmented
// ownership aggregation.
// ---------------------------------------------------------------------------
__global__ __launch_bounds__(512)
void bond_pass_kernel(const float* __restrict__ edge_attr,
                      const float* __restrict__ Wb, const float* __restrict__ bb,
                      const int* __restrict__ si, const int* __restrict__ perm,
                      float* __restrict__ h_head0,
                      float* __restrict__ sum_agg, int* __restrict__ max_agg,
                      int E, int N)
{
    __shared__ __align__(16) float ea_s[CB][16];   // 32 KB
    __shared__ int si_s[CB], pm_s[CB];             // 4 KB

    const int p0b = blockIdx.x * CB;
    if (p0b >= E) return;
    const int t = (int)threadIdx.x;

    for (int i = t; i < CB; i += 512) {
        const int p = min(p0b + i, E - 1);
        si_s[i] = si[p];
        pm_s[i] = perm[p];
    }
    for (int task = t; task < CB * 4; task += 512) {
        const int row = task >> 2;
        const int c4  = task & 3;
        const int p = min(p0b + row, E - 1);
        const int orig = perm[p];
        *(float4*)(&ea_s[row][c4 * 4]) =
            *(const float4*)(edge_attr + (size_t)orig * 16 + c4 * 4);
    }
    __syncthreads();

    const int w    = t >> 6;
    const int lane = t & 63;
    const int c    = lane * 2;
    const int q0   = w * 64;
    const int pg0  = p0b + q0;
    if (pg0 >= E) return;

    float wc0[16], wc1[16];
    #pragma unroll
    for (int k = 0; k < 16; ++k) {
        const float2 wv = *(const float2*)(Wb + k * DD + c);
        wc0[k] = wv.x; wc1[k] = wv.y;
    }
    const float2 bc = *(const float2*)(bb + c);

    const int firstNode = si_s[q0];
    const int lastNode  = si_s[q0 + 63];

    int curNode = firstNode;
    float2 rs = make_float2(0.f, 0.f), rm = make_float2(0.f, 0.f);

    #define BP_FLUSH()                                                           \
    {                                                                            \
        if (curNode == firstNode || curNode == lastNode) {                       \
            atomicAdd(&sum_agg[(size_t)curNode * DD + c],     rs.x);             \
            atomicAdd(&sum_agg[(size_t)curNode * DD + c + 1], rs.y);             \
            atomicMax(&max_agg[(size_t)curNode * DD + c],     __float_as_int(rm.x)); \
            atomicMax(&max_agg[(size_t)curNode * DD + c + 1], __float_as_int(rm.y)); \
        } else {                                                                 \
            *(float2*)(sum_agg + (size_t)curNode * DD + c) = rs;                 \
            *(int2*)(max_agg + (size_t)curNode * DD + c) =                       \
                make_int2(__float_as_int(rm.x), __float_as_int(rm.y));           \
        }                                                                        \
    }

    #pragma unroll 4
    for (int kk = 0; kk < 64; ++kk) {
        const int i = si_s[q0 + kk];
        if (i != curNode) {
            BP_FLUSH();
            curNode = i;
            rs = make_float2(0.f, 0.f);
            rm = make_float2(0.f, 0.f);
        }
        const float4* ear = (const float4*)(&ea_s[q0 + kk][0]);
        const float4 e0 = ear[0], e1 = ear[1], e2 = ear[2], e3 = ear[3];
        float ax = bc.x, ay = bc.y;
        ax = fmaf(e0.x, wc0[ 0], ax);  ay = fmaf(e0.x, wc1[ 0], ay);
        ax = fmaf(e0.y, wc0[ 1], ax);  ay = fmaf(e0.y, wc1[ 1], ay);
        ax = fmaf(e0.z, wc0[ 2], ax);  ay = fmaf(e0.z, wc1[ 2], ay);
        ax = fmaf(e0.w, wc0[ 3], ax);  ay = fmaf(e0.w, wc1[ 3], ay);
        ax = fmaf(e1.x, wc0[ 4], ax);  ay = fmaf(e1.x, wc1[ 4], ay);
        ax = fmaf(e1.y, wc0[ 5], ax);  ay = fmaf(e1.y, wc1[ 5], ay);
        ax = fmaf(e1.z, wc0[ 6], ax);  ay = fmaf(e1.z, wc1[ 6], ay);
        ax = fmaf(e1.w, wc0[ 7], ax);  ay = fmaf(e1.w, wc1[ 7], ay);
        ax = fmaf(e2.x, wc0[ 8], ax);  ay = fmaf(e2.x, wc1[ 8], ay);
        ax = fmaf(e2.y, wc0[ 9], ax);  ay = fmaf(e2.y, wc1[ 9], ay);
        ax = fmaf(e2.z, wc0[10], ax);  ay = fmaf(e2.z, wc1[10], ay);
        ax = fmaf(e2.w, wc0[11], ax);  ay = fmaf(e2.w, wc1[11], ay);
        ax = fmaf(e3.x, wc0[12], ax);  ay = fmaf(e3.x, wc1[12], ay);
        ax = fmaf(e3.y, wc0[13], ax);  ay = fmaf(e3.y, wc1[13], ay);
        ax = fmaf(e3.z, wc0[14], ax);  ay = fmaf(e3.z, wc1[14], ay);
        ax = fmaf(e3.w, wc0[15], ax);  ay = fmaf(e3.w, wc1[15], ay);
        float2 v;
        v.x = fmaxf(ax, 0.f);
        v.y = fmaxf(ay, 0.f);
        if (pg0 + kk >= E) { v.x = 0.f; v.y = 0.f; }
        rs.x += v.x; rs.y += v.y;
        rm.x = fmaxf(rm.x, v.x); rm.y = fmaxf(rm.y, v.y);
        if (pg0 + kk < E) {
            const int orig = pm_s[q0 + kk];
            if (orig < N) *(float2*)(h_head0 + (size_t)orig * DD + c) = v;
        }
    }
    BP_FLUSH();
    #undef BP_FLUSH
}

// ---------------------------------------------------------------------------
// edge pass v4 (unchanged): 8 waves x 64 edges + 8-deep prefetch;
// segmented ownership.
// ---------------------------------------------------------------------------
__global__ __launch_bounds__(512)
void edge_pass_kernel(const float* __restrict__ PQ,
                      const int* __restrict__ si, const int* __restrict__ sj,
                      const int* __restrict__ perm,
                      float* __restrict__ head_next, int store_head,
                      float* __restrict__ sum_agg, int* __restrict__ max_agg,
                      int E, int N)
{
    __shared__ int si_s[CE], sj_s[CE], pm_s[CE];
    const int p0b = blockIdx.x * CE;
    if (p0b >= E) return;
    const int t = (int)threadIdx.x;
    for (int i = t; i < CE; i += 512) {
        const int p = min(p0b + i, E - 1);
        si_s[i] = si[p];
        sj_s[i] = sj[p];
        pm_s[i] = perm[p];
    }
    __syncthreads();

    const int w    = t >> 6;
    const int lane = t & 63;
    const int c    = lane * 2;
    const int q0   = w * 64;
    const int pg0  = p0b + q0;
    if (pg0 >= E) return;

    const int firstNode = si_s[q0];
    const int lastNode  = si_s[q0 + 63];

    const float* __restrict__ Qbase = PQ + (size_t)N * DD + c;

    float2 qa = *(const float2*)(Qbase + (size_t)sj_s[q0 + 0] * DD);
    float2 qb = *(const float2*)(Qbase + (size_t)sj_s[q0 + 1] * DD);
    float2 qc = *(const float2*)(Qbase + (size_t)sj_s[q0 + 2] * DD);
    float2 qd = *(const float2*)(Qbase + (size_t)sj_s[q0 + 3] * DD);
    float2 qe = *(const float2*)(Qbase + (size_t)sj_s[q0 + 4] * DD);
    float2 qf = *(const float2*)(Qbase + (size_t)sj_s[q0 + 5] * DD);
    float2 qg = *(const float2*)(Qbase + (size_t)sj_s[q0 + 6] * DD);
    float2 qh = *(const float2*)(Qbase + (size_t)sj_s[q0 + 7] * DD);

    int curNode = firstNode;
    float2 Pi = *(const float2*)(PQ + (size_t)curNode * DD + c);
    float2 rs = make_float2(0.f, 0.f), rm = make_float2(0.f, 0.f);

    #define EP_FLUSH()                                                           \
    {                                                                            \
        if (curNode == firstNode || curNode == lastNode) {                       \
            atomicAdd(&sum_agg[(size_t)curNode * DD + c],     rs.x);             \
            atomicAdd(&sum_agg[(size_t)curNode * DD + c + 1], rs.y);             \
            atomicMax(&max_agg[(size_t)curNode * DD + c],     __float_as_int(rm.x)); \
            atomicMax(&max_agg[(size_t)curNode * DD + c + 1], __float_as_int(rm.y)); \
        } else {                                                                 \
            *(float2*)(sum_agg + (size_t)curNode * DD + c) = rs;                 \
            *(int2*)(max_agg + (size_t)curNode * DD + c) =                       \
                make_int2(__float_as_int(rm.x), __float_as_int(rm.y));           \
        }                                                                        \
    }

    #define EP_STEP(K, QREG)                                                     \
    {                                                                            \
        const int kk = (K);                                                      \
        const int i = si_s[q0 + kk];                                             \
        if (i != curNode) {                                                      \
            EP_FLUSH();                                                          \
            curNode = i;                                                         \
            Pi = *(const float2*)(PQ + (size_t)i * DD + c);                      \
            rs = make_float2(0.f, 0.f);                                          \
            rm = make_float2(0.f, 0.f);                                          \
        }                                                                        \
        float2 v;                                                                \
        v.x = fmaxf(Pi.x - QREG.x, 0.f);                                         \
        v.y = fmaxf(Pi.y - QREG.y, 0.f);                                         \
        if (pg0 + kk >= E) { v.x = 0.f; v.y = 0.f; }                             \
        rs.x += v.x; rs.y += v.y;                                                \
        rm.x = fmaxf(rm.x, v.x); rm.y = fmaxf(rm.y, v.y);                        \
        if (store_head && (pg0 + kk) < E) {                                      \
            const int orig = pm_s[q0 + kk];                                      \
            if (orig < N) *(float2*)(head_next + (size_t)orig * DD + c) = v;     \
        }                                                                        \
        if (kk + 8 < 64)                                                         \
            QREG = *(const float2*)(Qbase + (size_t)sj_s[q0 + kk + 8] * DD);     \
    }

    #pragma unroll
    for (int k = 0; k < 64; k += 8) {
        EP_STEP(k + 0, qa);
        EP_STEP(k + 1, qb);
        EP_STEP(k + 2, qc);
        EP_STEP(k + 3, qd);
        EP_STEP(k + 4, qe);
        EP_STEP(k + 5, qf);
        EP_STEP(k + 6, qg);
        EP_STEP(k + 7, qh);
    }
    EP_FLUSH();
    #undef EP_STEP
    #undef EP_FLUSH
}

// ---------------------------------------------------------------------------
// final: out = [ha, x_proj] @ W_lin + b_lin via split-bf16 MFMA, K=256
// (unchanged)
// ---------------------------------------------------------------------------
__global__ __launch_bounds__(512, 2)
void final_mfma_kernel(const float* __restrict__ h, const float* __restrict__ sum_agg,
                       const int* __restrict__ max_agg, const float* __restrict__ xp,
                       const float* __restrict__ Wl, const float* __restrict__ bl,
                       float* __restrict__ out, int N)
{
    __shared__ __align__(16) unsigned char SM[65808];
    char*  const Whi = (char*)SM;
    char*  const Wlo = (char*)SM + 32768;
    float* const Wf  = (float*)SM;
    float* const bs  = (float*)(SM + 65536);

    const int t = (int)threadIdx.x;
    {
        const float4* Wg = (const float4*)Wl;
        float4* Wd = (float4*)Wf;
        #pragma unroll
        for (int i = 0; i < 8; ++i) Wd[t + i * 512] = Wg[t + i * 512];
        if (t < 64) bs[t] = bl[t];
    }
    __syncthreads();
    {
        const int col = t & 63;
        const int kb  = (t >> 6) * 32;
        float v[32];
        #pragma unroll
        for (int j = 0; j < 32; ++j) v[j] = Wf[(size_t)(kb + j) * 64 + col];
        __syncthreads();
        #pragma unroll
        for (int c = 0; c < 4; ++c) {
            unsigned h8[8], l8[8];
            #pragma unroll
            for (int j = 0; j < 8; ++j) {
                const float w0 = v[c * 8 + j];
                const unsigned hb = bf16_rne(w0);
                h8[j] = hb;
                l8[j] = bf16_rne(w0 - __uint_as_float(hb << 16));
            }
            uint4 ph, pl;
            ph.x = h8[0] | (h8[1] << 16); ph.y = h8[2] | (h8[3] << 16);
            ph.z = h8[4] | (h8[5] << 16); ph.w = h8[6] | (h8[7] << 16);
            pl.x = l8[0] | (l8[1] << 16); pl.y = l8[2] | (l8[3] << 16);
            pl.z = l8[4] | (l8[5] << 16); pl.w = l8[6] | (l8[7] << 16);
            const int off = (col * 512 + (kb + c * 8) * 2) ^ ((col & 7) << 4);
            *(uint4*)(Whi + off) = ph;
            *(uint4*)(Wlo + off) = pl;
        }
    }
    __syncthreads();

    const int w  = t >> 6;
    const int l  = t & 63;
    const int wm = w >> 1;
    const int wn = w & 1;
    const int g  = l >> 4;
    const int q  = l & 15;
    const int r0 = (int)blockIdx.x * 128;

    f32x4 acc[2][2];
    const f32x4 zero = {0.f, 0.f, 0.f, 0.f};
    acc[0][0] = zero; acc[0][1] = zero; acc[1][0] = zero; acc[1][1] = zero;

    #pragma unroll
    for (int ks = 0; ks < 8; ++ks) {
        const int kf = (ks & 3) * 32 + g * 8;
        bf16x8 ah[2], al[2];
        #pragma unroll
        for (int m = 0; m < 2; ++m) {
            const int rr = min(r0 + wm * 32 + m * 16 + q, N - 1);
            float d[8];
            if (ks < 4) {
                const float* ph = h       + (size_t)rr * DD + kf;
                const float* ps = sum_agg + (size_t)rr * DD + kf;
                const int*   pm = max_agg + (size_t)rr * DD + kf;
                const float4 a0 = *(const float4*)ph;
                const float4 a1 = *(const float4*)(ph + 4);
                const float4 s0 = *(const float4*)ps;
                const float4 s1 = *(const float4*)(ps + 4);
                const int4   i0 = *(const int4*)pm;
                const int4   i1 = *(const int4*)(pm + 4);
                d[0] = a0.x * a0.x * s0.x * __int_as_float(i0.x);
                d[1] = a0.y * a0.y * s0.y * __int_as_float(i0.y);
                d[2] = a0.z * a0.z * s0.z * __int_as_float(i0.z);
                d[3] = a0.w * a0.w * s0.w * __int_as_float(i0.w);
                d[4] = a1.x * a1.x * s1.x * __int_as_float(i1.x);
                d[5] = a1.y * a1.y * s1.y * __int_as_float(i1.y);
                d[6] = a1.z * a1.z * s1.z * __int_as_float(i1.z);
                d[7] = a1.w * a1.w * s1.w * __int_as_float(i1.w);
            } else {
                const float* pa = xp + (size_t)rr * DD + kf;
                const float4 a0 = *(const float4*)pa;
                const float4 a1 = *(const float4*)(pa + 4);
                d[0] = a0.x; d[1] = a0.y; d[2] = a0.z; d[3] = a0.w;
                d[4] = a1.x; d[5] = a1.y; d[6] = a1.z; d[7] = a1.w;
            }
            unsigned h8[8], l8[8];
            #pragma unroll
            for (int j = 0; j < 8; ++j) {
                const unsigned hb = bf16_rne(d[j]);
                h8[j] = hb;
                l8[j] = bf16_rne(d[j] - __uint_as_float(hb << 16));
            }
            uint4 ph2, pl2;
            ph2.x = h8[0] | (h8[1] << 16); ph2.y = h8[2] | (h8[3] << 16);
            ph2.z = h8[4] | (h8[5] << 16); ph2.w = h8[6] | (h8[7] << 16);
            pl2.x = l8[0] | (l8[1] << 16); pl2.y = l8[2] | (l8[3] << 16);
            pl2.z = l8[4] | (l8[5] << 16); pl2.w = l8[6] | (l8[7] << 16);
            ah[m] = *(bf16x8*)&ph2;
            al[m] = *(bf16x8*)&pl2;
        }
        bf16x8 bh[2], blo[2];
        #pragma unroll
        for (int n = 0; n < 2; ++n) {
            const int colv = wn * 32 + n * 16 + q;
            const int off = (colv * 512 + ks * 64 + g * 16) ^ ((colv & 7) << 4);
            bh[n]  = *(const bf16x8*)(Whi + off);
            blo[n] = *(const bf16x8*)(Wlo + off);
        }
        #pragma unroll
        for (int m = 0; m < 2; ++m)
            #pragma unroll
            for (int n = 0; n < 2; ++n) {
                acc[m][n] = __builtin_amdgcn_mfma_f32_16x16x32_bf16(ah[m], bh[n],  acc[m][n], 0, 0, 0);
                acc[m][n] = __builtin_amdgcn_mfma_f32_16x16x32_bf16(ah[m], blo[n], acc[m][n], 0, 0, 0);
                acc[m][n] = __builtin_amdgcn_mfma_f32_16x16x32_bf16(al[m], bh[n],  acc[m][n], 0, 0, 0);
            }
    }

    #pragma unroll
    for (int n = 0; n < 2; ++n) {
        const int colv = wn * 32 + n * 16 + q;
        const float bv = bs[colv];
        #pragma unroll
        for (int m = 0; m < 2; ++m) {
            #pragma unroll
            for (int r = 0; r < 4; ++r) {
                const int row = r0 + wm * 32 + m * 16 + g * 4 + r;
                if (row < N) out[(size_t)row * 64 + colv] = acc[m][n][r] + bv;
            }
        }
    }
}

// ---------------------------------------------------------------------------
extern "C" void kernel_launch(void* const* d_in, const int* in_sizes, int n_in,
                              void* d_out, int out_size, void* d_ws, size_t ws_size,
                              hipStream_t stream)
{
    const float* x         = (const float*)d_in[0];
    const int*   edge_idx  = (const int*)d_in[1];
    const float* edge_attr = (const float*)d_in[2];
    const float* W_atom    = (const float*)d_in[3];
    const float* b_atom    = (const float*)d_in[4];
    const float* W_bond    = (const float*)d_in[5];
    const float* b_bond    = (const float*)d_in[6];
    const float* W_seq     = (const float*)d_in[7];
    const float* b_seq     = (const float*)d_in[8];
    const float* W_lin     = (const float*)d_in[9];
    const float* b_lin     = (const float*)d_in[10];
    float* out = (float*)d_out;

    const int N = in_sizes[0] / DD;   // 30000
    const int E = in_sizes[1] / 2;    // 480000
    const int* idx_i = edge_idx;
    const int* idx_j = edge_idx + E;

    const size_t nd = (size_t)N * DD;
    float* ws      = (float*)d_ws;
    float* x_proj  = ws;
    float* h_atom  = x_proj + nd;
    float* head    = h_atom + nd;
    float* sum_agg = head + nd;
    int*   max_agg = (int*)(sum_agg + nd);
    float* PQ      = (float*)(max_agg + nd);   // 2N x 128
    int*   cnt     = (int*)(PQ + 2 * nd);
    int*   cursor  = cnt + N;
    int*   bsum    = cursor + N;
    int*   perm    = bsum + 256;
    int*   si      = perm + E;
    int*   sj      = si + E;

    // ---- counting sort of edges by idx_i ----
    hipMemsetAsync(cnt, 0, (size_t)N * 4, stream);
    hist_kernel<<<(E + 255) / 256, 256, 0, stream>>>(idx_i, cnt, E);
    const int nb_scan = (N + SCB - 1) / SCB;
    scan1_kernel<<<nb_scan, SCB, 0, stream>>>(cnt, cursor, bsum, N);
    scan2_kernel<<<1, SCB, 0, stream>>>(bsum, nb_scan);
    scan3_kernel<<<nb_scan, SCB, 0, stream>>>(cursor, bsum, N);
    scatter_kernel<<<(E + 255) / 256, 256, 0, stream>>>(idx_i, idx_j, cursor, perm, si, sj, E);

    hipMemsetAsync(sum_agg, 0, nd * 4, stream);
    hipMemsetAsync(max_agg, 0, nd * 4, stream);

    // node projection via MFMA: x_proj = h_atom = relu(x @ W_atom + b_atom)
    const int ntiles_n = (N + 127) / 128;
    gemm128_mfma_kernel<<<ntiles_n, 512, 0, stream>>>(
        (float*)x, x, N, N, W_atom, b_atom, N, 1, 0, nullptr, nullptr,
        x_proj, h_atom, ntiles_n);

    // bond projection + layer-0 aggregation (v5)
    bond_pass_kernel<<<(E + CB - 1) / CB, 512, 0, stream>>>(
        edge_attr, W_bond, b_bond, si, perm, head, sum_agg, max_agg, E, N);

    const int ntiles_pq = (2 * N + 127) / 128;
    const int ep_blocks = (E + CE - 1) / CE;
    for (int l = 0; l < 3; ++l) {
        gemm128_mfma_kernel<<<ntiles_pq, 512, 0, stream>>>(
            h_atom, head, N, 2 * N, W_seq + (size_t)l * DD * DD,
            b_seq + (size_t)l * DD, N, 0, 1, sum_agg, max_agg,
            PQ, nullptr, ntiles_pq);
        edge_pass_kernel<<<ep_blocks, 512, 0, stream>>>(
            PQ, si, sj, perm, head, (l < 2) ? 1 : 0, sum_agg, max_agg, E, N);
    }

    final_mfma_kernel<<<(N + 127) / 128, 512, 0, stream>>>(
        h_atom, sum_agg, (const int*)max_agg, x_proj, W_lin, b_lin, out, N);
}

// Round 14
// 387.386 us; speedup vs baseline: 1.1778x; 1.0052x over previous
//
#include <hip/hip_runtime.h>
#include <hip/hip_bf16.h>

#define DD 128   // hidden dim
#define SCB 256  // scan block size
#define CE  512  // edges per block in edge_pass (8 waves x 64)
#define CB  512  // edges per block in bond pass (8 waves x 64)

typedef __attribute__((ext_vector_type(8))) short bf16x8;
typedef __attribute__((ext_vector_type(4))) float f32x4;
typedef __attribute__((ext_vector_type(2))) _Float16 f16x2;
typedef __attribute__((ext_vector_type(8))) _Float16 f16x8;

__device__ __forceinline__ unsigned bf16_rne(float f) {
    unsigned u = __float_as_uint(f);
    return (u + 0x7fffu + ((u >> 16) & 1u)) >> 16;
}

// ---------------------------------------------------------------------------
// counting-sort preprocessing (sort edges by idx_i)
// ---------------------------------------------------------------------------
__global__ __launch_bounds__(256)
void hist_kernel(const int* __restrict__ idx_i, int* __restrict__ cnt, int E)
{
    const int e = blockIdx.x * 256 + threadIdx.x;
    if (e < E) atomicAdd(&cnt[idx_i[e]], 1);
}

__global__ __launch_bounds__(SCB)
void scan1_kernel(const int* __restrict__ cnt, int* __restrict__ exc,
                  int* __restrict__ bsum, int n)
{
    __shared__ int s[SCB];
    const int i = blockIdx.x * SCB + (int)threadIdx.x;
    const int v = (i < n) ? cnt[i] : 0;
    s[threadIdx.x] = v;
    __syncthreads();
    #pragma unroll
    for (int off = 1; off < SCB; off <<= 1) {
        int t = (threadIdx.x >= off) ? s[threadIdx.x - off] : 0;
        __syncthreads();
        s[threadIdx.x] += t;
        __syncthreads();
    }
    if (i < n) exc[i] = s[threadIdx.x] - v;
    if (threadIdx.x == SCB - 1) bsum[blockIdx.x] = s[threadIdx.x];
}

__global__ __launch_bounds__(SCB)
void scan2_kernel(int* __restrict__ bsum, int nb)
{
    __shared__ int s[SCB];
    const int v = (threadIdx.x < nb) ? bsum[threadIdx.x] : 0;
    s[threadIdx.x] = v;
    __syncthreads();
    #pragma unroll
    for (int off = 1; off < SCB; off <<= 1) {
        int t = (threadIdx.x >= off) ? s[threadIdx.x - off] : 0;
        __syncthreads();
        s[threadIdx.x] += t;
        __syncthreads();
    }
    if (threadIdx.x < nb) bsum[threadIdx.x] = s[threadIdx.x] - v;
}

__global__ __launch_bounds__(SCB)
void scan3_kernel(int* __restrict__ exc, const int* __restrict__ bsum, int n)
{
    const int i = blockIdx.x * SCB + (int)threadIdx.x;
    if (i < n) exc[i] += bsum[i >> 8];
}

__global__ __launch_bounds__(256)
void scatter_kernel(const int* __restrict__ idx_i, const int* __restrict__ idx_j,
                    int* __restrict__ cursor, int* __restrict__ perm,
                    int* __restrict__ si, int* __restrict__ sj, int E)
{
    const int e = blockIdx.x * 256 + threadIdx.x;
    if (e < E) {
        const int n = idx_i[e];
        const int p = atomicAdd(&cursor[n], 1);
        perm[p] = e;
        si[p] = n;
        sj[p] = idx_j[e];
    }
}

// ---------------------------------------------------------------------------
// gemm128 v2 (unchanged from R13): W fragments in registers, A-only LDS.
// ---------------------------------------------------------------------------
__global__ __launch_bounds__(512, 4)
void gemm128_mfma_kernel(float* __restrict__ A0, const float* __restrict__ A1,
                         int nA, int nTotal,
                         const float* __restrict__ W, const float* __restrict__ bias,
                         int bias_limit, int do_relu, int update,
                         float* __restrict__ sum_agg, int* __restrict__ max_agg,
                         float* __restrict__ out0, float* __restrict__ out1,
                         int ntiles)
{
    __shared__ __align__(16) unsigned char SM[65536];
    char* const Ahi = (char*)SM;
    char* const Alo = (char*)SM + 32768;

    const int t = (int)threadIdx.x;
    const int w = t >> 6;
    const int l = t & 63;
    const int g = l >> 4;
    const int q = l & 15;
    const int colv = w * 16 + q;

    bf16x8 wh[4], wl[4];
    #pragma unroll
    for (int ks = 0; ks < 4; ++ks) {
        unsigned h8[8], l8[8];
        #pragma unroll
        for (int j = 0; j < 8; ++j) {
            const float w0 = W[(size_t)(ks * 32 + g * 8 + j) * DD + colv];
            const unsigned hb = bf16_rne(w0);
            h8[j] = hb;
            l8[j] = bf16_rne(w0 - __uint_as_float(hb << 16));
        }
        uint4 ph, pl;
        ph.x = h8[0] | (h8[1] << 16); ph.y = h8[2] | (h8[3] << 16);
        ph.z = h8[4] | (h8[5] << 16); ph.w = h8[6] | (h8[7] << 16);
        pl.x = l8[0] | (l8[1] << 16); pl.y = l8[2] | (l8[3] << 16);
        pl.z = l8[4] | (l8[5] << 16); pl.w = l8[6] | (l8[7] << 16);
        wh[ks] = *(bf16x8*)&ph;
        wl[ks] = *(bf16x8*)&pl;
    }
    const float bv = bias ? bias[colv] : 0.f;

    for (int tile = blockIdx.x; tile < ntiles; tile += gridDim.x) {
        const int e0 = tile * 128;
        __syncthreads();

        #pragma unroll
        for (int i = 0; i < 4; ++i) {
            const int task = t + i * 512;
            const int row  = task >> 4;
            const int c    = task & 15;
            const int rr = min(e0 + row, nTotal - 1);
            float d[8];
            if (rr < nA) {
                float* ph0 = A0 + (size_t)rr * DD + c * 8;
                const float4 a0 = *(const float4*)ph0;
                const float4 a1 = *(const float4*)(ph0 + 4);
                if (update) {
                    float* sp = sum_agg + (size_t)rr * DD + c * 8;
                    int*   mp = max_agg + (size_t)rr * DD + c * 8;
                    const float4 s0 = *(const float4*)sp;
                    const float4 s1 = *(const float4*)(sp + 4);
                    const int4   m0 = *(const int4*)mp;
                    const int4   m1 = *(const int4*)(mp + 4);
                    d[0] = a0.x * s0.x * __int_as_float(m0.x);
                    d[1] = a0.y * s0.y * __int_as_float(m0.y);
                    d[2] = a0.z * s0.z * __int_as_float(m0.z);
                    d[3] = a0.w * s0.w * __int_as_float(m0.w);
                    d[4] = a1.x * s1.x * __int_as_float(m1.x);
                    d[5] = a1.y * s1.y * __int_as_float(m1.y);
                    d[6] = a1.z * s1.z * __int_as_float(m1.z);
                    d[7] = a1.w * s1.w * __int_as_float(m1.w);
                    *(float4*)ph0       = make_float4(d[0], d[1], d[2], d[3]);
                    *(float4*)(ph0 + 4) = make_float4(d[4], d[5], d[6], d[7]);
                    *(float4*)sp       = make_float4(0.f, 0.f, 0.f, 0.f);
                    *(float4*)(sp + 4) = make_float4(0.f, 0.f, 0.f, 0.f);
                    *(int4*)mp       = make_int4(0, 0, 0, 0);
                    *(int4*)(mp + 4) = make_int4(0, 0, 0, 0);
                } else {
                    d[0] = a0.x; d[1] = a0.y; d[2] = a0.z; d[3] = a0.w;
                    d[4] = a1.x; d[5] = a1.y; d[6] = a1.z; d[7] = a1.w;
                }
            } else {
                const float* pa = A1 + (size_t)(rr - nA) * DD + c * 8;
                const float4 a0 = *(const float4*)pa;
                const float4 a1 = *(const float4*)(pa + 4);
                d[0] = a0.x; d[1] = a0.y; d[2] = a0.z; d[3] = a0.w;
                d[4] = a1.x; d[5] = a1.y; d[6] = a1.z; d[7] = a1.w;
            }
            unsigned h8[8], l8[8];
            #pragma unroll
            for (int j = 0; j < 8; ++j) {
                const unsigned hb = bf16_rne(d[j]);
                h8[j] = hb;
                l8[j] = bf16_rne(d[j] - __uint_as_float(hb << 16));
            }
            uint4 ph, pl;
            ph.x = h8[0] | (h8[1] << 16); ph.y = h8[2] | (h8[3] << 16);
            ph.z = h8[4] | (h8[5] << 16); ph.w = h8[6] | (h8[7] << 16);
            pl.x = l8[0] | (l8[1] << 16); pl.y = l8[2] | (l8[3] << 16);
            pl.z = l8[4] | (l8[5] << 16); pl.w = l8[6] | (l8[7] << 16);
            const int off = ((row * 256 + c * 16)) ^ ((row & 7) << 4);
            *(uint4*)(Ahi + off) = ph;
            *(uint4*)(Alo + off) = pl;
        }
        __syncthreads();

        f32x4 acc[8];
        const f32x4 zero = {0.f, 0.f, 0.f, 0.f};
        #pragma unroll
        for (int m = 0; m < 8; ++m) acc[m] = zero;

        #pragma unroll
        for (int ks = 0; ks < 4; ++ks) {
            const int kbyte = ks * 64 + g * 16;
            #pragma unroll
            for (int m = 0; m < 8; ++m) {
                const int row = m * 16 + q;
                const int off = (row * 256 + kbyte) ^ ((row & 7) << 4);
                const bf16x8 ah = *(const bf16x8*)(Ahi + off);
                const bf16x8 al = *(const bf16x8*)(Alo + off);
                acc[m] = __builtin_amdgcn_mfma_f32_16x16x32_bf16(ah, wh[ks], acc[m], 0, 0, 0);
                acc[m] = __builtin_amdgcn_mfma_f32_16x16x32_bf16(ah, wl[ks], acc[m], 0, 0, 0);
                acc[m] = __builtin_amdgcn_mfma_f32_16x16x32_bf16(al, wh[ks], acc[m], 0, 0, 0);
            }
        }

        #pragma unroll
        for (int m = 0; m < 8; ++m) {
            #pragma unroll
            for (int r = 0; r < 4; ++r) {
                const int row = e0 + m * 16 + g * 4 + r;
                if (row < nTotal) {
                    float v = acc[m][r] + ((row < bias_limit) ? bv : 0.f);
                    if (do_relu) v = fmaxf(v, 0.f);
                    out0[(size_t)row * DD + colv] = v;
                    if (out1) out1[(size_t)row * DD + colv] = v;
                }
            }
        }
    }
}

// ---------------------------------------------------------------------------
// bond pass v6: f16 dot2 projection. edge_attr staged as f16 in LDS (16 KB),
// W cols in packed half2 registers; 16 x v_dot2_f32_f16 per edge replaces
// 32 FMA, LDS reads halve. Segmented-ownership aggregation unchanged.
// ---------------------------------------------------------------------------
__global__ __launch_bounds__(512)
void bond_pass_kernel(const float* __restrict__ edge_attr,
                      const float* __restrict__ Wb, const float* __restrict__ bb,
                      const int* __restrict__ si, const int* __restrict__ perm,
                      float* __restrict__ h_head0,
                      float* __restrict__ sum_agg, int* __restrict__ max_agg,
                      int E, int N)
{
    __shared__ __align__(16) _Float16 ea_s[CB][16];   // 16 KB
    __shared__ int si_s[CB], pm_s[CB];                // 4 KB

    const int p0b = blockIdx.x * CB;
    if (p0b >= E) return;
    const int t = (int)threadIdx.x;

    for (int i = t; i < CB; i += 512) {
        const int p = min(p0b + i, E - 1);
        si_s[i] = si[p];
        pm_s[i] = perm[p];
    }
    // stage edge_attr rows as f16 (task = row*2 + 8-elem half)
    for (int task = t; task < CB * 2; task += 512) {
        const int row = task >> 1;
        const int h8i = task & 1;
        const int p = min(p0b + row, E - 1);
        const int orig = perm[p];
        const float4 a0 = *(const float4*)(edge_attr + (size_t)orig * 16 + h8i * 8);
        const float4 a1 = *(const float4*)(edge_attr + (size_t)orig * 16 + h8i * 8 + 4);
        f16x8 hv;
        hv[0] = (_Float16)a0.x; hv[1] = (_Float16)a0.y;
        hv[2] = (_Float16)a0.z; hv[3] = (_Float16)a0.w;
        hv[4] = (_Float16)a1.x; hv[5] = (_Float16)a1.y;
        hv[6] = (_Float16)a1.z; hv[7] = (_Float16)a1.w;
        *(f16x8*)(&ea_s[row][h8i * 8]) = hv;
    }
    __syncthreads();

    const int w    = t >> 6;         // wave 0..7
    const int lane = t & 63;
    const int c    = lane * 2;
    const int q0   = w * 64;
    const int pg0  = p0b + q0;
    if (pg0 >= E) return;

    // W columns c, c+1 as packed half2 along k (k-pairs)
    f16x2 w0h[8], w1h[8];
    #pragma unroll
    for (int k = 0; k < 8; ++k) {
        const float2 wa = *(const float2*)(Wb + (2 * k)     * DD + c);
        const float2 wb2 = *(const float2*)(Wb + (2 * k + 1) * DD + c);
        w0h[k][0] = (_Float16)wa.x; w0h[k][1] = (_Float16)wb2.x;
        w1h[k][0] = (_Float16)wa.y; w1h[k][1] = (_Float16)wb2.y;
    }
    const float2 bc = *(const float2*)(bb + c);

    const int firstNode = si_s[q0];
    const int lastNode  = si_s[q0 + 63];

    int curNode = firstNode;
    float2 rs = make_float2(0.f, 0.f), rm = make_float2(0.f, 0.f);

    #define BP_FLUSH()                                                           \
    {                                                                            \
        if (curNode == firstNode || curNode == lastNode) {                       \
            atomicAdd(&sum_agg[(size_t)curNode * DD + c],     rs.x);             \
            atomicAdd(&sum_agg[(size_t)curNode * DD + c + 1], rs.y);             \
            atomicMax(&max_agg[(size_t)curNode * DD + c],     __float_as_int(rm.x)); \
            atomicMax(&max_agg[(size_t)curNode * DD + c + 1], __float_as_int(rm.y)); \
        } else {                                                                 \
            *(float2*)(sum_agg + (size_t)curNode * DD + c) = rs;                 \
            *(int2*)(max_agg + (size_t)curNode * DD + c) =                       \
                make_int2(__float_as_int(rm.x), __float_as_int(rm.y));           \
        }                                                                        \
    }

    #pragma unroll 4
    for (int kk = 0; kk < 64; ++kk) {
        const int i = si_s[q0 + kk];
        if (i != curNode) {
            BP_FLUSH();
            curNode = i;
            rs = make_float2(0.f, 0.f);
            rm = make_float2(0.f, 0.f);
        }
        const f16x8 e0 = *(const f16x8*)(&ea_s[q0 + kk][0]);
        const f16x8 e1 = *(const f16x8*)(&ea_s[q0 + kk][8]);
        float ax = bc.x, ay = bc.y;
        f16x2 p2;
        p2[0] = e0[0]; p2[1] = e0[1];
        ax = __builtin_amdgcn_fdot2(p2, w0h[0], ax, false);
        ay = __builtin_amdgcn_fdot2(p2, w1h[0], ay, false);
        p2[0] = e0[2]; p2[1] = e0[3];
        ax = __builtin_amdgcn_fdot2(p2, w0h[1], ax, false);
        ay = __builtin_amdgcn_fdot2(p2, w1h[1], ay, false);
        p2[0] = e0[4]; p2[1] = e0[5];
        ax = __builtin_amdgcn_fdot2(p2, w0h[2], ax, false);
        ay = __builtin_amdgcn_fdot2(p2, w1h[2], ay, false);
        p2[0] = e0[6]; p2[1] = e0[7];
        ax = __builtin_amdgcn_fdot2(p2, w0h[3], ax, false);
        ay = __builtin_amdgcn_fdot2(p2, w1h[3], ay, false);
        p2[0] = e1[0]; p2[1] = e1[1];
        ax = __builtin_amdgcn_fdot2(p2, w0h[4], ax, false);
        ay = __builtin_amdgcn_fdot2(p2, w1h[4], ay, false);
        p2[0] = e1[2]; p2[1] = e1[3];
        ax = __builtin_amdgcn_fdot2(p2, w0h[5], ax, false);
        ay = __builtin_amdgcn_fdot2(p2, w1h[5], ay, false);
        p2[0] = e1[4]; p2[1] = e1[5];
        ax = __builtin_amdgcn_fdot2(p2, w0h[6], ax, false);
        ay = __builtin_amdgcn_fdot2(p2, w1h[6], ay, false);
        p2[0] = e1[6]; p2[1] = e1[7];
        ax = __builtin_amdgcn_fdot2(p2, w0h[7], ax, false);
        ay = __builtin_amdgcn_fdot2(p2, w1h[7], ay, false);
        float2 v;
        v.x = fmaxf(ax, 0.f);
        v.y = fmaxf(ay, 0.f);
        if (pg0 + kk >= E) { v.x = 0.f; v.y = 0.f; }
        rs.x += v.x; rs.y += v.y;
        rm.x = fmaxf(rm.x, v.x); rm.y = fmaxf(rm.y, v.y);
        if (pg0 + kk < E) {
            const int orig = pm_s[q0 + kk];
            if (orig < N) *(float2*)(h_head0 + (size_t)orig * DD + c) = v;
        }
    }
    BP_FLUSH();
    #undef BP_FLUSH
}

// ---------------------------------------------------------------------------
// edge pass v4 (unchanged): 8 waves x 64 edges + 8-deep prefetch;
// segmented ownership.
// ---------------------------------------------------------------------------
__global__ __launch_bounds__(512)
void edge_pass_kernel(const float* __restrict__ PQ,
                      const int* __restrict__ si, const int* __restrict__ sj,
                      const int* __restrict__ perm,
                      float* __restrict__ head_next, int store_head,
                      float* __restrict__ sum_agg, int* __restrict__ max_agg,
                      int E, int N)
{
    __shared__ int si_s[CE], sj_s[CE], pm_s[CE];
    const int p0b = blockIdx.x * CE;
    if (p0b >= E) return;
    const int t = (int)threadIdx.x;
    for (int i = t; i < CE; i += 512) {
        const int p = min(p0b + i, E - 1);
        si_s[i] = si[p];
        sj_s[i] = sj[p];
        pm_s[i] = perm[p];
    }
    __syncthreads();

    const int w    = t >> 6;
    const int lane = t & 63;
    const int c    = lane * 2;
    const int q0   = w * 64;
    const int pg0  = p0b + q0;
    if (pg0 >= E) return;

    const int firstNode = si_s[q0];
    const int lastNode  = si_s[q0 + 63];

    const float* __restrict__ Qbase = PQ + (size_t)N * DD + c;

    float2 qa = *(const float2*)(Qbase + (size_t)sj_s[q0 + 0] * DD);
    float2 qb = *(const float2*)(Qbase + (size_t)sj_s[q0 + 1] * DD);
    float2 qc = *(const float2*)(Qbase + (size_t)sj_s[q0 + 2] * DD);
    float2 qd = *(const float2*)(Qbase + (size_t)sj_s[q0 + 3] * DD);
    float2 qe = *(const float2*)(Qbase + (size_t)sj_s[q0 + 4] * DD);
    float2 qf = *(const float2*)(Qbase + (size_t)sj_s[q0 + 5] * DD);
    float2 qg = *(const float2*)(Qbase + (size_t)sj_s[q0 + 6] * DD);
    float2 qh = *(const float2*)(Qbase + (size_t)sj_s[q0 + 7] * DD);

    int curNode = firstNode;
    float2 Pi = *(const float2*)(PQ + (size_t)curNode * DD + c);
    float2 rs = make_float2(0.f, 0.f), rm = make_float2(0.f, 0.f);

    #define EP_FLUSH()                                                           \
    {                                                                            \
        if (curNode == firstNode || curNode == lastNode) {                       \
            atomicAdd(&sum_agg[(size_t)curNode * DD + c],     rs.x);             \
            atomicAdd(&sum_agg[(size_t)curNode * DD + c + 1], rs.y);             \
            atomicMax(&max_agg[(size_t)curNode * DD + c],     __float_as_int(rm.x)); \
            atomicMax(&max_agg[(size_t)curNode * DD + c + 1], __float_as_int(rm.y)); \
        } else {                                                                 \
            *(float2*)(sum_agg + (size_t)curNode * DD + c) = rs;                 \
            *(int2*)(max_agg + (size_t)curNode * DD + c) =                       \
                make_int2(__float_as_int(rm.x), __float_as_int(rm.y));           \
        }                                                                        \
    }

    #define EP_STEP(K, QREG)                                                     \
    {                                                                            \
        const int kk = (K);                                                      \
        const int i = si_s[q0 + kk];                                             \
        if (i != curNode) {                                                      \
            EP_FLUSH();                                                          \
            curNode = i;                                                         \
            Pi = *(const float2*)(PQ + (size_t)i * DD + c);                      \
            rs = make_float2(0.f, 0.f);                                          \
            rm = make_float2(0.f, 0.f);                                          \
        }                                                                        \
        float2 v;                                                                \
        v.x = fmaxf(Pi.x - QREG.x, 0.f);                                         \
        v.y = fmaxf(Pi.y - QREG.y, 0.f);                                         \
        if (pg0 + kk >= E) { v.x = 0.f; v.y = 0.f; }                             \
        rs.x += v.x; rs.y += v.y;                                                \
        rm.x = fmaxf(rm.x, v.x); rm.y = fmaxf(rm.y, v.y);                        \
        if (store_head && (pg0 + kk) < E) {                                      \
            const int orig = pm_s[q0 + kk];                                      \
            if (orig < N) *(float2*)(head_next + (size_t)orig * DD + c) = v;     \
        }                                                                        \
        if (kk + 8 < 64)                                                         \
            QREG = *(const float2*)(Qbase + (size_t)sj_s[q0 + kk + 8] * DD);     \
    }

    #pragma unroll
    for (int k = 0; k < 64; k += 8) {
        EP_STEP(k + 0, qa);
        EP_STEP(k + 1, qb);
        EP_STEP(k + 2, qc);
        EP_STEP(k + 3, qd);
        EP_STEP(k + 4, qe);
        EP_STEP(k + 5, qf);
        EP_STEP(k + 6, qg);
        EP_STEP(k + 7, qh);
    }
    EP_FLUSH();
    #undef EP_STEP
    #undef EP_FLUSH
}

// ---------------------------------------------------------------------------
// final: out = [ha, x_proj] @ W_lin + b_lin via split-bf16 MFMA, K=256
// (unchanged)
// ---------------------------------------------------------------------------
__global__ __launch_bounds__(512, 2)
void final_mfma_kernel(const float* __restrict__ h, const float* __restrict__ sum_agg,
                       const int* __restrict__ max_agg, const float* __restrict__ xp,
                       const float* __restrict__ Wl, const float* __restrict__ bl,
                       float* __restrict__ out, int N)
{
    __shared__ __align__(16) unsigned char SM[65808];
    char*  const Whi = (char*)SM;
    char*  const Wlo = (char*)SM + 32768;
    float* const Wf  = (float*)SM;
    float* const bs  = (float*)(SM + 65536);

    const int t = (int)threadIdx.x;
    {
        const float4* Wg = (const float4*)Wl;
        float4* Wd = (float4*)Wf;
        #pragma unroll
        for (int i = 0; i < 8; ++i) Wd[t + i * 512] = Wg[t + i * 512];
        if (t < 64) bs[t] = bl[t];
    }
    __syncthreads();
    {
        const int col = t & 63;
        const int kb  = (t >> 6) * 32;
        float v[32];
        #pragma unroll
        for (int j = 0; j < 32; ++j) v[j] = Wf[(size_t)(kb + j) * 64 + col];
        __syncthreads();
        #pragma unroll
        for (int c = 0; c < 4; ++c) {
            unsigned h8[8], l8[8];
            #pragma unroll
            for (int j = 0; j < 8; ++j) {
                const float w0 = v[c * 8 + j];
                const unsigned hb = bf16_rne(w0);
                h8[j] = hb;
                l8[j] = bf16_rne(w0 - __uint_as_float(hb << 16));
            }
            uint4 ph, pl;
            ph.x = h8[0] | (h8[1] << 16); ph.y = h8[2] | (h8[3] << 16);
            ph.z = h8[4] | (h8[5] << 16); ph.w = h8[6] | (h8[7] << 16);
            pl.x = l8[0] | (l8[1] << 16); pl.y = l8[2] | (l8[3] << 16);
            pl.z = l8[4] | (l8[5] << 16); pl.w = l8[6] | (l8[7] << 16);
            const int off = (col * 512 + (kb + c * 8) * 2) ^ ((col & 7) << 4);
            *(uint4*)(Whi + off) = ph;
            *(uint4*)(Wlo + off) = pl;
        }
    }
    __syncthreads();

    const int w  = t >> 6;
    const int l  = t & 63;
    const int wm = w >> 1;
    const int wn = w & 1;
    const int g  = l >> 4;
    const int q  = l & 15;
    const int r0 = (int)blockIdx.x * 128;

    f32x4 acc[2][2];
    const f32x4 zero = {0.f, 0.f, 0.f, 0.f};
    acc[0][0] = zero; acc[0][1] = zero; acc[1][0] = zero; acc[1][1] = zero;

    #pragma unroll
    for (int ks = 0; ks < 8; ++ks) {
        const int kf = (ks & 3) * 32 + g * 8;
        bf16x8 ah[2], al[2];
        #pragma unroll
        for (int m = 0; m < 2; ++m) {
            const int rr = min(r0 + wm * 32 + m * 16 + q, N - 1);
            float d[8];
            if (ks < 4) {
                const float* ph = h       + (size_t)rr * DD + kf;
                const float* ps = sum_agg + (size_t)rr * DD + kf;
                const int*   pm = max_agg + (size_t)rr * DD + kf;
                const float4 a0 = *(const float4*)ph;
                const float4 a1 = *(const float4*)(ph + 4);
                const float4 s0 = *(const float4*)ps;
                const float4 s1 = *(const float4*)(ps + 4);
                const int4   i0 = *(const int4*)pm;
                const int4   i1 = *(const int4*)(pm + 4);
                d[0] = a0.x * a0.x * s0.x * __int_as_float(i0.x);
                d[1] = a0.y * a0.y * s0.y * __int_as_float(i0.y);
                d[2] = a0.z * a0.z * s0.z * __int_as_float(i0.z);
                d[3] = a0.w * a0.w * s0.w * __int_as_float(i0.w);
                d[4] = a1.x * a1.x * s1.x * __int_as_float(i1.x);
                d[5] = a1.y * a1.y * s1.y * __int_as_float(i1.y);
                d[6] = a1.z * a1.z * s1.z * __int_as_float(i1.z);
                d[7] = a1.w * a1.w * s1.w * __int_as_float(i1.w);
            } else {
                const float* pa = xp + (size_t)rr * DD + kf;
                const float4 a0 = *(const float4*)pa;
                const float4 a1 = *(const float4*)(pa + 4);
                d[0] = a0.x; d[1] = a0.y; d[2] = a0.z; d[3] = a0.w;
                d[4] = a1.x; d[5] = a1.y; d[6] = a1.z; d[7] = a1.w;
            }
            unsigned h8[8], l8[8];
            #pragma unroll
            for (int j = 0; j < 8; ++j) {
                const unsigned hb = bf16_rne(d[j]);
                h8[j] = hb;
                l8[j] = bf16_rne(d[j] - __uint_as_float(hb << 16));
            }
            uint4 ph2, pl2;
            ph2.x = h8[0] | (h8[1] << 16); ph2.y = h8[2] | (h8[3] << 16);
            ph2.z = h8[4] | (h8[5] << 16); ph2.w = h8[6] | (h8[7] << 16);
            pl2.x = l8[0] | (l8[1] << 16); pl2.y = l8[2] | (l8[3] << 16);
            pl2.z = l8[4] | (l8[5] << 16); pl2.w = l8[6] | (l8[7] << 16);
            ah[m] = *(bf16x8*)&ph2;
            al[m] = *(bf16x8*)&pl2;
        }
        bf16x8 bh[2], blo[2];
        #pragma unroll
        for (int n = 0; n < 2; ++n) {
            const int colv = wn * 32 + n * 16 + q;
            const int off = (colv * 512 + ks * 64 + g * 16) ^ ((colv & 7) << 4);
            bh[n]  = *(const bf16x8*)(Whi + off);
            blo[n] = *(const bf16x8*)(Wlo + off);
        }
        #pragma unroll
        for (int m = 0; m < 2; ++m)
            #pragma unroll
            for (int n = 0; n < 2; ++n) {
                acc[m][n] = __builtin_amdgcn_mfma_f32_16x16x32_bf16(ah[m], bh[n],  acc[m][n], 0, 0, 0);
                acc[m][n] = __builtin_amdgcn_mfma_f32_16x16x32_bf16(ah[m], blo[n], acc[m][n], 0, 0, 0);
                acc[m][n] = __builtin_amdgcn_mfma_f32_16x16x32_bf16(al[m], bh[n],  acc[m][n], 0, 0, 0);
            }
    }

    #pragma unroll
    for (int n = 0; n < 2; ++n) {
        const int colv = wn * 32 + n * 16 + q;
        const float bv = bs[colv];
        #pragma unroll
        for (int m = 0; m < 2; ++m) {
            #pragma unroll
            for (int r = 0; r < 4; ++r) {
                const int row = r0 + wm * 32 + m * 16 + g * 4 + r;
                if (row < N) out[(size_t)row * 64 + colv] = acc[m][n][r] + bv;
            }
        }
    }
}

// ---------------------------------------------------------------------------
extern "C" void kernel_launch(void* const* d_in, const int* in_sizes, int n_in,
                              void* d_out, int out_size, void* d_ws, size_t ws_size,
                              hipStream_t stream)
{
    const float* x         = (const float*)d_in[0];
    const int*   edge_idx  = (const int*)d_in[1];
    const float* edge_attr = (const float*)d_in[2];
    const float* W_atom    = (const float*)d_in[3];
    const float* b_atom    = (const float*)d_in[4];
    const float* W_bond    = (const float*)d_in[5];
    const float* b_bond    = (const float*)d_in[6];
    const float* W_seq     = (const float*)d_in[7];
    const float* b_seq     = (const float*)d_in[8];
    const float* W_lin     = (const float*)d_in[9];
    const float* b_lin     = (const float*)d_in[10];
    float* out = (float*)d_out;

    const int N = in_sizes[0] / DD;   // 30000
    const int E = in_sizes[1] / 2;    // 480000
    const int* idx_i = edge_idx;
    const int* idx_j = edge_idx + E;

    const size_t nd = (size_t)N * DD;
    float* ws      = (float*)d_ws;
    float* x_proj  = ws;
    float* h_atom  = x_proj + nd;
    float* head    = h_atom + nd;
    float* sum_agg = head + nd;
    int*   max_agg = (int*)(sum_agg + nd);
    float* PQ      = (float*)(max_agg + nd);   // 2N x 128
    int*   cnt     = (int*)(PQ + 2 * nd);
    int*   cursor  = cnt + N;
    int*   bsum    = cursor + N;
    int*   perm    = bsum + 256;
    int*   si      = perm + E;
    int*   sj      = si + E;

    // ---- counting sort of edges by idx_i ----
    hipMemsetAsync(cnt, 0, (size_t)N * 4, stream);
    hist_kernel<<<(E + 255) / 256, 256, 0, stream>>>(idx_i, cnt, E);
    const int nb_scan = (N + SCB - 1) / SCB;
    scan1_kernel<<<nb_scan, SCB, 0, stream>>>(cnt, cursor, bsum, N);
    scan2_kernel<<<1, SCB, 0, stream>>>(bsum, nb_scan);
    scan3_kernel<<<nb_scan, SCB, 0, stream>>>(cursor, bsum, N);
    scatter_kernel<<<(E + 255) / 256, 256, 0, stream>>>(idx_i, idx_j, cursor, perm, si, sj, E);

    hipMemsetAsync(sum_agg, 0, nd * 4, stream);
    hipMemsetAsync(max_agg, 0, nd * 4, stream);

    // node projection via MFMA: x_proj = h_atom = relu(x @ W_atom + b_atom)
    const int ntiles_n = (N + 127) / 128;
    gemm128_mfma_kernel<<<ntiles_n, 512, 0, stream>>>(
        (float*)x, x, N, N, W_atom, b_atom, N, 1, 0, nullptr, nullptr,
        x_proj, h_atom, ntiles_n);

    // bond projection + layer-0 aggregation (v6: f16 dot2)
    bond_pass_kernel<<<(E + CB - 1) / CB, 512, 0, stream>>>(
        edge_attr, W_bond, b_bond, si, perm, head, sum_agg, max_agg, E, N);

    const int ntiles_pq = (2 * N + 127) / 128;
    const int ep_blocks = (E + CE - 1) / CE;
    for (int l = 0; l < 3; ++l) {
        gemm128_mfma_kernel<<<ntiles_pq, 512, 0, stream>>>(
            h_atom, head, N, 2 * N, W_seq + (size_t)l * DD * DD,
            b_seq + (size_t)l * DD, N, 0, 1, sum_agg, max_agg,
            PQ, nullptr, ntiles_pq);
        edge_pass_kernel<<<ep_blocks, 512, 0, stream>>>(
            PQ, si, sj, perm, head, (l < 2) ? 1 : 0, sum_agg, max_agg, E, N);
    }

    final_mfma_kernel<<<(N + 127) / 128, 512, 0, stream>>>(
        h_atom, sum_agg, (const int*)max_agg, x_proj, W_lin, b_lin, out, N);
}

// Round 15
// 384.263 us; speedup vs baseline: 1.1874x; 1.0081x over previous
//
#include <hip/hip_runtime.h>
#include <hip/hip_bf16.h>

#define DD 128   // hidden dim
#define SCB 256  // scan block size
#define CE  512  // edges per block in edge_pass (8 waves x 64)
#define CB  512  // edges per block in bond pass (8 waves x 64)

typedef __attribute__((ext_vector_type(8))) short bf16x8;
typedef __attribute__((ext_vector_type(4))) float f32x4;
typedef __attribute__((ext_vector_type(2))) _Float16 f16x2;
typedef __attribute__((ext_vector_type(8))) _Float16 f16x8;

__device__ __forceinline__ unsigned bf16_rne(float f) {
    unsigned u = __float_as_uint(f);
    return (u + 0x7fffu + ((u >> 16) & 1u)) >> 16;
}

// ---------------------------------------------------------------------------
// counting-sort preprocessing (sort edges by idx_i)
// ---------------------------------------------------------------------------
__global__ __launch_bounds__(256)
void hist_kernel(const int* __restrict__ idx_i, int* __restrict__ cnt, int E)
{
    const int e = blockIdx.x * 256 + threadIdx.x;
    if (e < E) atomicAdd(&cnt[idx_i[e]], 1);
}

__global__ __launch_bounds__(SCB)
void scan1_kernel(const int* __restrict__ cnt, int* __restrict__ exc,
                  int* __restrict__ bsum, int n)
{
    __shared__ int s[SCB];
    const int i = blockIdx.x * SCB + (int)threadIdx.x;
    const int v = (i < n) ? cnt[i] : 0;
    s[threadIdx.x] = v;
    __syncthreads();
    #pragma unroll
    for (int off = 1; off < SCB; off <<= 1) {
        int t = (threadIdx.x >= off) ? s[threadIdx.x - off] : 0;
        __syncthreads();
        s[threadIdx.x] += t;
        __syncthreads();
    }
    if (i < n) exc[i] = s[threadIdx.x] - v;
    if (threadIdx.x == SCB - 1) bsum[blockIdx.x] = s[threadIdx.x];
}

__global__ __launch_bounds__(SCB)
void scan2_kernel(int* __restrict__ bsum, int nb)
{
    __shared__ int s[SCB];
    const int v = (threadIdx.x < nb) ? bsum[threadIdx.x] : 0;
    s[threadIdx.x] = v;
    __syncthreads();
    #pragma unroll
    for (int off = 1; off < SCB; off <<= 1) {
        int t = (threadIdx.x >= off) ? s[threadIdx.x - off] : 0;
        __syncthreads();
        s[threadIdx.x] += t;
        __syncthreads();
    }
    if (threadIdx.x < nb) bsum[threadIdx.x] = s[threadIdx.x] - v;
}

__global__ __launch_bounds__(SCB)
void scan3_kernel(int* __restrict__ exc, const int* __restrict__ bsum, int n)
{
    const int i = blockIdx.x * SCB + (int)threadIdx.x;
    if (i < n) exc[i] += bsum[i >> 8];
}

__global__ __launch_bounds__(256)
void scatter_kernel(const int* __restrict__ idx_i, const int* __restrict__ idx_j,
                    int* __restrict__ cursor, int* __restrict__ perm,
                    int* __restrict__ si, int* __restrict__ sj, int E)
{
    const int e = blockIdx.x * 256 + threadIdx.x;
    if (e < E) {
        const int n = idx_i[e];
        const int p = atomicAdd(&cursor[n], 1);
        perm[p] = e;
        si[p] = n;
        sj[p] = idx_j[e];
    }
}

// ---------------------------------------------------------------------------
// gemm128 v2 (unchanged): W fragments in registers, A-only LDS (64 KB),
// used for the per-layer PQ GEMM with fused node-update.
// ---------------------------------------------------------------------------
__global__ __launch_bounds__(512, 4)
void gemm128_mfma_kernel(float* __restrict__ A0, const float* __restrict__ A1,
                         int nA, int nTotal,
                         const float* __restrict__ W, const float* __restrict__ bias,
                         int bias_limit, int do_relu, int update,
                         float* __restrict__ sum_agg, int* __restrict__ max_agg,
                         float* __restrict__ out0, float* __restrict__ out1,
                         int ntiles)
{
    __shared__ __align__(16) unsigned char SM[65536];
    char* const Ahi = (char*)SM;
    char* const Alo = (char*)SM + 32768;

    const int t = (int)threadIdx.x;
    const int w = t >> 6;
    const int l = t & 63;
    const int g = l >> 4;
    const int q = l & 15;
    const int colv = w * 16 + q;

    bf16x8 wh[4], wl[4];
    #pragma unroll
    for (int ks = 0; ks < 4; ++ks) {
        unsigned h8[8], l8[8];
        #pragma unroll
        for (int j = 0; j < 8; ++j) {
            const float w0 = W[(size_t)(ks * 32 + g * 8 + j) * DD + colv];
            const unsigned hb = bf16_rne(w0);
            h8[j] = hb;
            l8[j] = bf16_rne(w0 - __uint_as_float(hb << 16));
        }
        uint4 ph, pl;
        ph.x = h8[0] | (h8[1] << 16); ph.y = h8[2] | (h8[3] << 16);
        ph.z = h8[4] | (h8[5] << 16); ph.w = h8[6] | (h8[7] << 16);
        pl.x = l8[0] | (l8[1] << 16); pl.y = l8[2] | (l8[3] << 16);
        pl.z = l8[4] | (l8[5] << 16); pl.w = l8[6] | (l8[7] << 16);
        wh[ks] = *(bf16x8*)&ph;
        wl[ks] = *(bf16x8*)&pl;
    }
    const float bv = bias ? bias[colv] : 0.f;

    for (int tile = blockIdx.x; tile < ntiles; tile += gridDim.x) {
        const int e0 = tile * 128;
        __syncthreads();

        #pragma unroll
        for (int i = 0; i < 4; ++i) {
            const int task = t + i * 512;
            const int row  = task >> 4;
            const int c    = task & 15;
            const int rr = min(e0 + row, nTotal - 1);
            float d[8];
            if (rr < nA) {
                float* ph0 = A0 + (size_t)rr * DD + c * 8;
                const float4 a0 = *(const float4*)ph0;
                const float4 a1 = *(const float4*)(ph0 + 4);
                if (update) {
                    float* sp = sum_agg + (size_t)rr * DD + c * 8;
                    int*   mp = max_agg + (size_t)rr * DD + c * 8;
                    const float4 s0 = *(const float4*)sp;
                    const float4 s1 = *(const float4*)(sp + 4);
                    const int4   m0 = *(const int4*)mp;
                    const int4   m1 = *(const int4*)(mp + 4);
                    d[0] = a0.x * s0.x * __int_as_float(m0.x);
                    d[1] = a0.y * s0.y * __int_as_float(m0.y);
                    d[2] = a0.z * s0.z * __int_as_float(m0.z);
                    d[3] = a0.w * s0.w * __int_as_float(m0.w);
                    d[4] = a1.x * s1.x * __int_as_float(m1.x);
                    d[5] = a1.y * s1.y * __int_as_float(m1.y);
                    d[6] = a1.z * s1.z * __int_as_float(m1.z);
                    d[7] = a1.w * s1.w * __int_as_float(m1.w);
                    *(float4*)ph0       = make_float4(d[0], d[1], d[2], d[3]);
                    *(float4*)(ph0 + 4) = make_float4(d[4], d[5], d[6], d[7]);
                    *(float4*)sp       = make_float4(0.f, 0.f, 0.f, 0.f);
                    *(float4*)(sp + 4) = make_float4(0.f, 0.f, 0.f, 0.f);
                    *(int4*)mp       = make_int4(0, 0, 0, 0);
                    *(int4*)(mp + 4) = make_int4(0, 0, 0, 0);
                } else {
                    d[0] = a0.x; d[1] = a0.y; d[2] = a0.z; d[3] = a0.w;
                    d[4] = a1.x; d[5] = a1.y; d[6] = a1.z; d[7] = a1.w;
                }
            } else {
                const float* pa = A1 + (size_t)(rr - nA) * DD + c * 8;
                const float4 a0 = *(const float4*)pa;
                const float4 a1 = *(const float4*)(pa + 4);
                d[0] = a0.x; d[1] = a0.y; d[2] = a0.z; d[3] = a0.w;
                d[4] = a1.x; d[5] = a1.y; d[6] = a1.z; d[7] = a1.w;
            }
            unsigned h8[8], l8[8];
            #pragma unroll
            for (int j = 0; j < 8; ++j) {
                const unsigned hb = bf16_rne(d[j]);
                h8[j] = hb;
                l8[j] = bf16_rne(d[j] - __uint_as_float(hb << 16));
            }
            uint4 ph, pl;
            ph.x = h8[0] | (h8[1] << 16); ph.y = h8[2] | (h8[3] << 16);
            ph.z = h8[4] | (h8[5] << 16); ph.w = h8[6] | (h8[7] << 16);
            pl.x = l8[0] | (l8[1] << 16); pl.y = l8[2] | (l8[3] << 16);
            pl.z = l8[4] | (l8[5] << 16); pl.w = l8[6] | (l8[7] << 16);
            const int off = ((row * 256 + c * 16)) ^ ((row & 7) << 4);
            *(uint4*)(Ahi + off) = ph;
            *(uint4*)(Alo + off) = pl;
        }
        __syncthreads();

        f32x4 acc[8];
        const f32x4 zero = {0.f, 0.f, 0.f, 0.f};
        #pragma unroll
        for (int m = 0; m < 8; ++m) acc[m] = zero;

        #pragma unroll
        for (int ks = 0; ks < 4; ++ks) {
            const int kbyte = ks * 64 + g * 16;
            #pragma unroll
            for (int m = 0; m < 8; ++m) {
                const int row = m * 16 + q;
                const int off = (row * 256 + kbyte) ^ ((row & 7) << 4);
                const bf16x8 ah = *(const bf16x8*)(Ahi + off);
                const bf16x8 al = *(const bf16x8*)(Alo + off);
                acc[m] = __builtin_amdgcn_mfma_f32_16x16x32_bf16(ah, wh[ks], acc[m], 0, 0, 0);
                acc[m] = __builtin_amdgcn_mfma_f32_16x16x32_bf16(ah, wl[ks], acc[m], 0, 0, 0);
                acc[m] = __builtin_amdgcn_mfma_f32_16x16x32_bf16(al, wh[ks], acc[m], 0, 0, 0);
            }
        }

        #pragma unroll
        for (int m = 0; m < 8; ++m) {
            #pragma unroll
            for (int r = 0; r < 4; ++r) {
                const int row = e0 + m * 16 + g * 4 + r;
                if (row < nTotal) {
                    float v = acc[m][r] + ((row < bias_limit) ? bv : 0.f);
                    if (do_relu) v = fmaxf(v, 0.f);
                    out0[(size_t)row * DD + colv] = v;
                    if (out1) out1[(size_t)row * DD + colv] = v;
                }
            }
        }
    }
}

// ---------------------------------------------------------------------------
// FUSED front-end: blocks [0, nTilesProj) run the node-projection gemm
// (x_proj = h_atom = relu(x@W_atom+b)); blocks [nTilesProj, +nBondBlocks)
// run the bond projection + layer-0 aggregation (f16 dot2 + segmented
// ownership). Independent work co-resident -> VALU(bond) overlaps
// MFMA/memory(gemm).
// ---------------------------------------------------------------------------
__global__ __launch_bounds__(512, 4)
void proj_bond_kernel(const float* __restrict__ x,
                      const float* __restrict__ W, const float* __restrict__ bias,
                      float* __restrict__ x_proj, float* __restrict__ h_atom,
                      int Nn, int nTilesProj,
                      const float* __restrict__ edge_attr,
                      const float* __restrict__ Wb, const float* __restrict__ bb,
                      const int* __restrict__ si, const int* __restrict__ perm,
                      float* __restrict__ h_head0,
                      float* __restrict__ sum_agg, int* __restrict__ max_agg,
                      int E)
{
    __shared__ __align__(16) unsigned char SM[65536];
    const int t = (int)threadIdx.x;

    if ((int)blockIdx.x < nTilesProj) {
        // ================= node projection (gemm path) =================
        char* const Ahi = (char*)SM;
        char* const Alo = (char*)SM + 32768;
        const int w = t >> 6;
        const int l = t & 63;
        const int g = l >> 4;
        const int q = l & 15;
        const int colv = w * 16 + q;

        bf16x8 wh[4], wl[4];
        #pragma unroll
        for (int ks = 0; ks < 4; ++ks) {
            unsigned h8[8], l8[8];
            #pragma unroll
            for (int j = 0; j < 8; ++j) {
                const float w0 = W[(size_t)(ks * 32 + g * 8 + j) * DD + colv];
                const unsigned hb = bf16_rne(w0);
                h8[j] = hb;
                l8[j] = bf16_rne(w0 - __uint_as_float(hb << 16));
            }
            uint4 ph, pl;
            ph.x = h8[0] | (h8[1] << 16); ph.y = h8[2] | (h8[3] << 16);
            ph.z = h8[4] | (h8[5] << 16); ph.w = h8[6] | (h8[7] << 16);
            pl.x = l8[0] | (l8[1] << 16); pl.y = l8[2] | (l8[3] << 16);
            pl.z = l8[4] | (l8[5] << 16); pl.w = l8[6] | (l8[7] << 16);
            wh[ks] = *(bf16x8*)&ph;
            wl[ks] = *(bf16x8*)&pl;
        }
        const float bv = bias[colv];

        const int e0 = (int)blockIdx.x * 128;

        #pragma unroll
        for (int i = 0; i < 4; ++i) {
            const int task = t + i * 512;
            const int row  = task >> 4;
            const int c    = task & 15;
            const int rr = min(e0 + row, Nn - 1);
            const float* pa = x + (size_t)rr * DD + c * 8;
            const float4 a0 = *(const float4*)pa;
            const float4 a1 = *(const float4*)(pa + 4);
            float d[8] = {a0.x, a0.y, a0.z, a0.w, a1.x, a1.y, a1.z, a1.w};
            unsigned h8[8], l8[8];
            #pragma unroll
            for (int j = 0; j < 8; ++j) {
                const unsigned hb = bf16_rne(d[j]);
                h8[j] = hb;
                l8[j] = bf16_rne(d[j] - __uint_as_float(hb << 16));
            }
            uint4 ph, pl;
            ph.x = h8[0] | (h8[1] << 16); ph.y = h8[2] | (h8[3] << 16);
            ph.z = h8[4] | (h8[5] << 16); ph.w = h8[6] | (h8[7] << 16);
            pl.x = l8[0] | (l8[1] << 16); pl.y = l8[2] | (l8[3] << 16);
            pl.z = l8[4] | (l8[5] << 16); pl.w = l8[6] | (l8[7] << 16);
            const int off = ((row * 256 + c * 16)) ^ ((row & 7) << 4);
            *(uint4*)(Ahi + off) = ph;
            *(uint4*)(Alo + off) = pl;
        }
        __syncthreads();

        f32x4 acc[8];
        const f32x4 zero = {0.f, 0.f, 0.f, 0.f};
        #pragma unroll
        for (int m = 0; m < 8; ++m) acc[m] = zero;

        #pragma unroll
        for (int ks = 0; ks < 4; ++ks) {
            const int kbyte = ks * 64 + g * 16;
            #pragma unroll
            for (int m = 0; m < 8; ++m) {
                const int row = m * 16 + q;
                const int off = (row * 256 + kbyte) ^ ((row & 7) << 4);
                const bf16x8 ah = *(const bf16x8*)(Ahi + off);
                const bf16x8 al = *(const bf16x8*)(Alo + off);
                acc[m] = __builtin_amdgcn_mfma_f32_16x16x32_bf16(ah, wh[ks], acc[m], 0, 0, 0);
                acc[m] = __builtin_amdgcn_mfma_f32_16x16x32_bf16(ah, wl[ks], acc[m], 0, 0, 0);
                acc[m] = __builtin_amdgcn_mfma_f32_16x16x32_bf16(al, wh[ks], acc[m], 0, 0, 0);
            }
        }

        #pragma unroll
        for (int m = 0; m < 8; ++m) {
            #pragma unroll
            for (int r = 0; r < 4; ++r) {
                const int row = e0 + m * 16 + g * 4 + r;
                if (row < Nn) {
                    const float v = fmaxf(acc[m][r] + bv, 0.f);
                    x_proj[(size_t)row * DD + colv] = v;
                    h_atom[(size_t)row * DD + colv] = v;
                }
            }
        }
    } else {
        // ================= bond projection + aggregation (f16 dot2) =====
        _Float16* const ea_s = (_Float16*)SM;                 // [CB][16], 16 KB
        int* const si_s = (int*)(SM + 16384);                 // 2 KB
        int* const pm_s = (int*)(SM + 18432);                 // 2 KB

        const int bid = (int)blockIdx.x - nTilesProj;
        const int p0b = bid * CB;
        if (p0b >= E) return;

        for (int i = t; i < CB; i += 512) {
            const int p = min(p0b + i, E - 1);
            si_s[i] = si[p];
            pm_s[i] = perm[p];
        }
        for (int task = t; task < CB * 2; task += 512) {
            const int row = task >> 1;
            const int h8i = task & 1;
            const int p = min(p0b + row, E - 1);
            const int orig = perm[p];
            const float4 a0 = *(const float4*)(edge_attr + (size_t)orig * 16 + h8i * 8);
            const float4 a1 = *(const float4*)(edge_attr + (size_t)orig * 16 + h8i * 8 + 4);
            f16x8 hv;
            hv[0] = (_Float16)a0.x; hv[1] = (_Float16)a0.y;
            hv[2] = (_Float16)a0.z; hv[3] = (_Float16)a0.w;
            hv[4] = (_Float16)a1.x; hv[5] = (_Float16)a1.y;
            hv[6] = (_Float16)a1.z; hv[7] = (_Float16)a1.w;
            *(f16x8*)(&ea_s[row * 16 + h8i * 8]) = hv;
        }
        __syncthreads();

        const int w    = t >> 6;
        const int lane = t & 63;
        const int c    = lane * 2;
        const int q0   = w * 64;
        const int pg0  = p0b + q0;
        if (pg0 >= E) return;

        f16x2 w0h[8], w1h[8];
        #pragma unroll
        for (int k = 0; k < 8; ++k) {
            const float2 wa  = *(const float2*)(Wb + (2 * k)     * DD + c);
            const float2 wb2 = *(const float2*)(Wb + (2 * k + 1) * DD + c);
            w0h[k][0] = (_Float16)wa.x; w0h[k][1] = (_Float16)wb2.x;
            w1h[k][0] = (_Float16)wa.y; w1h[k][1] = (_Float16)wb2.y;
        }
        const float2 bc = *(const float2*)(bb + c);

        const int firstNode = si_s[q0];
        const int lastNode  = si_s[q0 + 63];

        int curNode = firstNode;
        float2 rs = make_float2(0.f, 0.f), rm = make_float2(0.f, 0.f);

        #define BP_FLUSH()                                                       \
        {                                                                        \
            if (curNode == firstNode || curNode == lastNode) {                   \
                atomicAdd(&sum_agg[(size_t)curNode * DD + c],     rs.x);         \
                atomicAdd(&sum_agg[(size_t)curNode * DD + c + 1], rs.y);         \
                atomicMax(&max_agg[(size_t)curNode * DD + c],     __float_as_int(rm.x)); \
                atomicMax(&max_agg[(size_t)curNode * DD + c + 1], __float_as_int(rm.y)); \
            } else {                                                             \
                *(float2*)(sum_agg + (size_t)curNode * DD + c) = rs;             \
                *(int2*)(max_agg + (size_t)curNode * DD + c) =                   \
                    make_int2(__float_as_int(rm.x), __float_as_int(rm.y));       \
            }                                                                    \
        }

        #pragma unroll 4
        for (int kk = 0; kk < 64; ++kk) {
            const int i = si_s[q0 + kk];
            if (i != curNode) {
                BP_FLUSH();
                curNode = i;
                rs = make_float2(0.f, 0.f);
                rm = make_float2(0.f, 0.f);
            }
            const f16x8 e0 = *(const f16x8*)(&ea_s[(q0 + kk) * 16]);
            const f16x8 e1 = *(const f16x8*)(&ea_s[(q0 + kk) * 16 + 8]);
            float ax = bc.x, ay = bc.y;
            f16x2 p2;
            p2[0] = e0[0]; p2[1] = e0[1];
            ax = __builtin_amdgcn_fdot2(p2, w0h[0], ax, false);
            ay = __builtin_amdgcn_fdot2(p2, w1h[0], ay, false);
            p2[0] = e0[2]; p2[1] = e0[3];
            ax = __builtin_amdgcn_fdot2(p2, w0h[1], ax, false);
            ay = __builtin_amdgcn_fdot2(p2, w1h[1], ay, false);
            p2[0] = e0[4]; p2[1] = e0[5];
            ax = __builtin_amdgcn_fdot2(p2, w0h[2], ax, false);
            ay = __builtin_amdgcn_fdot2(p2, w1h[2], ay, false);
            p2[0] = e0[6]; p2[1] = e0[7];
            ax = __builtin_amdgcn_fdot2(p2, w0h[3], ax, false);
            ay = __builtin_amdgcn_fdot2(p2, w1h[3], ay, false);
            p2[0] = e1[0]; p2[1] = e1[1];
            ax = __builtin_amdgcn_fdot2(p2, w0h[4], ax, false);
            ay = __builtin_amdgcn_fdot2(p2, w1h[4], ay, false);
            p2[0] = e1[2]; p2[1] = e1[3];
            ax = __builtin_amdgcn_fdot2(p2, w0h[5], ax, false);
            ay = __builtin_amdgcn_fdot2(p2, w1h[5], ay, false);
            p2[0] = e1[4]; p2[1] = e1[5];
            ax = __builtin_amdgcn_fdot2(p2, w0h[6], ax, false);
            ay = __builtin_amdgcn_fdot2(p2, w1h[6], ay, false);
            p2[0] = e1[6]; p2[1] = e1[7];
            ax = __builtin_amdgcn_fdot2(p2, w0h[7], ax, false);
            ay = __builtin_amdgcn_fdot2(p2, w1h[7], ay, false);
            float2 v;
            v.x = fmaxf(ax, 0.f);
            v.y = fmaxf(ay, 0.f);
            if (pg0 + kk >= E) { v.x = 0.f; v.y = 0.f; }
            rs.x += v.x; rs.y += v.y;
            rm.x = fmaxf(rm.x, v.x); rm.y = fmaxf(rm.y, v.y);
            if (pg0 + kk < E) {
                const int orig = pm_s[q0 + kk];
                if (orig < Nn) *(float2*)(h_head0 + (size_t)orig * DD + c) = v;
            }
        }
        BP_FLUSH();
        #undef BP_FLUSH
    }
}

// ---------------------------------------------------------------------------
// edge pass v4 (unchanged): 8 waves x 64 edges + 8-deep prefetch;
// segmented ownership.
// ---------------------------------------------------------------------------
__global__ __launch_bounds__(512)
void edge_pass_kernel(const float* __restrict__ PQ,
                      const int* __restrict__ si, const int* __restrict__ sj,
                      const int* __restrict__ perm,
                      float* __restrict__ head_next, int store_head,
                      float* __restrict__ sum_agg, int* __restrict__ max_agg,
                      int E, int N)
{
    __shared__ int si_s[CE], sj_s[CE], pm_s[CE];
    const int p0b = blockIdx.x * CE;
    if (p0b >= E) return;
    const int t = (int)threadIdx.x;
    for (int i = t; i < CE; i += 512) {
        const int p = min(p0b + i, E - 1);
        si_s[i] = si[p];
        sj_s[i] = sj[p];
        pm_s[i] = perm[p];
    }
    __syncthreads();

    const int w    = t >> 6;
    const int lane = t & 63;
    const int c    = lane * 2;
    const int q0   = w * 64;
    const int pg0  = p0b + q0;
    if (pg0 >= E) return;

    const int firstNode = si_s[q0];
    const int lastNode  = si_s[q0 + 63];

    const float* __restrict__ Qbase = PQ + (size_t)N * DD + c;

    float2 qa = *(const float2*)(Qbase + (size_t)sj_s[q0 + 0] * DD);
    float2 qb = *(const float2*)(Qbase + (size_t)sj_s[q0 + 1] * DD);
    float2 qc = *(const float2*)(Qbase + (size_t)sj_s[q0 + 2] * DD);
    float2 qd = *(const float2*)(Qbase + (size_t)sj_s[q0 + 3] * DD);
    float2 qe = *(const float2*)(Qbase + (size_t)sj_s[q0 + 4] * DD);
    float2 qf = *(const float2*)(Qbase + (size_t)sj_s[q0 + 5] * DD);
    float2 qg = *(const float2*)(Qbase + (size_t)sj_s[q0 + 6] * DD);
    float2 qh = *(const float2*)(Qbase + (size_t)sj_s[q0 + 7] * DD);

    int curNode = firstNode;
    float2 Pi = *(const float2*)(PQ + (size_t)curNode * DD + c);
    float2 rs = make_float2(0.f, 0.f), rm = make_float2(0.f, 0.f);

    #define EP_FLUSH()                                                           \
    {                                                                            \
        if (curNode == firstNode || curNode == lastNode) {                       \
            atomicAdd(&sum_agg[(size_t)curNode * DD + c],     rs.x);             \
            atomicAdd(&sum_agg[(size_t)curNode * DD + c + 1], rs.y);             \
            atomicMax(&max_agg[(size_t)curNode * DD + c],     __float_as_int(rm.x)); \
            atomicMax(&max_agg[(size_t)curNode * DD + c + 1], __float_as_int(rm.y)); \
        } else {                                                                 \
            *(float2*)(sum_agg + (size_t)curNode * DD + c) = rs;                 \
            *(int2*)(max_agg + (size_t)curNode * DD + c) =                       \
                make_int2(__float_as_int(rm.x), __float_as_int(rm.y));           \
        }                                                                        \
    }

    #define EP_STEP(K, QREG)                                                     \
    {                                                                            \
        const int kk = (K);                                                      \
        const int i = si_s[q0 + kk];                                             \
        if (i != curNode) {                                                      \
            EP_FLUSH();                                                          \
            curNode = i;                                                         \
            Pi = *(const float2*)(PQ + (size_t)i * DD + c);                      \
            rs = make_float2(0.f, 0.f);                                          \
            rm = make_float2(0.f, 0.f);                                          \
        }                                                                        \
        float2 v;                                                                \
        v.x = fmaxf(Pi.x - QREG.x, 0.f);                                         \
        v.y = fmaxf(Pi.y - QREG.y, 0.f);                                         \
        if (pg0 + kk >= E) { v.x = 0.f; v.y = 0.f; }                             \
        rs.x += v.x; rs.y += v.y;                                                \
        rm.x = fmaxf(rm.x, v.x); rm.y = fmaxf(rm.y, v.y);                        \
        if (store_head && (pg0 + kk) < E) {                                      \
            const int orig = pm_s[q0 + kk];                                      \
            if (orig < N) *(float2*)(head_next + (size_t)orig * DD + c) = v;     \
        }                                                                        \
        if (kk + 8 < 64)                                                         \
            QREG = *(const float2*)(Qbase + (size_t)sj_s[q0 + kk + 8] * DD);     \
    }

    #pragma unroll
    for (int k = 0; k < 64; k += 8) {
        EP_STEP(k + 0, qa);
        EP_STEP(k + 1, qb);
        EP_STEP(k + 2, qc);
        EP_STEP(k + 3, qd);
        EP_STEP(k + 4, qe);
        EP_STEP(k + 5, qf);
        EP_STEP(k + 6, qg);
        EP_STEP(k + 7, qh);
    }
    EP_FLUSH();
    #undef EP_STEP
    #undef EP_FLUSH
}

// ---------------------------------------------------------------------------
// final: out = [ha, x_proj] @ W_lin + b_lin via split-bf16 MFMA, K=256
// (unchanged)
// ---------------------------------------------------------------------------
__global__ __launch_bounds__(512, 2)
void final_mfma_kernel(const float* __restrict__ h, const float* __restrict__ sum_agg,
                       const int* __restrict__ max_agg, const float* __restrict__ xp,
                       const float* __restrict__ Wl, const float* __restrict__ bl,
                       float* __restrict__ out, int N)
{
    __shared__ __align__(16) unsigned char SM[65808];
    char*  const Whi = (char*)SM;
    char*  const Wlo = (char*)SM + 32768;
    float* const Wf  = (float*)SM;
    float* const bs  = (float*)(SM + 65536);

    const int t = (int)threadIdx.x;
    {
        const float4* Wg = (const float4*)Wl;
        float4* Wd = (float4*)Wf;
        #pragma unroll
        for (int i = 0; i < 8; ++i) Wd[t + i * 512] = Wg[t + i * 512];
        if (t < 64) bs[t] = bl[t];
    }
    __syncthreads();
    {
        const int col = t & 63;
        const int kb  = (t >> 6) * 32;
        float v[32];
        #pragma unroll
        for (int j = 0; j < 32; ++j) v[j] = Wf[(size_t)(kb + j) * 64 + col];
        __syncthreads();
        #pragma unroll
        for (int c = 0; c < 4; ++c) {
            unsigned h8[8], l8[8];
            #pragma unroll
            for (int j = 0; j < 8; ++j) {
                const float w0 = v[c * 8 + j];
                const unsigned hb = bf16_rne(w0);
                h8[j] = hb;
                l8[j] = bf16_rne(w0 - __uint_as_float(hb << 16));
            }
            uint4 ph, pl;
            ph.x = h8[0] | (h8[1] << 16); ph.y = h8[2] | (h8[3] << 16);
            ph.z = h8[4] | (h8[5] << 16); ph.w = h8[6] | (h8[7] << 16);
            pl.x = l8[0] | (l8[1] << 16); pl.y = l8[2] | (l8[3] << 16);
            pl.z = l8[4] | (l8[5] << 16); pl.w = l8[6] | (l8[7] << 16);
            const int off = (col * 512 + (kb + c * 8) * 2) ^ ((col & 7) << 4);
            *(uint4*)(Whi + off) = ph;
            *(uint4*)(Wlo + off) = pl;
        }
    }
    __syncthreads();

    const int w  = t >> 6;
    const int l  = t & 63;
    const int wm = w >> 1;
    const int wn = w & 1;
    const int g  = l >> 4;
    const int q  = l & 15;
    const int r0 = (int)blockIdx.x * 128;

    f32x4 acc[2][2];
    const f32x4 zero = {0.f, 0.f, 0.f, 0.f};
    acc[0][0] = zero; acc[0][1] = zero; acc[1][0] = zero; acc[1][1] = zero;

    #pragma unroll
    for (int ks = 0; ks < 8; ++ks) {
        const int kf = (ks & 3) * 32 + g * 8;
        bf16x8 ah[2], al[2];
        #pragma unroll
        for (int m = 0; m < 2; ++m) {
            const int rr = min(r0 + wm * 32 + m * 16 + q, N - 1);
            float d[8];
            if (ks < 4) {
                const float* ph = h       + (size_t)rr * DD + kf;
                const float* ps = sum_agg + (size_t)rr * DD + kf;
                const int*   pm = max_agg + (size_t)rr * DD + kf;
                const float4 a0 = *(const float4*)ph;
                const float4 a1 = *(const float4*)(ph + 4);
                const float4 s0 = *(const float4*)ps;
                const float4 s1 = *(const float4*)(ps + 4);
                const int4   i0 = *(const int4*)pm;
                const int4   i1 = *(const int4*)(pm + 4);
                d[0] = a0.x * a0.x * s0.x * __int_as_float(i0.x);
                d[1] = a0.y * a0.y * s0.y * __int_as_float(i0.y);
                d[2] = a0.z * a0.z * s0.z * __int_as_float(i0.z);
                d[3] = a0.w * a0.w * s0.w * __int_as_float(i0.w);
                d[4] = a1.x * a1.x * s1.x * __int_as_float(i1.x);
                d[5] = a1.y * a1.y * s1.y * __int_as_float(i1.y);
                d[6] = a1.z * a1.z * s1.z * __int_as_float(i1.z);
                d[7] = a1.w * a1.w * s1.w * __int_as_float(i1.w);
            } else {
                const float* pa = xp + (size_t)rr * DD + kf;
                const float4 a0 = *(const float4*)pa;
                const float4 a1 = *(const float4*)(pa + 4);
                d[0] = a0.x; d[1] = a0.y; d[2] = a0.z; d[3] = a0.w;
                d[4] = a1.x; d[5] = a1.y; d[6] = a1.z; d[7] = a1.w;
            }
            unsigned h8[8], l8[8];
            #pragma unroll
            for (int j = 0; j < 8; ++j) {
                const unsigned hb = bf16_rne(d[j]);
                h8[j] = hb;
                l8[j] = bf16_rne(d[j] - __uint_as_float(hb << 16));
            }
            uint4 ph2, pl2;
            ph2.x = h8[0] | (h8[1] << 16); ph2.y = h8[2] | (h8[3] << 16);
            ph2.z = h8[4] | (h8[5] << 16); ph2.w = h8[6] | (h8[7] << 16);
            pl2.x = l8[0] | (l8[1] << 16); pl2.y = l8[2] | (l8[3] << 16);
            pl2.z = l8[4] | (l8[5] << 16); pl2.w = l8[6] | (l8[7] << 16);
            ah[m] = *(bf16x8*)&ph2;
            al[m] = *(bf16x8*)&pl2;
        }
        bf16x8 bh[2], blo[2];
        #pragma unroll
        for (int n = 0; n < 2; ++n) {
            const int colv = wn * 32 + n * 16 + q;
            const int off = (colv * 512 + ks * 64 + g * 16) ^ ((colv & 7) << 4);
            bh[n]  = *(const bf16x8*)(Whi + off);
            blo[n] = *(const bf16x8*)(Wlo + off);
        }
        #pragma unroll
        for (int m = 0; m < 2; ++m)
            #pragma unroll
            for (int n = 0; n < 2; ++n) {
                acc[m][n] = __builtin_amdgcn_mfma_f32_16x16x32_bf16(ah[m], bh[n],  acc[m][n], 0, 0, 0);
                acc[m][n] = __builtin_amdgcn_mfma_f32_16x16x32_bf16(ah[m], blo[n], acc[m][n], 0, 0, 0);
                acc[m][n] = __builtin_amdgcn_mfma_f32_16x16x32_bf16(al[m], bh[n],  acc[m][n], 0, 0, 0);
            }
    }

    #pragma unroll
    for (int n = 0; n < 2; ++n) {
        const int colv = wn * 32 + n * 16 + q;
        const float bv = bs[colv];
        #pragma unroll
        for (int m = 0; m < 2; ++m) {
            #pragma unroll
            for (int r = 0; r < 4; ++r) {
                const int row = r0 + wm * 32 + m * 16 + g * 4 + r;
                if (row < N) out[(size_t)row * 64 + colv] = acc[m][n][r] + bv;
            }
        }
    }
}

// ---------------------------------------------------------------------------
extern "C" void kernel_launch(void* const* d_in, const int* in_sizes, int n_in,
                              void* d_out, int out_size, void* d_ws, size_t ws_size,
                              hipStream_t stream)
{
    const float* x         = (const float*)d_in[0];
    const int*   edge_idx  = (const int*)d_in[1];
    const float* edge_attr = (const float*)d_in[2];
    const float* W_atom    = (const float*)d_in[3];
    const float* b_atom    = (const float*)d_in[4];
    const float* W_bond    = (const float*)d_in[5];
    const float* b_bond    = (const float*)d_in[6];
    const float* W_seq     = (const float*)d_in[7];
    const float* b_seq     = (const float*)d_in[8];
    const float* W_lin     = (const float*)d_in[9];
    const float* b_lin     = (const float*)d_in[10];
    float* out = (float*)d_out;

    const int N = in_sizes[0] / DD;   // 30000
    const int E = in_sizes[1] / 2;    // 480000
    const int* idx_i = edge_idx;
    const int* idx_j = edge_idx + E;

    const size_t nd = (size_t)N * DD;
    float* ws      = (float*)d_ws;
    float* x_proj  = ws;
    float* h_atom  = x_proj + nd;
    float* head    = h_atom + nd;
    float* sum_agg = head + nd;
    int*   max_agg = (int*)(sum_agg + nd);
    float* PQ      = (float*)(max_agg + nd);   // 2N x 128
    int*   cnt     = (int*)(PQ + 2 * nd);
    int*   cursor  = cnt + N;
    int*   bsum    = cursor + N;
    int*   perm    = bsum + 256;
    int*   si      = perm + E;
    int*   sj      = si + E;

    // ---- counting sort of edges by idx_i ----
    hipMemsetAsync(cnt, 0, (size_t)N * 4, stream);
    hist_kernel<<<(E + 255) / 256, 256, 0, stream>>>(idx_i, cnt, E);
    const int nb_scan = (N + SCB - 1) / SCB;
    scan1_kernel<<<nb_scan, SCB, 0, stream>>>(cnt, cursor, bsum, N);
    scan2_kernel<<<1, SCB, 0, stream>>>(bsum, nb_scan);
    scan3_kernel<<<nb_scan, SCB, 0, stream>>>(cursor, bsum, N);
    scatter_kernel<<<(E + 255) / 256, 256, 0, stream>>>(idx_i, idx_j, cursor, perm, si, sj, E);

    hipMemsetAsync(sum_agg, 0, nd * 4, stream);
    hipMemsetAsync(max_agg, 0, nd * 4, stream);

    // FUSED: node projection (gemm blocks) + bond projection/agg (bond blocks)
    const int ntiles_n   = (N + 127) / 128;            // 235 gemm blocks
    const int bond_blocks = (E + CB - 1) / CB;         // 938 bond blocks
    proj_bond_kernel<<<ntiles_n + bond_blocks, 512, 0, stream>>>(
        x, W_atom, b_atom, x_proj, h_atom, N, ntiles_n,
        edge_attr, W_bond, b_bond, si, perm, head, sum_agg, max_agg, E);

    const int ntiles_pq = (2 * N + 127) / 128;
    const int ep_blocks = (E + CE - 1) / CE;
    for (int l = 0; l < 3; ++l) {
        gemm128_mfma_kernel<<<ntiles_pq, 512, 0, stream>>>(
            h_atom, head, N, 2 * N, W_seq + (size_t)l * DD * DD,
            b_seq + (size_t)l * DD, N, 0, 1, sum_agg, max_agg,
            PQ, nullptr, ntiles_pq);
        edge_pass_kernel<<<ep_blocks, 512, 0, stream>>>(
            PQ, si, sj, perm, head, (l < 2) ? 1 : 0, sum_agg, max_agg, E, N);
    }

    final_mfma_kernel<<<(N + 127) / 128, 512, 0, stream>>>(
        h_atom, sum_agg, (const int*)max_agg, x_proj, W_lin, b_lin, out, N);
}